// Round 4
// baseline (10781.888 us; speedup 1.0000x reference)
//
#include <hip/hip_runtime.h>
#include <hip/hip_bf16.h>

#define NG 50
#define NB 128

__device__ __forceinline__ float sspf(float x){
  float t = __expf(-fabsf(x));
  return fmaxf(x, 0.f) + __logf(1.f + t) - 0.6931471805599453094f;
}

constexpr float RBF_STEP  = 5.0f / 49.0f;
constexpr float RBF_COEFF = -0.5f / (RBF_STEP * RBF_STEP);

// ---------------- h = embed[r] ----------------
__global__ void embed_k(const int* __restrict__ r, const float* __restrict__ embed,
                        float* __restrict__ h, int N){
  int idx = blockIdx.x * blockDim.x + threadIdx.x;
  if (idx < N * 32){
    int n = idx >> 5, c = (idx & 31) * 4;
    *(float4*)&h[(size_t)n * NB + c] = *(const float4*)&embed[(size_t)r[n] * NB + c];
  }
}

// ---------------- per-edge distance ----------------
__global__ void dist_k(const int* __restrict__ a, const float* __restrict__ xyz,
                       float* __restrict__ d, int E){
  int e = blockIdx.x * blockDim.x + threadIdx.x;
  if (e < E){
    int i = a[2*e], j = a[2*e+1];
    float dx = xyz[3*i+0] - xyz[3*j+0];
    float dy = xyz[3*i+1] - xyz[3*j+1];
    float dz = xyz[3*i+2] - xyz[3*j+2];
    d[e] = sqrtf(dx*dx + dy*dy + dz*dz);
  }
}

// ================= CSR build =================
__global__ void hist_k(const int* __restrict__ a, int* __restrict__ cnt, int E){
  int e = blockIdx.x * blockDim.x + threadIdx.x;
  if (e < E){
    atomicAdd(&cnt[a[2*e]],   1);
    atomicAdd(&cnt[a[2*e+1]], 1);
  }
}

#define SCAN_TILE 512
__global__ void reduce_k(const int* __restrict__ cnt, int* __restrict__ bsum, int N){
  __shared__ int s[256];
  int b = blockIdx.x, t = threadIdx.x;
  int i0 = b*SCAN_TILE + t;
  int v = 0;
  if (i0 < N)       v += cnt[i0];
  if (i0+256 < N)   v += cnt[i0+256];
  s[t] = v; __syncthreads();
  for (int o=128;o>0;o>>=1){ if (t<o) s[t]+=s[t+o]; __syncthreads(); }
  if (t==0) bsum[b] = s[0];
}

__global__ void scanb_k(const int* __restrict__ bsum, int* __restrict__ boff, int nb){
  if (threadIdx.x==0 && blockIdx.x==0){
    int acc = 0;
    for (int i=0;i<nb;i++){ boff[i]=acc; acc+=bsum[i]; }
  }
}

__global__ void scan2_k(const int* __restrict__ cnt, const int* __restrict__ boff,
                        int* __restrict__ rowptr, int N, int total){
  __shared__ int s[256];
  int b = blockIdx.x, t = threadIdx.x;
  int i0 = b*SCAN_TILE;
  int a0 = (i0+2*t   < N) ? cnt[i0+2*t]   : 0;
  int a1 = (i0+2*t+1 < N) ? cnt[i0+2*t+1] : 0;
  int pair = a0 + a1;
  s[t] = pair; __syncthreads();
  for (int o=1;o<256;o<<=1){
    int v = (t>=o) ? s[t-o] : 0;
    __syncthreads();
    s[t] += v;
    __syncthreads();
  }
  int excl = s[t] - pair + boff[b];
  if (i0+2*t   < N) rowptr[i0+2*t]   = excl;
  if (i0+2*t+1 < N) rowptr[i0+2*t+1] = excl + a0;
  if (b==0 && t==0) rowptr[N] = total;
}

__global__ void copy_k(const int* __restrict__ src, int* __restrict__ dst, int n){
  int i = blockIdx.x*blockDim.x + threadIdx.x;
  if (i < n) dst[i] = src[i];
}

__global__ void fill_k(const int* __restrict__ a, int* __restrict__ cur,
                       int2* __restrict__ adj, int E){
  int e = blockIdx.x*blockDim.x + threadIdx.x;
  if (e < E){
    int i = a[2*e], j = a[2*e+1];
    int p = atomicAdd(&cur[i], 1);
    adj[p] = make_int2(j, e);
    int q = atomicAdd(&cur[j], 1);
    adj[q] = make_int2(i, e);
  }
}

// ---------------- generic (N x 128) @ (128 x 128) + b, opt ssp, opt residual ----
template<int ACT, int RESID>
__launch_bounds__(128, 3)
__global__ void gemm128_k(const float* __restrict__ in, const float* __restrict__ W,
                          const float* __restrict__ bias, float* __restrict__ out, int N){
  __shared__ float As[32][64];
  __shared__ float Ws[32][128];
  int tid = threadIdx.x;
  int tc = tid & 15, tr = tid >> 4;
  int row0 = blockIdx.x * 64;
  int c0 = tc * 8;

  float bcol[8];
  {
    float4 b0 = *(const float4*)&bias[c0];
    float4 b1 = *(const float4*)&bias[c0+4];
    bcol[0]=b0.x; bcol[1]=b0.y; bcol[2]=b0.z; bcol[3]=b0.w;
    bcol[4]=b1.x; bcol[5]=b1.y; bcol[6]=b1.z; bcol[7]=b1.w;
  }
  float acc[8][8];
  #pragma unroll
  for (int r=0;r<8;r++)
    #pragma unroll
    for (int q=0;q<8;q++) acc[r][q] = bcol[q];

  for (int kc=0; kc<4; kc++){
    #pragma unroll
    for (int p=0;p<4;p++){
      int f = tid + 128*p;
      int rr = f >> 3, kq = f & 7;
      int grow = row0 + rr;
      float4 v = (grow < N) ? *(const float4*)&in[(size_t)grow*NB + kc*32 + kq*4]
                            : make_float4(0.f,0.f,0.f,0.f);
      As[kq*4+0][rr] = v.x; As[kq*4+1][rr] = v.y;
      As[kq*4+2][rr] = v.z; As[kq*4+3][rr] = v.w;
    }
    #pragma unroll
    for (int p=0;p<8;p++){
      int f = tid + 128*p;
      int wk = f >> 5, cq = f & 31;
      *(float4*)&Ws[wk][cq*4] = *(const float4*)&W[(size_t)(kc*32+wk)*NB + cq*4];
    }
    __syncthreads();
    #pragma unroll 4
    for (int k=0;k<32;k++){
      float4 a0 = *(const float4*)&As[k][tr*8];
      float4 a1 = *(const float4*)&As[k][tr*8+4];
      float4 w0 = *(const float4*)&Ws[k][c0];
      float4 w1 = *(const float4*)&Ws[k][c0+4];
      float av[8] = {a0.x,a0.y,a0.z,a0.w,a1.x,a1.y,a1.z,a1.w};
      float wv[8] = {w0.x,w0.y,w0.z,w0.w,w1.x,w1.y,w1.z,w1.w};
      #pragma unroll
      for (int r=0;r<8;r++)
        #pragma unroll
        for (int q=0;q<8;q++) acc[r][q] += av[r]*wv[q];
    }
    __syncthreads();
  }
  #pragma unroll
  for (int r=0;r<8;r++){
    int row = row0 + tr*8 + r;
    if (row < N){
      float v[8];
      #pragma unroll
      for (int q=0;q<8;q++) v[q] = (ACT==1) ? sspf(acc[r][q]) : acc[r][q];
      if (RESID){
        float4 o0 = *(const float4*)&out[(size_t)row*NB + c0];
        float4 o1 = *(const float4*)&out[(size_t)row*NB + c0+4];
        v[0]+=o0.x; v[1]+=o0.y; v[2]+=o0.z; v[3]+=o0.w;
        v[4]+=o1.x; v[5]+=o1.y; v[6]+=o1.z; v[7]+=o1.w;
      }
      *(float4*)&out[(size_t)row*NB + c0]   = make_float4(v[0],v[1],v[2],v[3]);
      *(float4*)&out[(size_t)row*NB + c0+4] = make_float4(v[4],v[5],v[6],v[7]);
    }
  }
}

// ---------------- ef_k: ef = ssp(g@We1+be1)@We2+be2 -> efbuf (f32) ----------
__launch_bounds__(256, 2)
__global__ void ef_k(const float* __restrict__ dists,
                     const float* __restrict__ We1, const float* __restrict__ be1,
                     const float* __restrict__ We2, const float* __restrict__ be2,
                     float* __restrict__ efbuf, int E){
  __shared__ float We1s[NG][64];
  __shared__ float We2s[NG][NB];
  __shared__ float buf[NG][NB];
  __shared__ float be1s[64], be2s[NB];
  __shared__ float ds_[NB];
  int tid = threadIdx.x;

  for (int idx = tid; idx < NG*64; idx += 256){
    int m = idx >> 6, k = idx & 63;
    We1s[m][k] = (k < NG) ? We1[m*NG + k] : 0.f;
  }
  for (int idx = tid; idx < NG*NB; idx += 256)
    We2s[0][idx] = We2[idx];
  if (tid < 64)  be1s[tid] = (tid < NG) ? be1[tid] : 0.f;
  if (tid < NB)  be2s[tid] = be2[tid];

  int ebase = blockIdx.x * NB;
  if (tid < NB){
    int e = ebase + tid;
    ds_[tid] = (e < E) ? dists[e] : 0.f;
  }
  __syncthreads();

  for (int idx = tid; idx < NG*NB; idx += 256){
    int m = idx >> 7, e = idx & 127;
    float t = ds_[e] - RBF_STEP * (float)m;
    buf[m][e] = __expf(RBF_COEFF * t * t);
  }
  __syncthreads();

  int te = tid >> 4, tk = tid & 15;
  int e0 = te * 8, k0 = tk * 4;

  float tacc[8][4];
  {
    float4 bv = *(const float4*)&be1s[k0];
    float bq[4] = {bv.x,bv.y,bv.z,bv.w};
    #pragma unroll
    for (int r=0;r<8;r++)
      #pragma unroll
      for (int q=0;q<4;q++) tacc[r][q] = bq[q];
  }
  #pragma unroll 2
  for (int m=0;m<NG;m++){
    float4 w  = *(const float4*)&We1s[m][k0];
    float4 g0 = *(const float4*)&buf[m][e0];
    float4 g1 = *(const float4*)&buf[m][e0+4];
    float ge[8] = {g0.x,g0.y,g0.z,g0.w,g1.x,g1.y,g1.z,g1.w};
    float wv[4] = {w.x,w.y,w.z,w.w};
    #pragma unroll
    for (int r=0;r<8;r++)
      #pragma unroll
      for (int q=0;q<4;q++) tacc[r][q] += ge[r]*wv[q];
  }
  __syncthreads();
  #pragma unroll
  for (int q=0;q<4;q++){
    int k = k0 + q;
    if (k < NG){
      float v[8];
      #pragma unroll
      for (int r=0;r<8;r++) v[r] = sspf(tacc[r][q]);
      *(float4*)&buf[k][e0]   = make_float4(v[0],v[1],v[2],v[3]);
      *(float4*)&buf[k][e0+4] = make_float4(v[4],v[5],v[6],v[7]);
    }
  }
  __syncthreads();

  int c0 = tk * 8;
  float acc[8][8];
  {
    float4 b0 = *(const float4*)&be2s[c0];
    float4 b1 = *(const float4*)&be2s[c0+4];
    float bq[8] = {b0.x,b0.y,b0.z,b0.w,b1.x,b1.y,b1.z,b1.w};
    #pragma unroll
    for (int r=0;r<8;r++)
      #pragma unroll
      for (int q=0;q<8;q++) acc[r][q] = bq[q];
  }
  #pragma unroll 2
  for (int k=0;k<NG;k++){
    float4 w0 = *(const float4*)&We2s[k][c0];
    float4 w1 = *(const float4*)&We2s[k][c0+4];
    float4 t0 = *(const float4*)&buf[k][e0];
    float4 t1 = *(const float4*)&buf[k][e0+4];
    float tv[8] = {t0.x,t0.y,t0.z,t0.w,t1.x,t1.y,t1.z,t1.w};
    float wv[8] = {w0.x,w0.y,w0.z,w0.w,w1.x,w1.y,w1.z,w1.w};
    #pragma unroll
    for (int r=0;r<8;r++)
      #pragma unroll
      for (int q=0;q<8;q++) acc[r][q] += tv[r]*wv[q];
  }

  #pragma unroll
  for (int r=0;r<8;r++){
    int e = ebase + e0 + r;
    if (e < E){
      *(float4*)&efbuf[(size_t)e*NB + c0]   = make_float4(acc[r][0],acc[r][1],acc[r][2],acc[r][3]);
      *(float4*)&efbuf[(size_t)e*NB + c0+4] = make_float4(acc[r][4],acc[r][5],acc[r][6],acc[r][7]);
    }
  }
}

// ---------------- gather_k: agg[n] = sum_{(src,e) in adj[n]} nodef[src]*ef[e] --
__launch_bounds__(256)
__global__ void gather_k(const float* __restrict__ nodef, const float* __restrict__ efbuf,
                         const int2* __restrict__ adj, const int* __restrict__ rowptr,
                         float* __restrict__ agg, int N){
  int wave = blockIdx.x * (blockDim.x >> 6) + (threadIdx.x >> 6);
  int lane = threadIdx.x & 63;
  if (wave >= N) return;
  int beg = rowptr[wave], end = rowptr[wave+1];
  int c = lane * 2;
  float ax = 0.f, ay = 0.f;
  int k = beg;
  for (; k + 2 <= end; k += 2){
    int2 p0 = adj[k], p1 = adj[k+1];
    float2 n0 = *(const float2*)&nodef[(size_t)p0.x*NB + c];
    float2 f0 = *(const float2*)&efbuf[(size_t)p0.y*NB + c];
    float2 n1 = *(const float2*)&nodef[(size_t)p1.x*NB + c];
    float2 f1 = *(const float2*)&efbuf[(size_t)p1.y*NB + c];
    ax += n0.x*f0.x; ay += n0.y*f0.y;
    ax += n1.x*f1.x; ay += n1.y*f1.y;
  }
  if (k < end){
    int2 p0 = adj[k];
    float2 n0 = *(const float2*)&nodef[(size_t)p0.x*NB + c];
    float2 f0 = *(const float2*)&efbuf[(size_t)p0.y*NB + c];
    ax += n0.x*f0.x; ay += n0.y*f0.y;
  }
  *(float2*)&agg[(size_t)wave*NB + c] = make_float2(ax, ay);
}

// ---------------- legacy atomic edge kernel (ws fallback) --------------------
__launch_bounds__(256, 2)
__global__ void edge_k(const float* __restrict__ dists, const int* __restrict__ a,
                       const float* __restrict__ nodef,
                       const float* __restrict__ We1, const float* __restrict__ be1,
                       const float* __restrict__ We2, const float* __restrict__ be2,
                       float* __restrict__ agg, int E){
  __shared__ float We1s[NG][64];
  __shared__ float We2s[NG][NB];
  __shared__ float buf[NG][NB];
  __shared__ float be1s[64], be2s[NB];
  __shared__ float ds_[NB];
  __shared__ int   ijs[2*NB];
  int tid = threadIdx.x;

  for (int idx = tid; idx < NG*64; idx += 256){
    int m = idx >> 6, k = idx & 63;
    We1s[m][k] = (k < NG) ? We1[m*NG + k] : 0.f;
  }
  for (int idx = tid; idx < NG*NB; idx += 256)
    We2s[0][idx] = We2[idx];
  if (tid < 64)  be1s[tid] = (tid < NG) ? be1[tid] : 0.f;
  if (tid < NB)  be2s[tid] = be2[tid];

  int ebase = blockIdx.x * NB;
  if (tid < NB){
    int e = ebase + tid;
    if (e < E){ ds_[tid] = dists[e]; ijs[2*tid] = a[2*e]; ijs[2*tid+1] = a[2*e+1]; }
    else      { ds_[tid] = 0.f;      ijs[2*tid] = -1;     ijs[2*tid+1] = -1; }
  }
  __syncthreads();
  for (int idx = tid; idx < NG*NB; idx += 256){
    int m = idx >> 7, e = idx & 127;
    float t = ds_[e] - RBF_STEP * (float)m;
    buf[m][e] = __expf(RBF_COEFF * t * t);
  }
  __syncthreads();
  int te = tid >> 4, tk = tid & 15;
  int e0 = te * 8, k0 = tk * 4;
  float tacc[8][4];
  {
    float4 bv = *(const float4*)&be1s[k0];
    float bq[4] = {bv.x,bv.y,bv.z,bv.w};
    #pragma unroll
    for (int r=0;r<8;r++)
      #pragma unroll
      for (int q=0;q<4;q++) tacc[r][q] = bq[q];
  }
  #pragma unroll 2
  for (int m=0;m<NG;m++){
    float4 w  = *(const float4*)&We1s[m][k0];
    float4 g0 = *(const float4*)&buf[m][e0];
    float4 g1 = *(const float4*)&buf[m][e0+4];
    float ge[8] = {g0.x,g0.y,g0.z,g0.w,g1.x,g1.y,g1.z,g1.w};
    float wv[4] = {w.x,w.y,w.z,w.w};
    #pragma unroll
    for (int r=0;r<8;r++)
      #pragma unroll
      for (int q=0;q<4;q++) tacc[r][q] += ge[r]*wv[q];
  }
  __syncthreads();
  #pragma unroll
  for (int q=0;q<4;q++){
    int k = k0 + q;
    if (k < NG){
      float v[8];
      #pragma unroll
      for (int r=0;r<8;r++) v[r] = sspf(tacc[r][q]);
      *(float4*)&buf[k][e0]   = make_float4(v[0],v[1],v[2],v[3]);
      *(float4*)&buf[k][e0+4] = make_float4(v[4],v[5],v[6],v[7]);
    }
  }
  __syncthreads();
  int c0 = tk * 8;
  float acc[8][8];
  {
    float4 b0 = *(const float4*)&be2s[c0];
    float4 b1 = *(const float4*)&be2s[c0+4];
    float bq[8] = {b0.x,b0.y,b0.z,b0.w,b1.x,b1.y,b1.z,b1.w};
    #pragma unroll
    for (int r=0;r<8;r++)
      #pragma unroll
      for (int q=0;q<8;q++) acc[r][q] = bq[q];
  }
  #pragma unroll 2
  for (int k=0;k<NG;k++){
    float4 w0 = *(const float4*)&We2s[k][c0];
    float4 w1 = *(const float4*)&We2s[k][c0+4];
    float4 t0 = *(const float4*)&buf[k][e0];
    float4 t1 = *(const float4*)&buf[k][e0+4];
    float tv[8] = {t0.x,t0.y,t0.z,t0.w,t1.x,t1.y,t1.z,t1.w};
    float wv[8] = {w0.x,w0.y,w0.z,w0.w,w1.x,w1.y,w1.z,w1.w};
    #pragma unroll
    for (int r=0;r<8;r++)
      #pragma unroll
      for (int q=0;q<8;q++) acc[r][q] += tv[r]*wv[q];
  }
  #pragma unroll
  for (int r=0;r<8;r++){
    int el = e0 + r;
    int i = ijs[2*el], j = ijs[2*el+1];
    if (i < 0) continue;
    float4 nj0 = *(const float4*)&nodef[(size_t)j*NB + c0];
    float4 nj1 = *(const float4*)&nodef[(size_t)j*NB + c0+4];
    float4 ni0 = *(const float4*)&nodef[(size_t)i*NB + c0];
    float4 ni1 = *(const float4*)&nodef[(size_t)i*NB + c0+4];
    float* ai = &agg[(size_t)i*NB + c0];
    float* aj = &agg[(size_t)j*NB + c0];
    float njv[8] = {nj0.x,nj0.y,nj0.z,nj0.w,nj1.x,nj1.y,nj1.z,nj1.w};
    float niv[8] = {ni0.x,ni0.y,ni0.z,ni0.w,ni1.x,ni1.y,ni1.z,ni1.w};
    #pragma unroll
    for (int q=0;q<8;q++){
      atomicAdd(ai+q, njv[q]*acc[r][q]);
      atomicAdd(aj+q, niv[q]*acc[r][q]);
    }
  }
}

// ---------------- readout: e = ssp(h@W1+b1)@W2+b2, molecule segment sum ------
__launch_bounds__(128, 3)
__global__ void readout_k(const float* __restrict__ h, const float* __restrict__ W1,
                          const float* __restrict__ b1, const float* __restrict__ W2,
                          const float* __restrict__ b2, const int* __restrict__ molp,
                          float* __restrict__ out, int N){
  __shared__ float As[32][64];
  __shared__ float W1s[32][64];
  __shared__ float segsum[2];
  int tid = threadIdx.x;
  int tc = tid & 15, tr = tid >> 4;
  int row0 = blockIdx.x * 64;
  int c0 = tc * 4;

  float acc[8][4];
  {
    float4 bv = *(const float4*)&b1[c0];
    float bq[4] = {bv.x,bv.y,bv.z,bv.w};
    #pragma unroll
    for (int r=0;r<8;r++)
      #pragma unroll
      for (int q=0;q<4;q++) acc[r][q] = bq[q];
  }
  for (int kc=0;kc<4;kc++){
    #pragma unroll
    for (int p=0;p<4;p++){
      int f = tid + 128*p; int rr = f >> 3; int kq = f & 7;
      int grow = row0 + rr;
      float4 v = (grow < N) ? *(const float4*)&h[(size_t)grow*NB + kc*32 + kq*4]
                            : make_float4(0.f,0.f,0.f,0.f);
      As[kq*4+0][rr] = v.x; As[kq*4+1][rr] = v.y;
      As[kq*4+2][rr] = v.z; As[kq*4+3][rr] = v.w;
    }
    #pragma unroll
    for (int p=0;p<4;p++){
      int f = tid + 128*p; int wk = f >> 4; int cq = f & 15;
      *(float4*)&W1s[wk][cq*4] = *(const float4*)&W1[(size_t)(kc*32+wk)*64 + cq*4];
    }
    __syncthreads();
    #pragma unroll 4
    for (int k=0;k<32;k++){
      float4 a0 = *(const float4*)&As[k][tr*8];
      float4 a1 = *(const float4*)&As[k][tr*8+4];
      float4 w  = *(const float4*)&W1s[k][c0];
      float av[8] = {a0.x,a0.y,a0.z,a0.w,a1.x,a1.y,a1.z,a1.w};
      float wv[4] = {w.x,w.y,w.z,w.w};
      #pragma unroll
      for (int r=0;r<8;r++)
        #pragma unroll
        for (int q=0;q<4;q++) acc[r][q] += av[r]*wv[q];
    }
    __syncthreads();
  }
  float4 w2f = *(const float4*)&W2[c0];
  float part[8];
  #pragma unroll
  for (int r=0;r<8;r++)
    part[r] = sspf(acc[r][0])*w2f.x + sspf(acc[r][1])*w2f.y +
              sspf(acc[r][2])*w2f.z + sspf(acc[r][3])*w2f.w;
  #pragma unroll
  for (int off=1; off<16; off<<=1)
    #pragma unroll
    for (int r=0;r<8;r++) part[r] += __shfl_xor(part[r], off);

  if (tid < 2) segsum[tid] = 0.f;
  __syncthreads();
  int ms = molp[0];
  float b2v = b2[0];
  int seg0 = row0 / ms;
  if (tc == 0){
    #pragma unroll
    for (int r=0;r<8;r++){
      int row = row0 + tr*8 + r;
      if (row < N){
        int s = row/ms - seg0;
        if (s < 2) atomicAdd(&segsum[s], part[r] + b2v);
        else       atomicAdd(&out[row/ms], part[r] + b2v);
      }
    }
  }
  __syncthreads();
  if (tid == 0 && segsum[0] != 0.f) atomicAdd(&out[seg0], segsum[0]);
  if (tid == 1){
    int lastrow = row0 + 63; if (lastrow > N-1) lastrow = N-1;
    if (lastrow/ms > seg0 && segsum[1] != 0.f) atomicAdd(&out[seg0+1], segsum[1]);
  }
}

extern "C" void kernel_launch(void* const* d_in, const int* in_sizes, int n_in,
                              void* d_out, int out_size, void* d_ws, size_t ws_size,
                              hipStream_t stream){
  const int*   r     = (const int*)  d_in[0];
  const float* xyz   = (const float*)d_in[1];
  const int*   a     = (const int*)  d_in[2];
  const int*   molp  = (const int*)  d_in[3];
  const float* embed = (const float*)d_in[4];
  const float* Wn    = (const float*)d_in[5];
  const float* bn    = (const float*)d_in[6];
  const float* We1   = (const float*)d_in[7];
  const float* be1   = (const float*)d_in[8];
  const float* We2   = (const float*)d_in[9];
  const float* be2   = (const float*)d_in[10];
  const float* Wu1   = (const float*)d_in[11];
  const float* bu1   = (const float*)d_in[12];
  const float* Wu2   = (const float*)d_in[13];
  const float* bu2   = (const float*)d_in[14];
  const float* W1    = (const float*)d_in[15];
  const float* b1    = (const float*)d_in[16];
  const float* W2    = (const float*)d_in[17];
  const float* b2    = (const float*)d_in[18];

  int N = in_sizes[0];          // 50000
  int E = in_sizes[2] / 2;      // 500000

  float* ws   = (float*)d_ws;
  size_t E4   = ((size_t)E + 3) & ~(size_t)3;
  size_t NSZ  = (size_t)N * NB;
  size_t RPAD = ((size_t)N + 1 + 3) & ~(size_t)3;
  size_t NPAD = ((size_t)N + 3) & ~(size_t)3;

  // layout: dbuf | h | nodef | agg | efbuf | ints(rowptr,cnt,cur,bsum,boff,adj)
  size_t need_elems = E4 + 3*NSZ + (size_t)E*NB
                    + RPAD + 2*NPAD + 512 + 4*(size_t)E;
  bool modeA = ws_size >= need_elems * sizeof(float);

  float* dbuf = ws;
  float* h    = dbuf + E4;
  float* nodef= h + NSZ;
  float* agg  = nodef + NSZ;

  int gblocks = (N + 63)/64;
  int eblocks = (E + 127)/128;

  embed_k<<<(N*32 + 255)/256, 256, 0, stream>>>(r, embed, h, N);
  dist_k <<<(E + 255)/256,    256, 0, stream>>>(a, xyz, dbuf, E);

  if (modeA){
    float* efbuf  = agg + NSZ;
    int*   rowptr = (int*)(efbuf + (size_t)E*NB);
    int*   cnt    = rowptr + RPAD;
    int*   cur    = cnt + NPAD;
    int*   bsum   = cur + NPAD;
    int*   boff   = bsum + 256;
    int2*  adj    = (int2*)(boff + 256);

    int nb = (N + SCAN_TILE - 1) / SCAN_TILE;
    hipMemsetAsync(cnt, 0, (size_t)N*sizeof(int), stream);
    hist_k  <<<(E + 255)/256, 256, 0, stream>>>(a, cnt, E);
    reduce_k<<<nb, 256, 0, stream>>>(cnt, bsum, N);
    scanb_k <<<1, 64, 0, stream>>>(bsum, boff, nb);
    scan2_k <<<nb, 256, 0, stream>>>(cnt, boff, rowptr, N, 2*E);
    copy_k  <<<(N + 255)/256, 256, 0, stream>>>(rowptr, cur, N);
    fill_k  <<<(E + 255)/256, 256, 0, stream>>>(a, cur, adj, E);

    for (int l = 0; l < 3; l++){
      gemm128_k<0,0><<<gblocks, 128, 0, stream>>>(h, Wn + (size_t)l*NB*NB, bn + l*NB, nodef, N);
      ef_k<<<eblocks, 256, 0, stream>>>(dbuf,
                                        We1 + (size_t)l*NG*NG, be1 + l*NG,
                                        We2 + (size_t)l*NG*NB, be2 + l*NB, efbuf, E);
      gather_k<<<(N + 3)/4, 256, 0, stream>>>(nodef, efbuf, adj, rowptr, agg, N);
      gemm128_k<1,0><<<gblocks, 128, 0, stream>>>(agg,   Wu1 + (size_t)l*NB*NB, bu1 + l*NB, nodef, N);
      gemm128_k<0,1><<<gblocks, 128, 0, stream>>>(nodef, Wu2 + (size_t)l*NB*NB, bu2 + l*NB, h, N);
    }
  } else {
    for (int l = 0; l < 3; l++){
      gemm128_k<0,0><<<gblocks, 128, 0, stream>>>(h, Wn + (size_t)l*NB*NB, bn + l*NB, nodef, N);
      hipMemsetAsync(agg, 0, NSZ*sizeof(float), stream);
      edge_k<<<eblocks, 256, 0, stream>>>(dbuf, a, nodef,
                                          We1 + (size_t)l*NG*NG, be1 + l*NG,
                                          We2 + (size_t)l*NG*NB, be2 + l*NB, agg, E);
      gemm128_k<1,0><<<gblocks, 128, 0, stream>>>(agg,   Wu1 + (size_t)l*NB*NB, bu1 + l*NB, nodef, N);
      gemm128_k<0,1><<<gblocks, 128, 0, stream>>>(nodef, Wu2 + (size_t)l*NB*NB, bu2 + l*NB, h, N);
    }
  }

  hipMemsetAsync(d_out, 0, (size_t)out_size*sizeof(float), stream);
  readout_k<<<gblocks, 128, 0, stream>>>(h, W1, b1, W2, b2, molp, (float*)d_out, N);
}

// Round 5
// 2842.634 us; speedup vs baseline: 3.7929x; 3.7929x over previous
//
#include <hip/hip_runtime.h>
#include <hip/hip_bf16.h>

#define NG 50
#define NB 128

__device__ __forceinline__ float sspf(float x){
  float t = __expf(-fabsf(x));
  return fmaxf(x, 0.f) + __logf(1.f + t) - 0.6931471805599453094f;
}

constexpr float RBF_STEP  = 5.0f / 49.0f;
constexpr float RBF_COEFF = -0.5f / (RBF_STEP * RBF_STEP);

// ---------------- h = embed[r] ----------------
__global__ void embed_k(const int* __restrict__ r, const float* __restrict__ embed,
                        float* __restrict__ h, int N){
  int idx = blockIdx.x * blockDim.x + threadIdx.x;
  if (idx < N * 32){
    int n = idx >> 5, c = (idx & 31) * 4;
    *(float4*)&h[(size_t)n * NB + c] = *(const float4*)&embed[(size_t)r[n] * NB + c];
  }
}

// ---------------- per-edge distance ----------------
__global__ void dist_k(const int* __restrict__ a, const float* __restrict__ xyz,
                       float* __restrict__ d, int E){
  int e = blockIdx.x * blockDim.x + threadIdx.x;
  if (e < E){
    int i = a[2*e], j = a[2*e+1];
    float dx = xyz[3*i+0] - xyz[3*j+0];
    float dy = xyz[3*i+1] - xyz[3*j+1];
    float dz = xyz[3*i+2] - xyz[3*j+2];
    d[e] = sqrtf(dx*dx + dy*dy + dz*dz);
  }
}

// ================= CSR build =================
__global__ void hist_k(const int* __restrict__ a, int* __restrict__ cnt, int E){
  int e = blockIdx.x * blockDim.x + threadIdx.x;
  if (e < E){
    atomicAdd(&cnt[a[2*e]],   1);
    atomicAdd(&cnt[a[2*e+1]], 1);
  }
}

#define SCAN_TILE 512
__global__ void reduce_k(const int* __restrict__ cnt, int* __restrict__ bsum, int N){
  __shared__ int s[256];
  int b = blockIdx.x, t = threadIdx.x;
  int i0 = b*SCAN_TILE + t;
  int v = 0;
  if (i0 < N)       v += cnt[i0];
  if (i0+256 < N)   v += cnt[i0+256];
  s[t] = v; __syncthreads();
  for (int o=128;o>0;o>>=1){ if (t<o) s[t]+=s[t+o]; __syncthreads(); }
  if (t==0) bsum[b] = s[0];
}

__global__ void scanb_k(const int* __restrict__ bsum, int* __restrict__ boff, int nb){
  if (threadIdx.x==0 && blockIdx.x==0){
    int acc = 0;
    for (int i=0;i<nb;i++){ boff[i]=acc; acc+=bsum[i]; }
  }
}

__global__ void scan2_k(const int* __restrict__ cnt, const int* __restrict__ boff,
                        int* __restrict__ rowptr, int N, int total){
  __shared__ int s[256];
  int b = blockIdx.x, t = threadIdx.x;
  int i0 = b*SCAN_TILE;
  int a0 = (i0+2*t   < N) ? cnt[i0+2*t]   : 0;
  int a1 = (i0+2*t+1 < N) ? cnt[i0+2*t+1] : 0;
  int pair = a0 + a1;
  s[t] = pair; __syncthreads();
  for (int o=1;o<256;o<<=1){
    int v = (t>=o) ? s[t-o] : 0;
    __syncthreads();
    s[t] += v;
    __syncthreads();
  }
  int excl = s[t] - pair + boff[b];
  if (i0+2*t   < N) rowptr[i0+2*t]   = excl;
  if (i0+2*t+1 < N) rowptr[i0+2*t+1] = excl + a0;
  if (b==0 && t==0) rowptr[N] = total;
}

__global__ void copy_k(const int* __restrict__ src, int* __restrict__ dst, int n){
  int i = blockIdx.x*blockDim.x + threadIdx.x;
  if (i < n) dst[i] = src[i];
}

// visit list: adj[p] = (src, edge), tgtv[p] = target; grouped by target via cur[]
__global__ void fill_k(const int* __restrict__ a, int* __restrict__ cur,
                       int2* __restrict__ adj, int* __restrict__ tgtv, int E){
  int e = blockIdx.x*blockDim.x + threadIdx.x;
  if (e < E){
    int i = a[2*e], j = a[2*e+1];
    int p = atomicAdd(&cur[i], 1);
    adj[p] = make_int2(j, e);  tgtv[p] = i;
    int q = atomicAdd(&cur[j], 1);
    adj[q] = make_int2(i, e);  tgtv[q] = j;
  }
}

// ---------------- generic (N x 128) @ (128 x 128) + b, opt ssp, opt residual ----
template<int ACT, int RESID>
__launch_bounds__(128, 3)
__global__ void gemm128_k(const float* __restrict__ in, const float* __restrict__ W,
                          const float* __restrict__ bias, float* __restrict__ out, int N){
  __shared__ float As[32][64];
  __shared__ float Ws[32][128];
  int tid = threadIdx.x;
  int tc = tid & 15, tr = tid >> 4;
  int row0 = blockIdx.x * 64;
  int c0 = tc * 8;

  float bcol[8];
  {
    float4 b0 = *(const float4*)&bias[c0];
    float4 b1 = *(const float4*)&bias[c0+4];
    bcol[0]=b0.x; bcol[1]=b0.y; bcol[2]=b0.z; bcol[3]=b0.w;
    bcol[4]=b1.x; bcol[5]=b1.y; bcol[6]=b1.z; bcol[7]=b1.w;
  }
  float acc[8][8];
  #pragma unroll
  for (int r=0;r<8;r++)
    #pragma unroll
    for (int q=0;q<8;q++) acc[r][q] = bcol[q];

  for (int kc=0; kc<4; kc++){
    #pragma unroll
    for (int p=0;p<4;p++){
      int f = tid + 128*p;
      int rr = f >> 3, kq = f & 7;
      int grow = row0 + rr;
      float4 v = (grow < N) ? *(const float4*)&in[(size_t)grow*NB + kc*32 + kq*4]
                            : make_float4(0.f,0.f,0.f,0.f);
      As[kq*4+0][rr] = v.x; As[kq*4+1][rr] = v.y;
      As[kq*4+2][rr] = v.z; As[kq*4+3][rr] = v.w;
    }
    #pragma unroll
    for (int p=0;p<8;p++){
      int f = tid + 128*p;
      int wk = f >> 5, cq = f & 31;
      *(float4*)&Ws[wk][cq*4] = *(const float4*)&W[(size_t)(kc*32+wk)*NB + cq*4];
    }
    __syncthreads();
    #pragma unroll 4
    for (int k=0;k<32;k++){
      float4 a0 = *(const float4*)&As[k][tr*8];
      float4 a1 = *(const float4*)&As[k][tr*8+4];
      float4 w0 = *(const float4*)&Ws[k][c0];
      float4 w1 = *(const float4*)&Ws[k][c0+4];
      float av[8] = {a0.x,a0.y,a0.z,a0.w,a1.x,a1.y,a1.z,a1.w};
      float wv[8] = {w0.x,w0.y,w0.z,w0.w,w1.x,w1.y,w1.z,w1.w};
      #pragma unroll
      for (int r=0;r<8;r++)
        #pragma unroll
        for (int q=0;q<8;q++) acc[r][q] += av[r]*wv[q];
    }
    __syncthreads();
  }
  #pragma unroll
  for (int r=0;r<8;r++){
    int row = row0 + tr*8 + r;
    if (row < N){
      float v[8];
      #pragma unroll
      for (int q=0;q<8;q++) v[q] = (ACT==1) ? sspf(acc[r][q]) : acc[r][q];
      if (RESID){
        float4 o0 = *(const float4*)&out[(size_t)row*NB + c0];
        float4 o1 = *(const float4*)&out[(size_t)row*NB + c0+4];
        v[0]+=o0.x; v[1]+=o0.y; v[2]+=o0.z; v[3]+=o0.w;
        v[4]+=o1.x; v[5]+=o1.y; v[6]+=o1.z; v[7]+=o1.w;
      }
      *(float4*)&out[(size_t)row*NB + c0]   = make_float4(v[0],v[1],v[2],v[3]);
      *(float4*)&out[(size_t)row*NB + c0+4] = make_float4(v[4],v[5],v[6],v[7]);
    }
  }
}

// ---------------- visit_k: per directed visit (sorted by target) ------------
// ef = ssp(g@We1+be1)@We2+be2 (LDS-blocked), val = ef * nodef[src],
// segmented in-register reduce over sorted targets, atomicAdd per run-fragment.
__launch_bounds__(256, 2)
__global__ void visit_k(const float* __restrict__ dists,
                        const int2* __restrict__ adj, const int* __restrict__ tgtv,
                        const float* __restrict__ nodef,
                        const float* __restrict__ We1, const float* __restrict__ be1,
                        const float* __restrict__ We2, const float* __restrict__ be2,
                        float* __restrict__ agg, int V){
  __shared__ float We1s[NG][64];
  __shared__ float We2s[NG][NB];
  __shared__ float buf[NG][NB];     // g, then T (transposed: [k][visit])
  __shared__ float be1s[64], be2s[NB];
  __shared__ float ds_[NB];
  __shared__ int   srcs[NB], tgts[NB];
  int tid = threadIdx.x;

  for (int idx = tid; idx < NG*64; idx += 256){
    int m = idx >> 6, k = idx & 63;
    We1s[m][k] = (k < NG) ? We1[m*NG + k] : 0.f;
  }
  for (int idx = tid; idx < NG*NB; idx += 256)
    We2s[0][idx] = We2[idx];
  if (tid < 64)  be1s[tid] = (tid < NG) ? be1[tid] : 0.f;
  if (tid < NB)  be2s[tid] = be2[tid];

  int vbase = blockIdx.x * NB;
  if (tid < NB){
    int p = vbase + tid;
    if (p < V){
      int2 sv = adj[p];
      srcs[tid] = sv.x; tgts[tid] = tgtv[p];
      ds_[tid]  = dists[sv.y];
    } else {
      srcs[tid] = 0; tgts[tid] = -1; ds_[tid] = 0.f;
    }
  }
  __syncthreads();

  // g phase
  for (int idx = tid; idx < NG*NB; idx += 256){
    int m = idx >> 7, e = idx & 127;
    float t = ds_[e] - RBF_STEP * (float)m;
    buf[m][e] = __expf(RBF_COEFF * t * t);
  }
  __syncthreads();

  int te = tid >> 4, tk = tid & 15;
  int e0 = te * 8, k0 = tk * 4;

  // T phase
  float tacc[8][4];
  {
    float4 bv = *(const float4*)&be1s[k0];
    float bq[4] = {bv.x,bv.y,bv.z,bv.w};
    #pragma unroll
    for (int r=0;r<8;r++)
      #pragma unroll
      for (int q=0;q<4;q++) tacc[r][q] = bq[q];
  }
  #pragma unroll 2
  for (int m=0;m<NG;m++){
    float4 w  = *(const float4*)&We1s[m][k0];
    float4 g0 = *(const float4*)&buf[m][e0];
    float4 g1 = *(const float4*)&buf[m][e0+4];
    float ge[8] = {g0.x,g0.y,g0.z,g0.w,g1.x,g1.y,g1.z,g1.w};
    float wv[4] = {w.x,w.y,w.z,w.w};
    #pragma unroll
    for (int r=0;r<8;r++)
      #pragma unroll
      for (int q=0;q<4;q++) tacc[r][q] += ge[r]*wv[q];
  }
  __syncthreads();
  #pragma unroll
  for (int q=0;q<4;q++){
    int k = k0 + q;
    if (k < NG){
      float v[8];
      #pragma unroll
      for (int r=0;r<8;r++) v[r] = sspf(tacc[r][q]);
      *(float4*)&buf[k][e0]   = make_float4(v[0],v[1],v[2],v[3]);
      *(float4*)&buf[k][e0+4] = make_float4(v[4],v[5],v[6],v[7]);
    }
  }
  __syncthreads();

  // EF phase
  int c0 = tk * 8;
  float acc[8][8];
  {
    float4 b0 = *(const float4*)&be2s[c0];
    float4 b1 = *(const float4*)&be2s[c0+4];
    float bq[8] = {b0.x,b0.y,b0.z,b0.w,b1.x,b1.y,b1.z,b1.w};
    #pragma unroll
    for (int r=0;r<8;r++)
      #pragma unroll
      for (int q=0;q<8;q++) acc[r][q] = bq[q];
  }
  #pragma unroll 2
  for (int k=0;k<NG;k++){
    float4 w0 = *(const float4*)&We2s[k][c0];
    float4 w1 = *(const float4*)&We2s[k][c0+4];
    float4 t0 = *(const float4*)&buf[k][e0];
    float4 t1 = *(const float4*)&buf[k][e0+4];
    float tv[8] = {t0.x,t0.y,t0.z,t0.w,t1.x,t1.y,t1.z,t1.w};
    float wv[8] = {w0.x,w0.y,w0.z,w0.w,w1.x,w1.y,w1.z,w1.w};
    #pragma unroll
    for (int r=0;r<8;r++)
      #pragma unroll
      for (int q=0;q<8;q++) acc[r][q] += tv[r]*wv[q];
  }

  // val = ef * nodef[src]; segmented reduce over sorted tgts; atomic per fragment
  int   curtgt = tgts[e0];
  float run[8];
  #pragma unroll
  for (int q=0;q<8;q++) run[q] = 0.f;
  #pragma unroll
  for (int r=0;r<8;r++){
    int t = tgts[e0+r];
    int s = srcs[e0+r];
    float4 n0 = *(const float4*)&nodef[(size_t)s*NB + c0];
    float4 n1 = *(const float4*)&nodef[(size_t)s*NB + c0+4];
    float nv[8] = {n0.x,n0.y,n0.z,n0.w,n1.x,n1.y,n1.z,n1.w};
    if (t != curtgt){
      if (curtgt >= 0){
        float* ap = &agg[(size_t)curtgt*NB + c0];
        #pragma unroll
        for (int q=0;q<8;q++) atomicAdd(ap+q, run[q]);
      }
      curtgt = t;
      #pragma unroll
      for (int q=0;q<8;q++) run[q] = 0.f;
    }
    if (t >= 0){
      #pragma unroll
      for (int q=0;q<8;q++) run[q] += acc[r][q] * nv[q];
    }
  }
  if (curtgt >= 0){
    float* ap = &agg[(size_t)curtgt*NB + c0];
    #pragma unroll
    for (int q=0;q<8;q++) atomicAdd(ap+q, run[q]);
  }
}

// ---------------- legacy atomic edge kernel (ws fallback) --------------------
__launch_bounds__(256, 2)
__global__ void edge_k(const float* __restrict__ dists, const int* __restrict__ a,
                       const float* __restrict__ nodef,
                       const float* __restrict__ We1, const float* __restrict__ be1,
                       const float* __restrict__ We2, const float* __restrict__ be2,
                       float* __restrict__ agg, int E){
  __shared__ float We1s[NG][64];
  __shared__ float We2s[NG][NB];
  __shared__ float buf[NG][NB];
  __shared__ float be1s[64], be2s[NB];
  __shared__ float ds_[NB];
  __shared__ int   ijs[2*NB];
  int tid = threadIdx.x;

  for (int idx = tid; idx < NG*64; idx += 256){
    int m = idx >> 6, k = idx & 63;
    We1s[m][k] = (k < NG) ? We1[m*NG + k] : 0.f;
  }
  for (int idx = tid; idx < NG*NB; idx += 256)
    We2s[0][idx] = We2[idx];
  if (tid < 64)  be1s[tid] = (tid < NG) ? be1[tid] : 0.f;
  if (tid < NB)  be2s[tid] = be2[tid];

  int ebase = blockIdx.x * NB;
  if (tid < NB){
    int e = ebase + tid;
    if (e < E){ ds_[tid] = dists[e]; ijs[2*tid] = a[2*e]; ijs[2*tid+1] = a[2*e+1]; }
    else      { ds_[tid] = 0.f;      ijs[2*tid] = -1;     ijs[2*tid+1] = -1; }
  }
  __syncthreads();
  for (int idx = tid; idx < NG*NB; idx += 256){
    int m = idx >> 7, e = idx & 127;
    float t = ds_[e] - RBF_STEP * (float)m;
    buf[m][e] = __expf(RBF_COEFF * t * t);
  }
  __syncthreads();
  int te = tid >> 4, tk = tid & 15;
  int e0 = te * 8, k0 = tk * 4;
  float tacc[8][4];
  {
    float4 bv = *(const float4*)&be1s[k0];
    float bq[4] = {bv.x,bv.y,bv.z,bv.w};
    #pragma unroll
    for (int r=0;r<8;r++)
      #pragma unroll
      for (int q=0;q<4;q++) tacc[r][q] = bq[q];
  }
  #pragma unroll 2
  for (int m=0;m<NG;m++){
    float4 w  = *(const float4*)&We1s[m][k0];
    float4 g0 = *(const float4*)&buf[m][e0];
    float4 g1 = *(const float4*)&buf[m][e0+4];
    float ge[8] = {g0.x,g0.y,g0.z,g0.w,g1.x,g1.y,g1.z,g1.w};
    float wv[4] = {w.x,w.y,w.z,w.w};
    #pragma unroll
    for (int r=0;r<8;r++)
      #pragma unroll
      for (int q=0;q<4;q++) tacc[r][q] += ge[r]*wv[q];
  }
  __syncthreads();
  #pragma unroll
  for (int q=0;q<4;q++){
    int k = k0 + q;
    if (k < NG){
      float v[8];
      #pragma unroll
      for (int r=0;r<8;r++) v[r] = sspf(tacc[r][q]);
      *(float4*)&buf[k][e0]   = make_float4(v[0],v[1],v[2],v[3]);
      *(float4*)&buf[k][e0+4] = make_float4(v[4],v[5],v[6],v[7]);
    }
  }
  __syncthreads();
  int c0 = tk * 8;
  float acc[8][8];
  {
    float4 b0 = *(const float4*)&be2s[c0];
    float4 b1 = *(const float4*)&be2s[c0+4];
    float bq[8] = {b0.x,b0.y,b0.z,b0.w,b1.x,b1.y,b1.z,b1.w};
    #pragma unroll
    for (int r=0;r<8;r++)
      #pragma unroll
      for (int q=0;q<8;q++) acc[r][q] = bq[q];
  }
  #pragma unroll 2
  for (int k=0;k<NG;k++){
    float4 w0 = *(const float4*)&We2s[k][c0];
    float4 w1 = *(const float4*)&We2s[k][c0+4];
    float4 t0 = *(const float4*)&buf[k][e0];
    float4 t1 = *(const float4*)&buf[k][e0+4];
    float tv[8] = {t0.x,t0.y,t0.z,t0.w,t1.x,t1.y,t1.z,t1.w};
    float wv[8] = {w0.x,w0.y,w0.z,w0.w,w1.x,w1.y,w1.z,w1.w};
    #pragma unroll
    for (int r=0;r<8;r++)
      #pragma unroll
      for (int q=0;q<8;q++) acc[r][q] += tv[r]*wv[q];
  }
  #pragma unroll
  for (int r=0;r<8;r++){
    int el = e0 + r;
    int i = ijs[2*el], j = ijs[2*el+1];
    if (i < 0) continue;
    float4 nj0 = *(const float4*)&nodef[(size_t)j*NB + c0];
    float4 nj1 = *(const float4*)&nodef[(size_t)j*NB + c0+4];
    float4 ni0 = *(const float4*)&nodef[(size_t)i*NB + c0];
    float4 ni1 = *(const float4*)&nodef[(size_t)i*NB + c0+4];
    float* ai = &agg[(size_t)i*NB + c0];
    float* aj = &agg[(size_t)j*NB + c0];
    float njv[8] = {nj0.x,nj0.y,nj0.z,nj0.w,nj1.x,nj1.y,nj1.z,nj1.w};
    float niv[8] = {ni0.x,ni0.y,ni0.z,ni0.w,ni1.x,ni1.y,ni1.z,ni1.w};
    #pragma unroll
    for (int q=0;q<8;q++){
      atomicAdd(ai+q, njv[q]*acc[r][q]);
      atomicAdd(aj+q, niv[q]*acc[r][q]);
    }
  }
}

// ---------------- readout: e = ssp(h@W1+b1)@W2+b2, molecule segment sum ------
__launch_bounds__(128, 3)
__global__ void readout_k(const float* __restrict__ h, const float* __restrict__ W1,
                          const float* __restrict__ b1, const float* __restrict__ W2,
                          const float* __restrict__ b2, const int* __restrict__ molp,
                          float* __restrict__ out, int N){
  __shared__ float As[32][64];
  __shared__ float W1s[32][64];
  __shared__ float segsum[2];
  int tid = threadIdx.x;
  int tc = tid & 15, tr = tid >> 4;
  int row0 = blockIdx.x * 64;
  int c0 = tc * 4;

  float acc[8][4];
  {
    float4 bv = *(const float4*)&b1[c0];
    float bq[4] = {bv.x,bv.y,bv.z,bv.w};
    #pragma unroll
    for (int r=0;r<8;r++)
      #pragma unroll
      for (int q=0;q<4;q++) acc[r][q] = bq[q];
  }
  for (int kc=0;kc<4;kc++){
    #pragma unroll
    for (int p=0;p<4;p++){
      int f = tid + 128*p; int rr = f >> 3; int kq = f & 7;
      int grow = row0 + rr;
      float4 v = (grow < N) ? *(const float4*)&h[(size_t)grow*NB + kc*32 + kq*4]
                            : make_float4(0.f,0.f,0.f,0.f);
      As[kq*4+0][rr] = v.x; As[kq*4+1][rr] = v.y;
      As[kq*4+2][rr] = v.z; As[kq*4+3][rr] = v.w;
    }
    #pragma unroll
    for (int p=0;p<4;p++){
      int f = tid + 128*p; int wk = f >> 4; int cq = f & 15;
      *(float4*)&W1s[wk][cq*4] = *(const float4*)&W1[(size_t)(kc*32+wk)*64 + cq*4];
    }
    __syncthreads();
    #pragma unroll 4
    for (int k=0;k<32;k++){
      float4 a0 = *(const float4*)&As[k][tr*8];
      float4 a1 = *(const float4*)&As[k][tr*8+4];
      float4 w  = *(const float4*)&W1s[k][c0];
      float av[8] = {a0.x,a0.y,a0.z,a0.w,a1.x,a1.y,a1.z,a1.w};
      float wv[4] = {w.x,w.y,w.z,w.w};
      #pragma unroll
      for (int r=0;r<8;r++)
        #pragma unroll
        for (int q=0;q<4;q++) acc[r][q] += av[r]*wv[q];
    }
    __syncthreads();
  }
  float4 w2f = *(const float4*)&W2[c0];
  float part[8];
  #pragma unroll
  for (int r=0;r<8;r++)
    part[r] = sspf(acc[r][0])*w2f.x + sspf(acc[r][1])*w2f.y +
              sspf(acc[r][2])*w2f.z + sspf(acc[r][3])*w2f.w;
  #pragma unroll
  for (int off=1; off<16; off<<=1)
    #pragma unroll
    for (int r=0;r<8;r++) part[r] += __shfl_xor(part[r], off);

  if (tid < 2) segsum[tid] = 0.f;
  __syncthreads();
  int ms = molp[0];
  float b2v = b2[0];
  int seg0 = row0 / ms;
  if (tc == 0){
    #pragma unroll
    for (int r=0;r<8;r++){
      int row = row0 + tr*8 + r;
      if (row < N){
        int s = row/ms - seg0;
        if (s < 2) atomicAdd(&segsum[s], part[r] + b2v);
        else       atomicAdd(&out[row/ms], part[r] + b2v);
      }
    }
  }
  __syncthreads();
  if (tid == 0 && segsum[0] != 0.f) atomicAdd(&out[seg0], segsum[0]);
  if (tid == 1){
    int lastrow = row0 + 63; if (lastrow > N-1) lastrow = N-1;
    if (lastrow/ms > seg0 && segsum[1] != 0.f) atomicAdd(&out[seg0+1], segsum[1]);
  }
}

extern "C" void kernel_launch(void* const* d_in, const int* in_sizes, int n_in,
                              void* d_out, int out_size, void* d_ws, size_t ws_size,
                              hipStream_t stream){
  const int*   r     = (const int*)  d_in[0];
  const float* xyz   = (const float*)d_in[1];
  const int*   a     = (const int*)  d_in[2];
  const int*   molp  = (const int*)  d_in[3];
  const float* embed = (const float*)d_in[4];
  const float* Wn    = (const float*)d_in[5];
  const float* bn    = (const float*)d_in[6];
  const float* We1   = (const float*)d_in[7];
  const float* be1   = (const float*)d_in[8];
  const float* We2   = (const float*)d_in[9];
  const float* be2   = (const float*)d_in[10];
  const float* Wu1   = (const float*)d_in[11];
  const float* bu1   = (const float*)d_in[12];
  const float* Wu2   = (const float*)d_in[13];
  const float* bu2   = (const float*)d_in[14];
  const float* W1    = (const float*)d_in[15];
  const float* b1    = (const float*)d_in[16];
  const float* W2    = (const float*)d_in[17];
  const float* b2    = (const float*)d_in[18];

  int N = in_sizes[0];          // 50000
  int E = in_sizes[2] / 2;      // 500000
  int V = 2*E;                  // directed visits

  float* ws   = (float*)d_ws;
  size_t E4   = ((size_t)E + 3) & ~(size_t)3;
  size_t NSZ  = (size_t)N * NB;
  size_t RPAD = ((size_t)N + 1 + 3) & ~(size_t)3;
  size_t NPAD = ((size_t)N + 3) & ~(size_t)3;

  // modeB layout: dbuf | h | nodef | agg | ints{rowptr,cnt,cur,bsum,boff, adj(int2), tgtv}
  size_t int_base  = E4 + 3*NSZ;
  size_t int_elems = RPAD + 2*NPAD + 512 + 2*(size_t)V + (size_t)V;
  size_t needB = (int_base + int_elems) * sizeof(float);
  bool modeB = ws_size >= needB;

  float* dbuf = ws;
  float* h    = dbuf + E4;
  float* nodef= h + NSZ;
  float* agg  = nodef + NSZ;

  int gblocks = (N + 63)/64;
  int eblocks = (E + 127)/128;

  embed_k<<<(N*32 + 255)/256, 256, 0, stream>>>(r, embed, h, N);
  dist_k <<<(E + 255)/256,    256, 0, stream>>>(a, xyz, dbuf, E);

  if (modeB){
    int* ibase  = (int*)(agg + NSZ);
    int* rowptr = ibase;
    int* cnt    = rowptr + RPAD;
    int* cur    = cnt + NPAD;
    int* bsum   = cur + NPAD;
    int* boff   = bsum + 256;
    int2* adj   = (int2*)(boff + 256);      // 8B-aligned: even float offset
    int* tgtv   = (int*)(adj + V);

    int nb = (N + SCAN_TILE - 1) / SCAN_TILE;
    hipMemsetAsync(cnt, 0, (size_t)N*sizeof(int), stream);
    hist_k  <<<(E + 255)/256, 256, 0, stream>>>(a, cnt, E);
    reduce_k<<<nb, 256, 0, stream>>>(cnt, bsum, N);
    scanb_k <<<1, 64, 0, stream>>>(bsum, boff, nb);
    scan2_k <<<nb, 256, 0, stream>>>(cnt, boff, rowptr, N, V);
    copy_k  <<<(N + 255)/256, 256, 0, stream>>>(rowptr, cur, N);
    fill_k  <<<(E + 255)/256, 256, 0, stream>>>(a, cur, adj, tgtv, E);

    int vblocks = (V + 127)/128;
    for (int l = 0; l < 3; l++){
      gemm128_k<0,0><<<gblocks, 128, 0, stream>>>(h, Wn + (size_t)l*NB*NB, bn + l*NB, nodef, N);
      hipMemsetAsync(agg, 0, NSZ*sizeof(float), stream);
      visit_k<<<vblocks, 256, 0, stream>>>(dbuf, adj, tgtv, nodef,
                                           We1 + (size_t)l*NG*NG, be1 + l*NG,
                                           We2 + (size_t)l*NG*NB, be2 + l*NB, agg, V);
      gemm128_k<1,0><<<gblocks, 128, 0, stream>>>(agg,   Wu1 + (size_t)l*NB*NB, bu1 + l*NB, nodef, N);
      gemm128_k<0,1><<<gblocks, 128, 0, stream>>>(nodef, Wu2 + (size_t)l*NB*NB, bu2 + l*NB, h, N);
    }
  } else {
    for (int l = 0; l < 3; l++){
      gemm128_k<0,0><<<gblocks, 128, 0, stream>>>(h, Wn + (size_t)l*NB*NB, bn + l*NB, nodef, N);
      hipMemsetAsync(agg, 0, NSZ*sizeof(float), stream);
      edge_k<<<eblocks, 256, 0, stream>>>(dbuf, a, nodef,
                                          We1 + (size_t)l*NG*NG, be1 + l*NG,
                                          We2 + (size_t)l*NG*NB, be2 + l*NB, agg, E);
      gemm128_k<1,0><<<gblocks, 128, 0, stream>>>(agg,   Wu1 + (size_t)l*NB*NB, bu1 + l*NB, nodef, N);
      gemm128_k<0,1><<<gblocks, 128, 0, stream>>>(nodef, Wu2 + (size_t)l*NB*NB, bu2 + l*NB, h, N);
    }
  }

  hipMemsetAsync(d_out, 0, (size_t)out_size*sizeof(float), stream);
  readout_k<<<gblocks, 128, 0, stream>>>(h, W1, b1, W2, b2, molp, (float*)d_out, N);
}

// Round 8
// 1722.521 us; speedup vs baseline: 6.2594x; 1.6503x over previous
//
#include <hip/hip_runtime.h>
#include <hip/hip_bf16.h>

#define NG 50
#define NB 128

__device__ __forceinline__ float sspf(float x){
  float t = __expf(-fabsf(x));
  return fmaxf(x, 0.f) + __logf(1.f + t) - 0.6931471805599453094f;
}

constexpr float RBF_STEP  = 5.0f / 49.0f;
constexpr float RBF_COEFF = -0.5f / (RBF_STEP * RBF_STEP);

// ---------------- h = embed[r] ----------------
__global__ void embed_k(const int* __restrict__ r, const float* __restrict__ embed,
                        float* __restrict__ h, int N){
  int idx = blockIdx.x * blockDim.x + threadIdx.x;
  if (idx < N * 32){
    int n = idx >> 5, c = (idx & 31) * 4;
    *(float4*)&h[(size_t)n * NB + c] = *(const float4*)&embed[(size_t)r[n] * NB + c];
  }
}

// ---------------- per-edge distance ----------------
__global__ void dist_k(const int* __restrict__ a, const float* __restrict__ xyz,
                       float* __restrict__ d, int E){
  int e = blockIdx.x * blockDim.x + threadIdx.x;
  if (e < E){
    int i = a[2*e], j = a[2*e+1];
    float dx = xyz[3*i+0] - xyz[3*j+0];
    float dy = xyz[3*i+1] - xyz[3*j+1];
    float dz = xyz[3*i+2] - xyz[3*j+2];
    d[e] = sqrtf(dx*dx + dy*dy + dz*dz);
  }
}

// ================= CSR build =================
__global__ void hist_k(const int* __restrict__ a, int* __restrict__ cnt, int E){
  int e = blockIdx.x * blockDim.x + threadIdx.x;
  if (e < E){
    atomicAdd(&cnt[a[2*e]],   1);
    atomicAdd(&cnt[a[2*e+1]], 1);
  }
}

__global__ void pad_k(const int* __restrict__ cnt, int* __restrict__ pcnt, int N){
  int i = blockIdx.x*blockDim.x + threadIdx.x;
  if (i < N) pcnt[i] = (cnt[i] + 7) & ~7;
}

#define SCAN_TILE 512
__global__ void reduce_k(const int* __restrict__ cnt, int* __restrict__ bsum, int N){
  __shared__ int s[256];
  int b = blockIdx.x, t = threadIdx.x;
  int i0 = b*SCAN_TILE + t;
  int v = 0;
  if (i0 < N)       v += cnt[i0];
  if (i0+256 < N)   v += cnt[i0+256];
  s[t] = v; __syncthreads();
  for (int o=128;o>0;o>>=1){ if (t<o) s[t]+=s[t+o]; __syncthreads(); }
  if (t==0) bsum[b] = s[0];
}

__global__ void scanb_k(const int* __restrict__ bsum, int* __restrict__ boff, int nb){
  if (threadIdx.x==0 && blockIdx.x==0){
    int acc = 0;
    for (int i=0;i<nb;i++){ boff[i]=acc; acc+=bsum[i]; }
  }
}

__global__ void scan2_k(const int* __restrict__ cnt, const int* __restrict__ boff,
                        int* __restrict__ rowptr, int N, int total){
  __shared__ int s[256];
  int b = blockIdx.x, t = threadIdx.x;
  int i0 = b*SCAN_TILE;
  int a0 = (i0+2*t   < N) ? cnt[i0+2*t]   : 0;
  int a1 = (i0+2*t+1 < N) ? cnt[i0+2*t+1] : 0;
  int pair = a0 + a1;
  s[t] = pair; __syncthreads();
  for (int o=1;o<256;o<<=1){
    int v = (t>=o) ? s[t-o] : 0;
    __syncthreads();
    s[t] += v;
    __syncthreads();
  }
  int excl = s[t] - pair + boff[b];
  if (i0+2*t   < N) rowptr[i0+2*t]   = excl;
  if (i0+2*t+1 < N) rowptr[i0+2*t+1] = excl + a0;
  if (b==0 && t==0) rowptr[N] = total;
}

__global__ void copy_k(const int* __restrict__ src, int* __restrict__ dst, int n){
  int i = blockIdx.x*blockDim.x + threadIdx.x;
  if (i < n) dst[i] = src[i];
}

// visit list (SoA): asrc[p]=source node, aedg[p]=edge id, tgtv[p]=target node
__global__ void fill_k(const int* __restrict__ a, int* __restrict__ cur,
                       int* __restrict__ asrc, int* __restrict__ aedg,
                       int* __restrict__ tgtv, int E){
  int e = blockIdx.x*blockDim.x + threadIdx.x;
  if (e < E){
    int i = a[2*e], j = a[2*e+1];
    int p = atomicAdd(&cur[i], 1);
    asrc[p] = j; aedg[p] = e; tgtv[p] = i;
    int q = atomicAdd(&cur[j], 1);
    asrc[q] = i; aedg[q] = e; tgtv[q] = j;
  }
}

// ---------------- generic (N x 128) @ (128 x 128) + b, opt ssp, opt residual ----
template<int ACT, int RESID>
__launch_bounds__(128, 3)
__global__ void gemm128_k(const float* __restrict__ in, const float* __restrict__ W,
                          const float* __restrict__ bias, float* __restrict__ out, int N){
  __shared__ float As[32][64];
  __shared__ float Ws[32][128];
  int tid = threadIdx.x;
  int tc = tid & 15, tr = tid >> 4;
  int row0 = blockIdx.x * 64;
  int c0 = tc * 8;

  float bcol[8];
  {
    float4 b0 = *(const float4*)&bias[c0];
    float4 b1 = *(const float4*)&bias[c0+4];
    bcol[0]=b0.x; bcol[1]=b0.y; bcol[2]=b0.z; bcol[3]=b0.w;
    bcol[4]=b1.x; bcol[5]=b1.y; bcol[6]=b1.z; bcol[7]=b1.w;
  }
  float acc[8][8];
  #pragma unroll
  for (int r=0;r<8;r++)
    #pragma unroll
    for (int q=0;q<8;q++) acc[r][q] = bcol[q];

  for (int kc=0; kc<4; kc++){
    #pragma unroll
    for (int p=0;p<4;p++){
      int f = tid + 128*p;
      int rr = f >> 3, kq = f & 7;
      int grow = row0 + rr;
      float4 v = (grow < N) ? *(const float4*)&in[(size_t)grow*NB + kc*32 + kq*4]
                            : make_float4(0.f,0.f,0.f,0.f);
      As[kq*4+0][rr] = v.x; As[kq*4+1][rr] = v.y;
      As[kq*4+2][rr] = v.z; As[kq*4+3][rr] = v.w;
    }
    #pragma unroll
    for (int p=0;p<8;p++){
      int f = tid + 128*p;
      int wk = f >> 5, cq = f & 31;
      *(float4*)&Ws[wk][cq*4] = *(const float4*)&W[(size_t)(kc*32+wk)*NB + cq*4];
    }
    __syncthreads();
    #pragma unroll 4
    for (int k=0;k<32;k++){
      float4 a0 = *(const float4*)&As[k][tr*8];
      float4 a1 = *(const float4*)&As[k][tr*8+4];
      float4 w0 = *(const float4*)&Ws[k][c0];
      float4 w1 = *(const float4*)&Ws[k][c0+4];
      float av[8] = {a0.x,a0.y,a0.z,a0.w,a1.x,a1.y,a1.z,a1.w};
      float wv[8] = {w0.x,w0.y,w0.z,w0.w,w1.x,w1.y,w1.z,w1.w};
      #pragma unroll
      for (int r=0;r<8;r++)
        #pragma unroll
        for (int q=0;q<8;q++) acc[r][q] += av[r]*wv[q];
    }
    __syncthreads();
  }
  #pragma unroll
  for (int r=0;r<8;r++){
    int row = row0 + tr*8 + r;
    if (row < N){
      float v[8];
      #pragma unroll
      for (int q=0;q<8;q++) v[q] = (ACT==1) ? sspf(acc[r][q]) : acc[r][q];
      if (RESID){
        float4 o0 = *(const float4*)&out[(size_t)row*NB + c0];
        float4 o1 = *(const float4*)&out[(size_t)row*NB + c0+4];
        v[0]+=o0.x; v[1]+=o0.y; v[2]+=o0.z; v[3]+=o0.w;
        v[4]+=o1.x; v[5]+=o1.y; v[6]+=o1.z; v[7]+=o1.w;
      }
      *(float4*)&out[(size_t)row*NB + c0]   = make_float4(v[0],v[1],v[2],v[3]);
      *(float4*)&out[(size_t)row*NB + c0+4] = make_float4(v[4],v[5],v[6],v[7]);
    }
  }
}

// ---------------- visit2_k: 8-aligned runs, LDS block reduce, plain stores ---
// Each 8-visit group belongs to exactly ONE target (runs padded to 8).
// Interior targets (run fully inside block): plain float4 store.
// Border targets (first/last run of block): atomicAdd.
__launch_bounds__(256, 2)
__global__ void visit2_k(const float* __restrict__ dists,
                         const int* __restrict__ asrc, const int* __restrict__ aedg,
                         const int* __restrict__ tgtv,
                         const float* __restrict__ nodef,
                         const float* __restrict__ We1, const float* __restrict__ be1,
                         const float* __restrict__ We2, const float* __restrict__ be2,
                         float* __restrict__ agg, int Vmax){
  __shared__ float We1s[NG][64];
  __shared__ float We2s[NG][NB];
  __shared__ float buf[NG][NB];     // g -> T -> part[16][NB]
  __shared__ float be1s[64], be2s[NB];
  __shared__ float ds_[NB];
  __shared__ int   srcs[NB], tgts[NB];
  __shared__ int   tgt8[16];
  int tid = threadIdx.x;

  int vbase = blockIdx.x * NB;
  if (tid < NB){
    int p = vbase + tid;
    if (p < Vmax){
      srcs[tid] = asrc[p]; tgts[tid] = tgtv[p];
      ds_[tid]  = dists[aedg[p]];
    } else {
      srcs[tid] = 0; tgts[tid] = -1; ds_[tid] = 0.f;
    }
  }
  __syncthreads();
  if (tgts[0] < 0) return;          // fully-padded trailing block (uniform)

  for (int idx = tid; idx < NG*64; idx += 256){
    int m = idx >> 6, k = idx & 63;
    We1s[m][k] = (k < NG) ? We1[m*NG + k] : 0.f;
  }
  for (int idx = tid; idx < NG*NB; idx += 256)
    We2s[0][idx] = We2[idx];
  if (tid < 64)  be1s[tid] = (tid < NG) ? be1[tid] : 0.f;
  if (tid < NB)  be2s[tid] = be2[tid];
  if (tid < 16)  tgt8[tid] = tgts[tid*8];

  // g phase
  for (int idx = tid; idx < NG*NB; idx += 256){
    int m = idx >> 7, e = idx & 127;
    float t = ds_[e] - RBF_STEP * (float)m;
    buf[m][e] = __expf(RBF_COEFF * t * t);
  }
  __syncthreads();

  int te = tid >> 4, tk = tid & 15;
  int e0 = te * 8, k0 = tk * 4;

  // T phase
  float tacc[8][4];
  {
    float4 bv = *(const float4*)&be1s[k0];
    float bq[4] = {bv.x,bv.y,bv.z,bv.w};
    #pragma unroll
    for (int r=0;r<8;r++)
      #pragma unroll
      for (int q=0;q<4;q++) tacc[r][q] = bq[q];
  }
  #pragma unroll 2
  for (int m=0;m<NG;m++){
    float4 w  = *(const float4*)&We1s[m][k0];
    float4 g0 = *(const float4*)&buf[m][e0];
    float4 g1 = *(const float4*)&buf[m][e0+4];
    float ge[8] = {g0.x,g0.y,g0.z,g0.w,g1.x,g1.y,g1.z,g1.w};
    float wv[4] = {w.x,w.y,w.z,w.w};
    #pragma unroll
    for (int r=0;r<8;r++)
      #pragma unroll
      for (int q=0;q<4;q++) tacc[r][q] += ge[r]*wv[q];
  }
  __syncthreads();
  #pragma unroll
  for (int q=0;q<4;q++){
    int k = k0 + q;
    if (k < NG){
      float v[8];
      #pragma unroll
      for (int r=0;r<8;r++) v[r] = sspf(tacc[r][q]);
      *(float4*)&buf[k][e0]   = make_float4(v[0],v[1],v[2],v[3]);
      *(float4*)&buf[k][e0+4] = make_float4(v[4],v[5],v[6],v[7]);
    }
  }
  __syncthreads();

  // EF phase
  int c0 = tk * 8;
  float acc[8][8];
  {
    float4 b0 = *(const float4*)&be2s[c0];
    float4 b1 = *(const float4*)&be2s[c0+4];
    float bq[8] = {b0.x,b0.y,b0.z,b0.w,b1.x,b1.y,b1.z,b1.w};
    #pragma unroll
    for (int r=0;r<8;r++)
      #pragma unroll
      for (int q=0;q<8;q++) acc[r][q] = bq[q];
  }
  #pragma unroll 2
  for (int k=0;k<NG;k++){
    float4 w0 = *(const float4*)&We2s[k][c0];
    float4 w1 = *(const float4*)&We2s[k][c0+4];
    float4 t0 = *(const float4*)&buf[k][e0];
    float4 t1 = *(const float4*)&buf[k][e0+4];
    float tv[8] = {t0.x,t0.y,t0.z,t0.w,t1.x,t1.y,t1.z,t1.w};
    float wv[8] = {w0.x,w0.y,w0.z,w0.w,w1.x,w1.y,w1.z,w1.w};
    #pragma unroll
    for (int r=0;r<8;r++)
      #pragma unroll
      for (int q=0;q<8;q++) acc[r][q] += tv[r]*wv[q];
  }
  __syncthreads();   // buf reads done; reuse as part[16][NB]

  // group accumulate: all 8 visits in this group share one target (8-aligned)
  float run[8];
  #pragma unroll
  for (int q=0;q<8;q++) run[q] = 0.f;
  #pragma unroll
  for (int r=0;r<8;r++){
    int t = tgts[e0+r];
    int s = srcs[e0+r];
    float4 n0 = *(const float4*)&nodef[(size_t)s*NB + c0];
    float4 n1 = *(const float4*)&nodef[(size_t)s*NB + c0+4];
    float nv[8] = {n0.x,n0.y,n0.z,n0.w,n1.x,n1.y,n1.z,n1.w};
    if (t >= 0){
      #pragma unroll
      for (int q=0;q<8;q++) run[q] += acc[r][q] * nv[q];
    }
  }
  float* part = &buf[0][0];         // part[g][ch] = buf row g
  #pragma unroll
  for (int q=0;q<8;q++) part[te*NB + c0 + q] = run[q];
  __syncthreads();

  // leaders: sum consecutive groups with same target; store/atomic
  int g = te;
  int t = tgt8[g];
  if (t >= 0 && (g == 0 || tgt8[g-1] != t)){
    int gend = g;
    while (gend+1 < 16 && tgt8[gend+1] == t) gend++;
    float s[8];
    #pragma unroll
    for (int q=0;q<8;q++) s[q] = 0.f;
    for (int g2=g; g2<=gend; ++g2)
      #pragma unroll
      for (int q=0;q<8;q++) s[q] += part[g2*NB + c0 + q];
    float* ap = &agg[(size_t)t*NB + c0];
    bool border = (g == 0) || (gend == 15);
    if (border){
      #pragma unroll
      for (int q=0;q<8;q++) atomicAdd(ap+q, s[q]);
    } else {
      *(float4*)ap     = make_float4(s[0],s[1],s[2],s[3]);
      *(float4*)(ap+4) = make_float4(s[4],s[5],s[6],s[7]);
    }
  }
}

// ---------------- visit_k (tier-2 fallback): fragment atomics ----------------
__launch_bounds__(256, 2)
__global__ void visit_k(const float* __restrict__ dists,
                        const int* __restrict__ asrc, const int* __restrict__ aedg,
                        const int* __restrict__ tgtv,
                        const float* __restrict__ nodef,
                        const float* __restrict__ We1, const float* __restrict__ be1,
                        const float* __restrict__ We2, const float* __restrict__ be2,
                        float* __restrict__ agg, int V){
  __shared__ float We1s[NG][64];
  __shared__ float We2s[NG][NB];
  __shared__ float buf[NG][NB];
  __shared__ float be1s[64], be2s[NB];
  __shared__ float ds_[NB];
  __shared__ int   srcs[NB], tgts[NB];
  int tid = threadIdx.x;

  for (int idx = tid; idx < NG*64; idx += 256){
    int m = idx >> 6, k = idx & 63;
    We1s[m][k] = (k < NG) ? We1[m*NG + k] : 0.f;
  }
  for (int idx = tid; idx < NG*NB; idx += 256)
    We2s[0][idx] = We2[idx];
  if (tid < 64)  be1s[tid] = (tid < NG) ? be1[tid] : 0.f;
  if (tid < NB)  be2s[tid] = be2[tid];

  int vbase = blockIdx.x * NB;
  if (tid < NB){
    int p = vbase + tid;
    if (p < V){
      srcs[tid] = asrc[p]; tgts[tid] = tgtv[p];
      ds_[tid]  = dists[aedg[p]];
    } else {
      srcs[tid] = 0; tgts[tid] = -1; ds_[tid] = 0.f;
    }
  }
  __syncthreads();
  for (int idx = tid; idx < NG*NB; idx += 256){
    int m = idx >> 7, e = idx & 127;
    float t = ds_[e] - RBF_STEP * (float)m;
    buf[m][e] = __expf(RBF_COEFF * t * t);
  }
  __syncthreads();
  int te = tid >> 4, tk = tid & 15;
  int e0 = te * 8, k0 = tk * 4;
  float tacc[8][4];
  {
    float4 bv = *(const float4*)&be1s[k0];
    float bq[4] = {bv.x,bv.y,bv.z,bv.w};
    #pragma unroll
    for (int r=0;r<8;r++)
      #pragma unroll
      for (int q=0;q<4;q++) tacc[r][q] = bq[q];
  }
  #pragma unroll 2
  for (int m=0;m<NG;m++){
    float4 w  = *(const float4*)&We1s[m][k0];
    float4 g0 = *(const float4*)&buf[m][e0];
    float4 g1 = *(const float4*)&buf[m][e0+4];
    float ge[8] = {g0.x,g0.y,g0.z,g0.w,g1.x,g1.y,g1.z,g1.w};
    float wv[4] = {w.x,w.y,w.z,w.w};
    #pragma unroll
    for (int r=0;r<8;r++)
      #pragma unroll
      for (int q=0;q<4;q++) tacc[r][q] += ge[r]*wv[q];
  }
  __syncthreads();
  #pragma unroll
  for (int q=0;q<4;q++){
    int k = k0 + q;
    if (k < NG){
      float v[8];
      #pragma unroll
      for (int r=0;r<8;r++) v[r] = sspf(tacc[r][q]);
      *(float4*)&buf[k][e0]   = make_float4(v[0],v[1],v[2],v[3]);
      *(float4*)&buf[k][e0+4] = make_float4(v[4],v[5],v[6],v[7]);
    }
  }
  __syncthreads();
  int c0 = tk * 8;
  float acc[8][8];
  {
    float4 b0 = *(const float4*)&be2s[c0];
    float4 b1 = *(const float4*)&be2s[c0+4];
    float bq[8] = {b0.x,b0.y,b0.z,b0.w,b1.x,b1.y,b1.z,b1.w};
    #pragma unroll
    for (int r=0;r<8;r++)
      #pragma unroll
      for (int q=0;q<8;q++) acc[r][q] = bq[q];
  }
  #pragma unroll 2
  for (int k=0;k<NG;k++){
    float4 w0 = *(const float4*)&We2s[k][c0];
    float4 w1 = *(const float4*)&We2s[k][c0+4];
    float4 t0 = *(const float4*)&buf[k][e0];
    float4 t1 = *(const float4*)&buf[k][e0+4];
    float tv[8] = {t0.x,t0.y,t0.z,t0.w,t1.x,t1.y,t1.z,t1.w};
    float wv[8] = {w0.x,w0.y,w0.z,w0.w,w1.x,w1.y,w1.z,w1.w};
    #pragma unroll
    for (int r=0;r<8;r++)
      #pragma unroll
      for (int q=0;q<8;q++) acc[r][q] += tv[r]*wv[q];
  }
  int   curtgt = tgts[e0];
  float run[8];
  #pragma unroll
  for (int q=0;q<8;q++) run[q] = 0.f;
  #pragma unroll
  for (int r=0;r<8;r++){
    int t = tgts[e0+r];
    int s = srcs[e0+r];
    float4 n0 = *(const float4*)&nodef[(size_t)s*NB + c0];
    float4 n1 = *(const float4*)&nodef[(size_t)s*NB + c0+4];
    float nv[8] = {n0.x,n0.y,n0.z,n0.w,n1.x,n1.y,n1.z,n1.w};
    if (t != curtgt){
      if (curtgt >= 0){
        float* ap = &agg[(size_t)curtgt*NB + c0];
        #pragma unroll
        for (int q=0;q<8;q++) atomicAdd(ap+q, run[q]);
      }
      curtgt = t;
      #pragma unroll
      for (int q=0;q<8;q++) run[q] = 0.f;
    }
    if (t >= 0){
      #pragma unroll
      for (int q=0;q<8;q++) run[q] += acc[r][q] * nv[q];
    }
  }
  if (curtgt >= 0){
    float* ap = &agg[(size_t)curtgt*NB + c0];
    #pragma unroll
    for (int q=0;q<8;q++) atomicAdd(ap+q, run[q]);
  }
}

// ---------------- legacy atomic edge kernel (last-resort fallback) -----------
__launch_bounds__(256, 2)
__global__ void edge_k(const float* __restrict__ dists, const int* __restrict__ a,
                       const float* __restrict__ nodef,
                       const float* __restrict__ We1, const float* __restrict__ be1,
                       const float* __restrict__ We2, const float* __restrict__ be2,
                       float* __restrict__ agg, int E){
  __shared__ float We1s[NG][64];
  __shared__ float We2s[NG][NB];
  __shared__ float buf[NG][NB];
  __shared__ float be1s[64], be2s[NB];
  __shared__ float ds_[NB];
  __shared__ int   ijs[2*NB];
  int tid = threadIdx.x;

  for (int idx = tid; idx < NG*64; idx += 256){
    int m = idx >> 6, k = idx & 63;
    We1s[m][k] = (k < NG) ? We1[m*NG + k] : 0.f;
  }
  for (int idx = tid; idx < NG*NB; idx += 256)
    We2s[0][idx] = We2[idx];
  if (tid < 64)  be1s[tid] = (tid < NG) ? be1[tid] : 0.f;
  if (tid < NB)  be2s[tid] = be2[tid];

  int ebase = blockIdx.x * NB;
  if (tid < NB){
    int e = ebase + tid;
    if (e < E){ ds_[tid] = dists[e]; ijs[2*tid] = a[2*e]; ijs[2*tid+1] = a[2*e+1]; }
    else      { ds_[tid] = 0.f;      ijs[2*tid] = -1;     ijs[2*tid+1] = -1; }
  }
  __syncthreads();
  for (int idx = tid; idx < NG*NB; idx += 256){
    int m = idx >> 7, e = idx & 127;
    float t = ds_[e] - RBF_STEP * (float)m;
    buf[m][e] = __expf(RBF_COEFF * t * t);
  }
  __syncthreads();
  int te = tid >> 4, tk = tid & 15;
  int e0 = te * 8, k0 = tk * 4;
  float tacc[8][4];
  {
    float4 bv = *(const float4*)&be1s[k0];
    float bq[4] = {bv.x,bv.y,bv.z,bv.w};
    #pragma unroll
    for (int r=0;r<8;r++)
      #pragma unroll
      for (int q=0;q<4;q++) tacc[r][q] = bq[q];
  }
  #pragma unroll 2
  for (int m=0;m<NG;m++){
    float4 w  = *(const float4*)&We1s[m][k0];
    float4 g0 = *(const float4*)&buf[m][e0];
    float4 g1 = *(const float4*)&buf[m][e0+4];
    float ge[8] = {g0.x,g0.y,g0.z,g0.w,g1.x,g1.y,g1.z,g1.w};
    float wv[4] = {w.x,w.y,w.z,w.w};
    #pragma unroll
    for (int r=0;r<8;r++)
      #pragma unroll
      for (int q=0;q<4;q++) tacc[r][q] += ge[r]*wv[q];
  }
  __syncthreads();
  #pragma unroll
  for (int q=0;q<4;q++){
    int k = k0 + q;
    if (k < NG){
      float v[8];
      #pragma unroll
      for (int r=0;r<8;r++) v[r] = sspf(tacc[r][q]);
      *(float4*)&buf[k][e0]   = make_float4(v[0],v[1],v[2],v[3]);
      *(float4*)&buf[k][e0+4] = make_float4(v[4],v[5],v[6],v[7]);
    }
  }
  __syncthreads();
  int c0 = tk * 8;
  float acc[8][8];
  {
    float4 b0 = *(const float4*)&be2s[c0];
    float4 b1 = *(const float4*)&be2s[c0+4];
    float bq[8] = {b0.x,b0.y,b0.z,b0.w,b1.x,b1.y,b1.z,b1.w};
    #pragma unroll
    for (int r=0;r<8;r++)
      #pragma unroll
      for (int q=0;q<8;q++) acc[r][q] = bq[q];
  }
  #pragma unroll 2
  for (int k=0;k<NG;k++){
    float4 w0 = *(const float4*)&We2s[k][c0];
    float4 w1 = *(const float4*)&We2s[k][c0+4];
    float4 t0 = *(const float4*)&buf[k][e0];
    float4 t1 = *(const float4*)&buf[k][e0+4];
    float tv[8] = {t0.x,t0.y,t0.z,t0.w,t1.x,t1.y,t1.z,t1.w};
    float wv[8] = {w0.x,w0.y,w0.z,w0.w,w1.x,w1.y,w1.z,w1.w};
    #pragma unroll
    for (int r=0;r<8;r++)
      #pragma unroll
      for (int q=0;q<8;q++) acc[r][q] += tv[r]*wv[q];
  }
  #pragma unroll
  for (int r=0;r<8;r++){
    int el = e0 + r;
    int i = ijs[2*el], j = ijs[2*el+1];
    if (i < 0) continue;
    float4 nj0 = *(const float4*)&nodef[(size_t)j*NB + c0];
    float4 nj1 = *(const float4*)&nodef[(size_t)j*NB + c0+4];
    float4 ni0 = *(const float4*)&nodef[(size_t)i*NB + c0];
    float4 ni1 = *(const float4*)&nodef[(size_t)i*NB + c0+4];
    float* ai = &agg[(size_t)i*NB + c0];
    float* aj = &agg[(size_t)j*NB + c0];
    float njv[8] = {nj0.x,nj0.y,nj0.z,nj0.w,nj1.x,nj1.y,nj1.z,nj1.w};
    float niv[8] = {ni0.x,ni0.y,ni0.z,ni0.w,ni1.x,ni1.y,ni1.z,ni1.w};
    #pragma unroll
    for (int q=0;q<8;q++){
      atomicAdd(ai+q, njv[q]*acc[r][q]);
      atomicAdd(aj+q, niv[q]*acc[r][q]);
    }
  }
}

// ---------------- readout: e = ssp(h@W1+b1)@W2+b2, molecule segment sum ------
__launch_bounds__(128, 3)
__global__ void readout_k(const float* __restrict__ h, const float* __restrict__ W1,
                          const float* __restrict__ b1, const float* __restrict__ W2,
                          const float* __restrict__ b2, const int* __restrict__ molp,
                          float* __restrict__ out, int N){
  __shared__ float As[32][64];
  __shared__ float W1s[32][64];
  __shared__ float segsum[2];
  int tid = threadIdx.x;
  int tc = tid & 15, tr = tid >> 4;
  int row0 = blockIdx.x * 64;
  int c0 = tc * 4;

  float acc[8][4];
  {
    float4 bv = *(const float4*)&b1[c0];
    float bq[4] = {bv.x,bv.y,bv.z,bv.w};
    #pragma unroll
    for (int r=0;r<8;r++)
      #pragma unroll
      for (int q=0;q<4;q++) acc[r][q] = bq[q];
  }
  for (int kc=0;kc<4;kc++){
    #pragma unroll
    for (int p=0;p<4;p++){
      int f = tid + 128*p; int rr = f >> 3; int kq = f & 7;
      int grow = row0 + rr;
      float4 v = (grow < N) ? *(const float4*)&h[(size_t)grow*NB + kc*32 + kq*4]
                            : make_float4(0.f,0.f,0.f,0.f);
      As[kq*4+0][rr] = v.x; As[kq*4+1][rr] = v.y;
      As[kq*4+2][rr] = v.z; As[kq*4+3][rr] = v.w;
    }
    #pragma unroll
    for (int p=0;p<4;p++){
      int f = tid + 128*p; int wk = f >> 4; int cq = f & 15;
      *(float4*)&W1s[wk][cq*4] = *(const float4*)&W1[(size_t)(kc*32+wk)*64 + cq*4];
    }
    __syncthreads();
    #pragma unroll 4
    for (int k=0;k<32;k++){
      float4 a0 = *(const float4*)&As[k][tr*8];
      float4 a1 = *(const float4*)&As[k][tr*8+4];
      float4 w  = *(const float4*)&W1s[k][c0];
      float av[8] = {a0.x,a0.y,a0.z,a0.w,a1.x,a1.y,a1.z,a1.w};
      float wv[4] = {w.x,w.y,w.z,w.w};
      #pragma unroll
      for (int r=0;r<8;r++)
        #pragma unroll
        for (int q=0;q<4;q++) acc[r][q] += av[r]*wv[q];
    }
    __syncthreads();
  }
  float4 w2f = *(const float4*)&W2[c0];
  float part[8];
  #pragma unroll
  for (int r=0;r<8;r++)
    part[r] = sspf(acc[r][0])*w2f.x + sspf(acc[r][1])*w2f.y +
              sspf(acc[r][2])*w2f.z + sspf(acc[r][3])*w2f.w;
  #pragma unroll
  for (int off=1; off<16; off<<=1)
    #pragma unroll
    for (int r=0;r<8;r++) part[r] += __shfl_xor(part[r], off);

  if (tid < 2) segsum[tid] = 0.f;
  __syncthreads();
  int ms = molp[0];
  float b2v = b2[0];
  int seg0 = row0 / ms;
  if (tc == 0){
    #pragma unroll
    for (int r=0;r<8;r++){
      int row = row0 + tr*8 + r;
      if (row < N){
        int s = row/ms - seg0;
        if (s < 2) atomicAdd(&segsum[s], part[r] + b2v);
        else       atomicAdd(&out[row/ms], part[r] + b2v);
      }
    }
  }
  __syncthreads();
  if (tid == 0 && segsum[0] != 0.f) atomicAdd(&out[seg0], segsum[0]);
  if (tid == 1){
    int lastrow = row0 + 63; if (lastrow > N-1) lastrow = N-1;
    if (lastrow/ms > seg0 && segsum[1] != 0.f) atomicAdd(&out[seg0+1], segsum[1]);
  }
}

extern "C" void kernel_launch(void* const* d_in, const int* in_sizes, int n_in,
                              void* d_out, int out_size, void* d_ws, size_t ws_size,
                              hipStream_t stream){
  const int*   r     = (const int*)  d_in[0];
  const float* xyz   = (const float*)d_in[1];
  const int*   a     = (const int*)  d_in[2];
  const int*   molp  = (const int*)  d_in[3];
  const float* embed = (const float*)d_in[4];
  const float* Wn    = (const float*)d_in[5];
  const float* bn    = (const float*)d_in[6];
  const float* We1   = (const float*)d_in[7];
  const float* be1   = (const float*)d_in[8];
  const float* We2   = (const float*)d_in[9];
  const float* be2   = (const float*)d_in[10];
  const float* Wu1   = (const float*)d_in[11];
  const float* bu1   = (const float*)d_in[12];
  const float* Wu2   = (const float*)d_in[13];
  const float* bu2   = (const float*)d_in[14];
  const float* W1    = (const float*)d_in[15];
  const float* b1    = (const float*)d_in[16];
  const float* W2    = (const float*)d_in[17];
  const float* b2    = (const float*)d_in[18];

  int N = in_sizes[0];          // 50000
  int E = in_sizes[2] / 2;      // 500000
  int V = 2*E;                  // directed visits
  size_t VmaxS = (size_t)V + 8*(size_t)N;   // 8-pad worst case

  float* ws   = (float*)d_ws;
  size_t E4   = ((size_t)E + 3) & ~(size_t)3;
  size_t NSZ  = (size_t)N * NB;
  size_t RPAD = ((size_t)N + 1 + 3) & ~(size_t)3;
  size_t NPAD = ((size_t)N + 3) & ~(size_t)3;
  size_t base = E4 + 3*NSZ;

  // tier1: rowptr | cnt | pcnt | cur | bsum | boff | asrc,aedg,tgtv (3*VmaxS)
  size_t need1 = (base + RPAD + 3*NPAD + 512 + 3*VmaxS) * sizeof(float);
  // tier2: rowptr | cnt | cur | bsum | boff | asrc,aedg,tgtv (3*V)
  size_t need2 = (base + RPAD + 2*NPAD + 512 + 3*(size_t)V) * sizeof(float);

  float* dbuf  = ws;
  float* h     = dbuf + E4;
  float* nodef = h + NSZ;
  float* agg   = nodef + NSZ;

  int gblocks = (N + 63)/64;
  int eblocks = (E + 127)/128;
  int nb = (N + SCAN_TILE - 1) / SCAN_TILE;

  embed_k<<<(N*32 + 255)/256, 256, 0, stream>>>(r, embed, h, N);
  dist_k <<<(E + 255)/256,    256, 0, stream>>>(a, xyz, dbuf, E);

  if (ws_size >= need1){
    int* rowptr = (int*)(agg + NSZ);
    int* cnt    = rowptr + RPAD;
    int* pcnt   = cnt + NPAD;
    int* cur    = pcnt + NPAD;
    int* bsum   = cur + NPAD;
    int* boff   = bsum + 256;
    int* asrc   = boff + 256;
    int* aedg   = asrc + VmaxS;
    int* tgtv   = aedg + VmaxS;

    (void)hipMemsetAsync(cnt, 0, (size_t)N*sizeof(int), stream);
    (void)hipMemsetAsync(asrc, 0, VmaxS*sizeof(int), stream);
    (void)hipMemsetAsync(aedg, 0, VmaxS*sizeof(int), stream);
    (void)hipMemsetAsync(tgtv, 0xFF, VmaxS*sizeof(int), stream);
    hist_k  <<<(E + 255)/256, 256, 0, stream>>>(a, cnt, E);
    pad_k   <<<(N + 255)/256, 256, 0, stream>>>(cnt, pcnt, N);
    reduce_k<<<nb, 256, 0, stream>>>(pcnt, bsum, N);
    scanb_k <<<1, 64, 0, stream>>>(bsum, boff, nb);
    scan2_k <<<nb, 256, 0, stream>>>(pcnt, boff, rowptr, N, 0);
    copy_k  <<<(N + 255)/256, 256, 0, stream>>>(rowptr, cur, N);
    fill_k  <<<(E + 255)/256, 256, 0, stream>>>(a, cur, asrc, aedg, tgtv, E);

    int vblocks = (int)((VmaxS + 127)/128);
    for (int l = 0; l < 3; l++){
      gemm128_k<0,0><<<gblocks, 128, 0, stream>>>(h, Wn + (size_t)l*NB*NB, bn + l*NB, nodef, N);
      (void)hipMemsetAsync(agg, 0, NSZ*sizeof(float), stream);
      visit2_k<<<vblocks, 256, 0, stream>>>(dbuf, asrc, aedg, tgtv, nodef,
                                            We1 + (size_t)l*NG*NG, be1 + l*NG,
                                            We2 + (size_t)l*NG*NB, be2 + l*NB, agg, (int)VmaxS);
      gemm128_k<1,0><<<gblocks, 128, 0, stream>>>(agg,   Wu1 + (size_t)l*NB*NB, bu1 + l*NB, nodef, N);
      gemm128_k<0,1><<<gblocks, 128, 0, stream>>>(nodef, Wu2 + (size_t)l*NB*NB, bu2 + l*NB, h, N);
    }
  } else if (ws_size >= need2){
    int* rowptr = (int*)(agg + NSZ);
    int* cnt    = rowptr + RPAD;
    int* cur    = cnt + NPAD;
    int* bsum   = cur + NPAD;
    int* boff   = bsum + 256;
    int* asrc   = boff + 256;
    int* aedg   = asrc + V;
    int* tgtv   = aedg + V;

    (void)hipMemsetAsync(cnt, 0, (size_t)N*sizeof(int), stream);
    hist_k  <<<(E + 255)/256, 256, 0, stream>>>(a, cnt, E);
    reduce_k<<<nb, 256, 0, stream>>>(cnt, bsum, N);
    scanb_k <<<1, 64, 0, stream>>>(bsum, boff, nb);
    scan2_k <<<nb, 256, 0, stream>>>(cnt, boff, rowptr, N, V);
    copy_k  <<<(N + 255)/256, 256, 0, stream>>>(rowptr, cur, N);
    fill_k  <<<(E + 255)/256, 256, 0, stream>>>(a, cur, asrc, aedg, tgtv, E);

    int vblocks = (V + 127)/128;
    for (int l = 0; l < 3; l++){
      gemm128_k<0,0><<<gblocks, 128, 0, stream>>>(h, Wn + (size_t)l*NB*NB, bn + l*NB, nodef, N);
      (void)hipMemsetAsync(agg, 0, NSZ*sizeof(float), stream);
      visit_k<<<vblocks, 256, 0, stream>>>(dbuf, asrc, aedg, tgtv, nodef,
                                           We1 + (size_t)l*NG*NG, be1 + l*NG,
                                           We2 + (size_t)l*NG*NB, be2 + l*NB, agg, V);
      gemm128_k<1,0><<<gblocks, 128, 0, stream>>>(agg,   Wu1 + (size_t)l*NB*NB, bu1 + l*NB, nodef, N);
      gemm128_k<0,1><<<gblocks, 128, 0, stream>>>(nodef, Wu2 + (size_t)l*NB*NB, bu2 + l*NB, h, N);
    }
  } else {
    for (int l = 0; l < 3; l++){
      gemm128_k<0,0><<<gblocks, 128, 0, stream>>>(h, Wn + (size_t)l*NB*NB, bn + l*NB, nodef, N);
      (void)hipMemsetAsync(agg, 0, NSZ*sizeof(float), stream);
      edge_k<<<eblocks, 256, 0, stream>>>(dbuf, a, nodef,
                                          We1 + (size_t)l*NG*NG, be1 + l*NG,
                                          We2 + (size_t)l*NG*NB, be2 + l*NB, agg, E);
      gemm128_k<1,0><<<gblocks, 128, 0, stream>>>(agg,   Wu1 + (size_t)l*NB*NB, bu1 + l*NB, nodef, N);
      gemm128_k<0,1><<<gblocks, 128, 0, stream>>>(nodef, Wu2 + (size_t)l*NB*NB, bu2 + l*NB, h, N);
    }
  }

  (void)hipMemsetAsync(d_out, 0, (size_t)out_size*sizeof(float), stream);
  readout_k<<<gblocks, 128, 0, stream>>>(h, W1, b1, W2, b2, molp, (float*)d_out, N);
}

// Round 10
// 1551.048 us; speedup vs baseline: 6.9514x; 1.1106x over previous
//
#include <hip/hip_runtime.h>
#include <hip/hip_bf16.h>

#define NG 50
#define NB 128

__device__ __forceinline__ float sspf(float x){
  float t = __expf(-fabsf(x));
  return fmaxf(x, 0.f) + __logf(1.f + t) - 0.6931471805599453094f;
}

constexpr float RBF_STEP  = 5.0f / 49.0f;
constexpr float RBF_COEFF = -0.5f / (RBF_STEP * RBF_STEP);

// ---------------- h = embed[r] ----------------
__global__ void embed_k(const int* __restrict__ r, const float* __restrict__ embed,
                        float* __restrict__ h, int N){
  int idx = blockIdx.x * blockDim.x + threadIdx.x;
  if (idx < N * 32){
    int n = idx >> 5, c = (idx & 31) * 4;
    *(float4*)&h[(size_t)n * NB + c] = *(const float4*)&embed[(size_t)r[n] * NB + c];
  }
}

// ---------------- per-edge distance ----------------
__global__ void dist_k(const int* __restrict__ a, const float* __restrict__ xyz,
                       float* __restrict__ d, int E){
  int e = blockIdx.x * blockDim.x + threadIdx.x;
  if (e < E){
    int i = a[2*e], j = a[2*e+1];
    float dx = xyz[3*i+0] - xyz[3*j+0];
    float dy = xyz[3*i+1] - xyz[3*j+1];
    float dz = xyz[3*i+2] - xyz[3*j+2];
    d[e] = sqrtf(dx*dx + dy*dy + dz*dz);
  }
}

// ---------------- pad We1/be1 into [50][64] / [64] per layer ----------------
__global__ void padw_k(const float* __restrict__ We1, const float* __restrict__ be1,
                       float* __restrict__ We1p, float* __restrict__ be1p){
  int idx = blockIdx.x*blockDim.x + threadIdx.x;
  if (idx < 3*NG*64){
    int l = idx/(NG*64), rem = idx%(NG*64), m = rem>>6, k = rem&63;
    We1p[idx] = (k < NG) ? We1[((size_t)l*NG + m)*NG + k] : 0.f;
  }
  if (idx < 3*64){
    int l = idx>>6, k = idx&63;
    be1p[idx] = (k < NG) ? be1[l*NG + k] : 0.f;
  }
}

// ================= CSR build =================
__global__ void hist_k(const int* __restrict__ a, int* __restrict__ cnt, int E){
  int e = blockIdx.x * blockDim.x + threadIdx.x;
  if (e < E){
    atomicAdd(&cnt[a[2*e]],   1);
    atomicAdd(&cnt[a[2*e+1]], 1);
  }
}

__global__ void pad_k(const int* __restrict__ cnt, int* __restrict__ pcnt, int N){
  int i = blockIdx.x*blockDim.x + threadIdx.x;
  if (i < N) pcnt[i] = (cnt[i] + 7) & ~7;
}

#define SCAN_TILE 512
__global__ void reduce_k(const int* __restrict__ cnt, int* __restrict__ bsum, int N){
  __shared__ int s[256];
  int b = blockIdx.x, t = threadIdx.x;
  int i0 = b*SCAN_TILE + t;
  int v = 0;
  if (i0 < N)       v += cnt[i0];
  if (i0+256 < N)   v += cnt[i0+256];
  s[t] = v; __syncthreads();
  for (int o=128;o>0;o>>=1){ if (t<o) s[t]+=s[t+o]; __syncthreads(); }
  if (t==0) bsum[b] = s[0];
}

__global__ void scanb_k(const int* __restrict__ bsum, int* __restrict__ boff, int nb){
  if (threadIdx.x==0 && blockIdx.x==0){
    int acc = 0;
    for (int i=0;i<nb;i++){ boff[i]=acc; acc+=bsum[i]; }
  }
}

__global__ void scan2_k(const int* __restrict__ cnt, const int* __restrict__ boff,
                        int* __restrict__ rowptr, int N, int total){
  __shared__ int s[256];
  int b = blockIdx.x, t = threadIdx.x;
  int i0 = b*SCAN_TILE;
  int a0 = (i0+2*t   < N) ? cnt[i0+2*t]   : 0;
  int a1 = (i0+2*t+1 < N) ? cnt[i0+2*t+1] : 0;
  int pair = a0 + a1;
  s[t] = pair; __syncthreads();
  for (int o=1;o<256;o<<=1){
    int v = (t>=o) ? s[t-o] : 0;
    __syncthreads();
    s[t] += v;
    __syncthreads();
  }
  int excl = s[t] - pair + boff[b];
  if (i0+2*t   < N) rowptr[i0+2*t]   = excl;
  if (i0+2*t+1 < N) rowptr[i0+2*t+1] = excl + a0;
  if (b==0 && t==0) rowptr[N] = total;
}

__global__ void copy_k(const int* __restrict__ src, int* __restrict__ dst, int n){
  int i = blockIdx.x*blockDim.x + threadIdx.x;
  if (i < n) dst[i] = src[i];
}

// visit list (SoA): asrc[p]=source node, dvis[p]=edge distance, tgtv[p]=target
__global__ void fill_k(const int* __restrict__ a, const float* __restrict__ dists,
                       int* __restrict__ cur,
                       int* __restrict__ asrc, float* __restrict__ dvis,
                       int* __restrict__ tgtv, int E){
  int e = blockIdx.x*blockDim.x + threadIdx.x;
  if (e < E){
    int i = a[2*e], j = a[2*e+1];
    float d = dists[e];
    int p = atomicAdd(&cur[i], 1);
    asrc[p] = j; dvis[p] = d; tgtv[p] = i;
    int q = atomicAdd(&cur[j], 1);
    asrc[q] = i; dvis[q] = d; tgtv[q] = j;
  }
}

// ---------------- generic (N x 128) @ (128 x 128) + b, opt ssp, opt residual ----
template<int ACT, int RESID>
__launch_bounds__(128, 3)
__global__ void gemm128_k(const float* __restrict__ in, const float* __restrict__ W,
                          const float* __restrict__ bias, float* __restrict__ out, int N){
  __shared__ float As[32][64];
  __shared__ float Ws[32][128];
  int tid = threadIdx.x;
  int tc = tid & 15, tr = tid >> 4;
  int row0 = blockIdx.x * 64;
  int c0 = tc * 8;

  float bcol[8];
  {
    float4 b0 = *(const float4*)&bias[c0];
    float4 b1 = *(const float4*)&bias[c0+4];
    bcol[0]=b0.x; bcol[1]=b0.y; bcol[2]=b0.z; bcol[3]=b0.w;
    bcol[4]=b1.x; bcol[5]=b1.y; bcol[6]=b1.z; bcol[7]=b1.w;
  }
  float acc[8][8];
  #pragma unroll
  for (int r=0;r<8;r++)
    #pragma unroll
    for (int q=0;q<8;q++) acc[r][q] = bcol[q];

  for (int kc=0; kc<4; kc++){
    #pragma unroll
    for (int p=0;p<4;p++){
      int f = tid + 128*p;
      int rr = f >> 3, kq = f & 7;
      int grow = row0 + rr;
      float4 v = (grow < N) ? *(const float4*)&in[(size_t)grow*NB + kc*32 + kq*4]
                            : make_float4(0.f,0.f,0.f,0.f);
      As[kq*4+0][rr] = v.x; As[kq*4+1][rr] = v.y;
      As[kq*4+2][rr] = v.z; As[kq*4+3][rr] = v.w;
    }
    #pragma unroll
    for (int p=0;p<8;p++){
      int f = tid + 128*p;
      int wk = f >> 5, cq = f & 31;
      *(float4*)&Ws[wk][cq*4] = *(const float4*)&W[(size_t)(kc*32+wk)*NB + cq*4];
    }
    __syncthreads();
    #pragma unroll 4
    for (int k=0;k<32;k++){
      float4 a0 = *(const float4*)&As[k][tr*8];
      float4 a1 = *(const float4*)&As[k][tr*8+4];
      float4 w0 = *(const float4*)&Ws[k][c0];
      float4 w1 = *(const float4*)&Ws[k][c0+4];
      float av[8] = {a0.x,a0.y,a0.z,a0.w,a1.x,a1.y,a1.z,a1.w};
      float wv[8] = {w0.x,w0.y,w0.z,w0.w,w1.x,w1.y,w1.z,w1.w};
      #pragma unroll
      for (int r=0;r<8;r++)
        #pragma unroll
        for (int q=0;q<8;q++) acc[r][q] += av[r]*wv[q];
    }
    __syncthreads();
  }
  #pragma unroll
  for (int r=0;r<8;r++){
    int row = row0 + tr*8 + r;
    if (row < N){
      float v[8];
      #pragma unroll
      for (int q=0;q<8;q++) v[q] = (ACT==1) ? sspf(acc[r][q]) : acc[r][q];
      if (RESID){
        float4 o0 = *(const float4*)&out[(size_t)row*NB + c0];
        float4 o1 = *(const float4*)&out[(size_t)row*NB + c0+4];
        v[0]+=o0.x; v[1]+=o0.y; v[2]+=o0.z; v[3]+=o0.w;
        v[4]+=o1.x; v[5]+=o1.y; v[6]+=o1.z; v[7]+=o1.w;
      }
      *(float4*)&out[(size_t)row*NB + c0]   = make_float4(v[0],v[1],v[2],v[3]);
      *(float4*)&out[(size_t)row*NB + c0+4] = make_float4(v[4],v[5],v[6],v[7]);
    }
  }
}

// ---------------- visit2_k: 8-aligned runs, slim LDS (3 blocks/CU) -----------
// We1p/be1p read from global (L1-resident, zero-padded to stride 64).
__launch_bounds__(256, 3)
__global__ void visit2_k(const float* __restrict__ dvis,
                         const int* __restrict__ asrc,
                         const int* __restrict__ tgtv,
                         const float* __restrict__ nodef,
                         const float* __restrict__ We1p, const float* __restrict__ be1p,
                         const float* __restrict__ We2, const float* __restrict__ be2,
                         float* __restrict__ agg, int Vmax){
  __shared__ float We2s[NG][NB];    // 25.6 KB
  __shared__ float buf[NG][NB];     // 25.6 KB : g -> T -> part[16][NB]
  __shared__ float ds_[NB];
  __shared__ int   srcs[NB], tgts[NB];
  __shared__ int   tgt8[16];
  int tid = threadIdx.x;

  int vbase = blockIdx.x * NB;
  if (tid < NB){
    int p = vbase + tid;
    if (p < Vmax){
      srcs[tid] = asrc[p]; tgts[tid] = tgtv[p]; ds_[tid] = dvis[p];
    } else {
      srcs[tid] = 0; tgts[tid] = -1; ds_[tid] = 0.f;
    }
  }
  __syncthreads();
  if (tgts[0] < 0) return;          // fully-padded trailing block (uniform)

  for (int idx = tid; idx < NG*NB; idx += 256)
    We2s[0][idx] = We2[idx];
  if (tid < 16)  tgt8[tid] = tgts[tid*8];

  // g phase
  for (int idx = tid; idx < NG*NB; idx += 256){
    int m = idx >> 7, e = idx & 127;
    float t = ds_[e] - RBF_STEP * (float)m;
    buf[m][e] = __expf(RBF_COEFF * t * t);
  }
  __syncthreads();

  int te = tid >> 4, tk = tid & 15;
  int e0 = te * 8, k0 = tk * 4;

  // T phase (We1p from global, padded stride 64)
  float tacc[8][4];
  {
    float4 bv = *(const float4*)&be1p[k0];
    float bq[4] = {bv.x,bv.y,bv.z,bv.w};
    #pragma unroll
    for (int r=0;r<8;r++)
      #pragma unroll
      for (int q=0;q<4;q++) tacc[r][q] = bq[q];
  }
  #pragma unroll 2
  for (int m=0;m<NG;m++){
    float4 w  = *(const float4*)&We1p[m*64 + k0];
    float4 g0 = *(const float4*)&buf[m][e0];
    float4 g1 = *(const float4*)&buf[m][e0+4];
    float ge[8] = {g0.x,g0.y,g0.z,g0.w,g1.x,g1.y,g1.z,g1.w};
    float wv[4] = {w.x,w.y,w.z,w.w};
    #pragma unroll
    for (int r=0;r<8;r++)
      #pragma unroll
      for (int q=0;q<4;q++) tacc[r][q] += ge[r]*wv[q];
  }
  __syncthreads();
  #pragma unroll
  for (int q=0;q<4;q++){
    int k = k0 + q;
    if (k < NG){
      float v[8];
      #pragma unroll
      for (int r=0;r<8;r++) v[r] = sspf(tacc[r][q]);
      *(float4*)&buf[k][e0]   = make_float4(v[0],v[1],v[2],v[3]);
      *(float4*)&buf[k][e0+4] = make_float4(v[4],v[5],v[6],v[7]);
    }
  }
  __syncthreads();

  // EF phase
  int c0 = tk * 8;
  float acc[8][8];
  {
    float4 b0 = *(const float4*)&be2[c0];
    float4 b1 = *(const float4*)&be2[c0+4];
    float bq[8] = {b0.x,b0.y,b0.z,b0.w,b1.x,b1.y,b1.z,b1.w};
    #pragma unroll
    for (int r=0;r<8;r++)
      #pragma unroll
      for (int q=0;q<8;q++) acc[r][q] = bq[q];
  }
  #pragma unroll 2
  for (int k=0;k<NG;k++){
    float4 w0 = *(const float4*)&We2s[k][c0];
    float4 w1 = *(const float4*)&We2s[k][c0+4];
    float4 t0 = *(const float4*)&buf[k][e0];
    float4 t1 = *(const float4*)&buf[k][e0+4];
    float tv[8] = {t0.x,t0.y,t0.z,t0.w,t1.x,t1.y,t1.z,t1.w};
    float wv[8] = {w0.x,w0.y,w0.z,w0.w,w1.x,w1.y,w1.z,w1.w};
    #pragma unroll
    for (int r=0;r<8;r++)
      #pragma unroll
      for (int q=0;q<8;q++) acc[r][q] += tv[r]*wv[q];
  }
  __syncthreads();   // buf reads done; reuse as part[16][NB]

  // group accumulate: all 8 visits in this group share one target (8-aligned)
  float run[8];
  #pragma unroll
  for (int q=0;q<8;q++) run[q] = 0.f;
  #pragma unroll
  for (int r=0;r<8;r++){
    int t = tgts[e0+r];
    int s = srcs[e0+r];
    float4 n0 = *(const float4*)&nodef[(size_t)s*NB + c0];
    float4 n1 = *(const float4*)&nodef[(size_t)s*NB + c0+4];
    float nv[8] = {n0.x,n0.y,n0.z,n0.w,n1.x,n1.y,n1.z,n1.w};
    if (t >= 0){
      #pragma unroll
      for (int q=0;q<8;q++) run[q] += acc[r][q] * nv[q];
    }
  }
  float* part = &buf[0][0];         // part[g][ch] = buf row g
  #pragma unroll
  for (int q=0;q<8;q++) part[te*NB + c0 + q] = run[q];
  __syncthreads();

  // leaders: sum consecutive groups with same target; store/atomic
  int g = te;
  int t = tgt8[g];
  if (t >= 0 && (g == 0 || tgt8[g-1] != t)){
    int gend = g;
    while (gend+1 < 16 && tgt8[gend+1] == t) gend++;
    float s[8];
    #pragma unroll
    for (int q=0;q<8;q++) s[q] = 0.f;
    for (int g2=g; g2<=gend; ++g2)
      #pragma unroll
      for (int q=0;q<8;q++) s[q] += part[g2*NB + c0 + q];
    float* ap = &agg[(size_t)t*NB + c0];
    bool border = (g == 0) || (gend == 15);
    if (border){
      #pragma unroll
      for (int q=0;q<8;q++) atomicAdd(ap+q, s[q]);
    } else {
      *(float4*)ap     = make_float4(s[0],s[1],s[2],s[3]);
      *(float4*)(ap+4) = make_float4(s[4],s[5],s[6],s[7]);
    }
  }
}

// ---------------- visit_k (tier-2 fallback): fragment atomics ----------------
__launch_bounds__(256, 2)
__global__ void visit_k(const float* __restrict__ dvis,
                        const int* __restrict__ asrc,
                        const int* __restrict__ tgtv,
                        const float* __restrict__ nodef,
                        const float* __restrict__ We1, const float* __restrict__ be1,
                        const float* __restrict__ We2, const float* __restrict__ be2,
                        float* __restrict__ agg, int V){
  __shared__ float We1s[NG][64];
  __shared__ float We2s[NG][NB];
  __shared__ float buf[NG][NB];
  __shared__ float be1s[64], be2s[NB];
  __shared__ float ds_[NB];
  __shared__ int   srcs[NB], tgts[NB];
  int tid = threadIdx.x;

  for (int idx = tid; idx < NG*64; idx += 256){
    int m = idx >> 6, k = idx & 63;
    We1s[m][k] = (k < NG) ? We1[m*NG + k] : 0.f;
  }
  for (int idx = tid; idx < NG*NB; idx += 256)
    We2s[0][idx] = We2[idx];
  if (tid < 64)  be1s[tid] = (tid < NG) ? be1[tid] : 0.f;
  if (tid < NB)  be2s[tid] = be2[tid];

  int vbase = blockIdx.x * NB;
  if (tid < NB){
    int p = vbase + tid;
    if (p < V){
      srcs[tid] = asrc[p]; tgts[tid] = tgtv[p]; ds_[tid] = dvis[p];
    } else {
      srcs[tid] = 0; tgts[tid] = -1; ds_[tid] = 0.f;
    }
  }
  __syncthreads();
  for (int idx = tid; idx < NG*NB; idx += 256){
    int m = idx >> 7, e = idx & 127;
    float t = ds_[e] - RBF_STEP * (float)m;
    buf[m][e] = __expf(RBF_COEFF * t * t);
  }
  __syncthreads();
  int te = tid >> 4, tk = tid & 15;
  int e0 = te * 8, k0 = tk * 4;
  float tacc[8][4];
  {
    float4 bv = *(const float4*)&be1s[k0];
    float bq[4] = {bv.x,bv.y,bv.z,bv.w};
    #pragma unroll
    for (int r=0;r<8;r++)
      #pragma unroll
      for (int q=0;q<4;q++) tacc[r][q] = bq[q];
  }
  #pragma unroll 2
  for (int m=0;m<NG;m++){
    float4 w  = *(const float4*)&We1s[m][k0];
    float4 g0 = *(const float4*)&buf[m][e0];
    float4 g1 = *(const float4*)&buf[m][e0+4];
    float ge[8] = {g0.x,g0.y,g0.z,g0.w,g1.x,g1.y,g1.z,g1.w};
    float wv[4] = {w.x,w.y,w.z,w.w};
    #pragma unroll
    for (int r=0;r<8;r++)
      #pragma unroll
      for (int q=0;q<4;q++) tacc[r][q] += ge[r]*wv[q];
  }
  __syncthreads();
  #pragma unroll
  for (int q=0;q<4;q++){
    int k = k0 + q;
    if (k < NG){
      float v[8];
      #pragma unroll
      for (int r=0;r<8;r++) v[r] = sspf(tacc[r][q]);
      *(float4*)&buf[k][e0]   = make_float4(v[0],v[1],v[2],v[3]);
      *(float4*)&buf[k][e0+4] = make_float4(v[4],v[5],v[6],v[7]);
    }
  }
  __syncthreads();
  int c0 = tk * 8;
  float acc[8][8];
  {
    float4 b0 = *(const float4*)&be2s[c0];
    float4 b1 = *(const float4*)&be2s[c0+4];
    float bq[8] = {b0.x,b0.y,b0.z,b0.w,b1.x,b1.y,b1.z,b1.w};
    #pragma unroll
    for (int r=0;r<8;r++)
      #pragma unroll
      for (int q=0;q<8;q++) acc[r][q] = bq[q];
  }
  #pragma unroll 2
  for (int k=0;k<NG;k++){
    float4 w0 = *(const float4*)&We2s[k][c0];
    float4 w1 = *(const float4*)&We2s[k][c0+4];
    float4 t0 = *(const float4*)&buf[k][e0];
    float4 t1 = *(const float4*)&buf[k][e0+4];
    float tv[8] = {t0.x,t0.y,t0.z,t0.w,t1.x,t1.y,t1.z,t1.w};
    float wv[8] = {w0.x,w0.y,w0.z,w0.w,w1.x,w1.y,w1.z,w1.w};
    #pragma unroll
    for (int r=0;r<8;r++)
      #pragma unroll
      for (int q=0;q<8;q++) acc[r][q] += tv[r]*wv[q];
  }
  int   curtgt = tgts[e0];
  float run[8];
  #pragma unroll
  for (int q=0;q<8;q++) run[q] = 0.f;
  #pragma unroll
  for (int r=0;r<8;r++){
    int t = tgts[e0+r];
    int s = srcs[e0+r];
    float4 n0 = *(const float4*)&nodef[(size_t)s*NB + c0];
    float4 n1 = *(const float4*)&nodef[(size_t)s*NB + c0+4];
    float nv[8] = {n0.x,n0.y,n0.z,n0.w,n1.x,n1.y,n1.z,n1.w};
    if (t != curtgt){
      if (curtgt >= 0){
        float* ap = &agg[(size_t)curtgt*NB + c0];
        #pragma unroll
        for (int q=0;q<8;q++) atomicAdd(ap+q, run[q]);
      }
      curtgt = t;
      #pragma unroll
      for (int q=0;q<8;q++) run[q] = 0.f;
    }
    if (t >= 0){
      #pragma unroll
      for (int q=0;q<8;q++) run[q] += acc[r][q] * nv[q];
    }
  }
  if (curtgt >= 0){
    float* ap = &agg[(size_t)curtgt*NB + c0];
    #pragma unroll
    for (int q=0;q<8;q++) atomicAdd(ap+q, run[q]);
  }
}

// ---------------- legacy atomic edge kernel (last-resort fallback) -----------
__launch_bounds__(256, 2)
__global__ void edge_k(const float* __restrict__ dists, const int* __restrict__ a,
                       const float* __restrict__ nodef,
                       const float* __restrict__ We1, const float* __restrict__ be1,
                       const float* __restrict__ We2, const float* __restrict__ be2,
                       float* __restrict__ agg, int E){
  __shared__ float We1s[NG][64];
  __shared__ float We2s[NG][NB];
  __shared__ float buf[NG][NB];
  __shared__ float be1s[64], be2s[NB];
  __shared__ float ds_[NB];
  __shared__ int   ijs[2*NB];
  int tid = threadIdx.x;

  for (int idx = tid; idx < NG*64; idx += 256){
    int m = idx >> 6, k = idx & 63;
    We1s[m][k] = (k < NG) ? We1[m*NG + k] : 0.f;
  }
  for (int idx = tid; idx < NG*NB; idx += 256)
    We2s[0][idx] = We2[idx];
  if (tid < 64)  be1s[tid] = (tid < NG) ? be1[tid] : 0.f;
  if (tid < NB)  be2s[tid] = be2[tid];

  int ebase = blockIdx.x * NB;
  if (tid < NB){
    int e = ebase + tid;
    if (e < E){ ds_[tid] = dists[e]; ijs[2*tid] = a[2*e]; ijs[2*tid+1] = a[2*e+1]; }
    else      { ds_[tid] = 0.f;      ijs[2*tid] = -1;     ijs[2*tid+1] = -1; }
  }
  __syncthreads();
  for (int idx = tid; idx < NG*NB; idx += 256){
    int m = idx >> 7, e = idx & 127;
    float t = ds_[e] - RBF_STEP * (float)m;
    buf[m][e] = __expf(RBF_COEFF * t * t);
  }
  __syncthreads();
  int te = tid >> 4, tk = tid & 15;
  int e0 = te * 8, k0 = tk * 4;
  float tacc[8][4];
  {
    float4 bv = *(const float4*)&be1s[k0];
    float bq[4] = {bv.x,bv.y,bv.z,bv.w};
    #pragma unroll
    for (int r=0;r<8;r++)
      #pragma unroll
      for (int q=0;q<4;q++) tacc[r][q] = bq[q];
  }
  #pragma unroll 2
  for (int m=0;m<NG;m++){
    float4 w  = *(const float4*)&We1s[m][k0];
    float4 g0 = *(const float4*)&buf[m][e0];
    float4 g1 = *(const float4*)&buf[m][e0+4];
    float ge[8] = {g0.x,g0.y,g0.z,g0.w,g1.x,g1.y,g1.z,g1.w};
    float wv[4] = {w.x,w.y,w.z,w.w};
    #pragma unroll
    for (int r=0;r<8;r++)
      #pragma unroll
      for (int q=0;q<4;q++) tacc[r][q] += ge[r]*wv[q];
  }
  __syncthreads();
  #pragma unroll
  for (int q=0;q<4;q++){
    int k = k0 + q;
    if (k < NG){
      float v[8];
      #pragma unroll
      for (int r=0;r<8;r++) v[r] = sspf(tacc[r][q]);
      *(float4*)&buf[k][e0]   = make_float4(v[0],v[1],v[2],v[3]);
      *(float4*)&buf[k][e0+4] = make_float4(v[4],v[5],v[6],v[7]);
    }
  }
  __syncthreads();
  int c0 = tk * 8;
  float acc[8][8];
  {
    float4 b0 = *(const float4*)&be2s[c0];
    float4 b1 = *(const float4*)&be2s[c0+4];
    float bq[8] = {b0.x,b0.y,b0.z,b0.w,b1.x,b1.y,b1.z,b1.w};
    #pragma unroll
    for (int r=0;r<8;r++)
      #pragma unroll
      for (int q=0;q<8;q++) acc[r][q] = bq[q];
  }
  #pragma unroll 2
  for (int k=0;k<NG;k++){
    float4 w0 = *(const float4*)&We2s[k][c0];
    float4 w1 = *(const float4*)&We2s[k][c0+4];
    float4 t0 = *(const float4*)&buf[k][e0];
    float4 t1 = *(const float4*)&buf[k][e0+4];
    float tv[8] = {t0.x,t0.y,t0.z,t0.w,t1.x,t1.y,t1.z,t1.w};
    float wv[8] = {w0.x,w0.y,w0.z,w0.w,w1.x,w1.y,w1.z,w1.w};
    #pragma unroll
    for (int r=0;r<8;r++)
      #pragma unroll
      for (int q=0;q<8;q++) acc[r][q] += tv[r]*wv[q];
  }
  #pragma unroll
  for (int r=0;r<8;r++){
    int el = e0 + r;
    int i = ijs[2*el], j = ijs[2*el+1];
    if (i < 0) continue;
    float4 nj0 = *(const float4*)&nodef[(size_t)j*NB + c0];
    float4 nj1 = *(const float4*)&nodef[(size_t)j*NB + c0+4];
    float4 ni0 = *(const float4*)&nodef[(size_t)i*NB + c0];
    float4 ni1 = *(const float4*)&nodef[(size_t)i*NB + c0+4];
    float* ai = &agg[(size_t)i*NB + c0];
    float* aj = &agg[(size_t)j*NB + c0];
    float njv[8] = {nj0.x,nj0.y,nj0.z,nj0.w,nj1.x,nj1.y,nj1.z,nj1.w};
    float niv[8] = {ni0.x,ni0.y,ni0.z,ni0.w,ni1.x,ni1.y,ni1.z,ni1.w};
    #pragma unroll
    for (int q=0;q<8;q++){
      atomicAdd(ai+q, njv[q]*acc[r][q]);
      atomicAdd(aj+q, niv[q]*acc[r][q]);
    }
  }
}

// ---------------- readout: e = ssp(h@W1+b1)@W2+b2, molecule segment sum ------
__launch_bounds__(128, 3)
__global__ void readout_k(const float* __restrict__ h, const float* __restrict__ W1,
                          const float* __restrict__ b1, const float* __restrict__ W2,
                          const float* __restrict__ b2, const int* __restrict__ molp,
                          float* __restrict__ out, int N){
  __shared__ float As[32][64];
  __shared__ float W1s[32][64];
  __shared__ float segsum[2];
  int tid = threadIdx.x;
  int tc = tid & 15, tr = tid >> 4;
  int row0 = blockIdx.x * 64;
  int c0 = tc * 4;

  float acc[8][4];
  {
    float4 bv = *(const float4*)&b1[c0];
    float bq[4] = {bv.x,bv.y,bv.z,bv.w};
    #pragma unroll
    for (int r=0;r<8;r++)
      #pragma unroll
      for (int q=0;q<4;q++) acc[r][q] = bq[q];
  }
  for (int kc=0;kc<4;kc++){
    #pragma unroll
    for (int p=0;p<4;p++){
      int f = tid + 128*p; int rr = f >> 3; int kq = f & 7;
      int grow = row0 + rr;
      float4 v = (grow < N) ? *(const float4*)&h[(size_t)grow*NB + kc*32 + kq*4]
                            : make_float4(0.f,0.f,0.f,0.f);
      As[kq*4+0][rr] = v.x; As[kq*4+1][rr] = v.y;
      As[kq*4+2][rr] = v.z; As[kq*4+3][rr] = v.w;
    }
    #pragma unroll
    for (int p=0;p<4;p++){
      int f = tid + 128*p; int wk = f >> 4; int cq = f & 15;
      *(float4*)&W1s[wk][cq*4] = *(const float4*)&W1[(size_t)(kc*32+wk)*64 + cq*4];
    }
    __syncthreads();
    #pragma unroll 4
    for (int k=0;k<32;k++){
      float4 a0 = *(const float4*)&As[k][tr*8];
      float4 a1 = *(const float4*)&As[k][tr*8+4];
      float4 w  = *(const float4*)&W1s[k][c0];
      float av[8] = {a0.x,a0.y,a0.z,a0.w,a1.x,a1.y,a1.z,a1.w};
      float wv[4] = {w.x,w.y,w.z,w.w};
      #pragma unroll
      for (int r=0;r<8;r++)
        #pragma unroll
        for (int q=0;q<4;q++) acc[r][q] += av[r]*wv[q];
    }
    __syncthreads();
  }
  float4 w2f = *(const float4*)&W2[c0];
  float part[8];
  #pragma unroll
  for (int r=0;r<8;r++)
    part[r] = sspf(acc[r][0])*w2f.x + sspf(acc[r][1])*w2f.y +
              sspf(acc[r][2])*w2f.z + sspf(acc[r][3])*w2f.w;
  #pragma unroll
  for (int off=1; off<16; off<<=1)
    #pragma unroll
    for (int r=0;r<8;r++) part[r] += __shfl_xor(part[r], off);

  if (tid < 2) segsum[tid] = 0.f;
  __syncthreads();
  int ms = molp[0];
  float b2v = b2[0];
  int seg0 = row0 / ms;
  if (tc == 0){
    #pragma unroll
    for (int r=0;r<8;r++){
      int row = row0 + tr*8 + r;
      if (row < N){
        int s = row/ms - seg0;
        if (s < 2) atomicAdd(&segsum[s], part[r] + b2v);
        else       atomicAdd(&out[row/ms], part[r] + b2v);
      }
    }
  }
  __syncthreads();
  if (tid == 0 && segsum[0] != 0.f) atomicAdd(&out[seg0], segsum[0]);
  if (tid == 1){
    int lastrow = row0 + 63; if (lastrow > N-1) lastrow = N-1;
    if (lastrow/ms > seg0 && segsum[1] != 0.f) atomicAdd(&out[seg0+1], segsum[1]);
  }
}

extern "C" void kernel_launch(void* const* d_in, const int* in_sizes, int n_in,
                              void* d_out, int out_size, void* d_ws, size_t ws_size,
                              hipStream_t stream){
  const int*   r     = (const int*)  d_in[0];
  const float* xyz   = (const float*)d_in[1];
  const int*   a     = (const int*)  d_in[2];
  const int*   molp  = (const int*)  d_in[3];
  const float* embed = (const float*)d_in[4];
  const float* Wn    = (const float*)d_in[5];
  const float* bn    = (const float*)d_in[6];
  const float* We1   = (const float*)d_in[7];
  const float* be1   = (const float*)d_in[8];
  const float* We2   = (const float*)d_in[9];
  const float* be2   = (const float*)d_in[10];
  const float* Wu1   = (const float*)d_in[11];
  const float* bu1   = (const float*)d_in[12];
  const float* Wu2   = (const float*)d_in[13];
  const float* bu2   = (const float*)d_in[14];
  const float* W1    = (const float*)d_in[15];
  const float* b1    = (const float*)d_in[16];
  const float* W2    = (const float*)d_in[17];
  const float* b2    = (const float*)d_in[18];

  int N = in_sizes[0];          // 50000
  int E = in_sizes[2] / 2;      // 500000
  int V = 2*E;                  // directed visits
  size_t VmaxS = (size_t)V + 8*(size_t)N;   // 8-pad worst case

  float* ws   = (float*)d_ws;
  size_t E4   = ((size_t)E + 3) & ~(size_t)3;
  size_t NSZ  = (size_t)N * NB;
  size_t RPAD = ((size_t)N + 1 + 3) & ~(size_t)3;
  size_t NPAD = ((size_t)N + 3) & ~(size_t)3;
  size_t base = E4 + 3*NSZ;
  size_t WPAD = 3*NG*64 + 3*64;   // We1p + be1p

  // tier1: rowptr|cnt|pcnt|cur|bsum|boff | asrc,tgtv (int, VmaxS each) | dvis (float) | We1p,be1p
  size_t need1 = (base + RPAD + 3*NPAD + 512 + 3*VmaxS + WPAD) * sizeof(float);
  // tier2: rowptr|cnt|cur|bsum|boff | asrc,tgtv,dvis (V each)
  size_t need2 = (base + RPAD + 2*NPAD + 512 + 3*(size_t)V) * sizeof(float);

  float* dbuf  = ws;
  float* h     = dbuf + E4;
  float* nodef = h + NSZ;
  float* agg   = nodef + NSZ;

  int gblocks = (N + 63)/64;
  int eblocks = (E + 127)/128;
  int nb = (N + SCAN_TILE - 1) / SCAN_TILE;

  embed_k<<<(N*32 + 255)/256, 256, 0, stream>>>(r, embed, h, N);
  dist_k <<<(E + 255)/256,    256, 0, stream>>>(a, xyz, dbuf, E);

  if (ws_size >= need1){
    int*   rowptr = (int*)(agg + NSZ);
    int*   cnt    = rowptr + RPAD;
    int*   pcnt   = cnt + NPAD;
    int*   cur    = pcnt + NPAD;
    int*   bsum   = cur + NPAD;
    int*   boff   = bsum + 256;
    int*   asrc   = boff + 256;
    int*   tgtv   = asrc + VmaxS;
    float* dvis   = (float*)(tgtv + VmaxS);
    float* We1p   = dvis + VmaxS;
    float* be1p   = We1p + 3*NG*64;

    (void)hipMemsetAsync(cnt, 0, (size_t)N*sizeof(int), stream);
    (void)hipMemsetAsync(asrc, 0, VmaxS*sizeof(int), stream);
    (void)hipMemsetAsync(tgtv, 0xFF, VmaxS*sizeof(int), stream);
    (void)hipMemsetAsync(dvis, 0, VmaxS*sizeof(float), stream);
    padw_k  <<<(3*NG*64 + 255)/256, 256, 0, stream>>>(We1, be1, We1p, be1p);
    hist_k  <<<(E + 255)/256, 256, 0, stream>>>(a, cnt, E);
    pad_k   <<<(N + 255)/256, 256, 0, stream>>>(cnt, pcnt, N);
    reduce_k<<<nb, 256, 0, stream>>>(pcnt, bsum, N);
    scanb_k <<<1, 64, 0, stream>>>(bsum, boff, nb);
    scan2_k <<<nb, 256, 0, stream>>>(pcnt, boff, rowptr, N, 0);
    copy_k  <<<(N + 255)/256, 256, 0, stream>>>(rowptr, cur, N);
    fill_k  <<<(E + 255)/256, 256, 0, stream>>>(a, dbuf, cur, asrc, dvis, tgtv, E);

    int vblocks = (int)((VmaxS + 127)/128);
    for (int l = 0; l < 3; l++){
      gemm128_k<0,0><<<gblocks, 128, 0, stream>>>(h, Wn + (size_t)l*NB*NB, bn + l*NB, nodef, N);
      (void)hipMemsetAsync(agg, 0, NSZ*sizeof(float), stream);
      visit2_k<<<vblocks, 256, 0, stream>>>(dvis, asrc, tgtv, nodef,
                                            We1p + (size_t)l*NG*64, be1p + (size_t)l*64,
                                            We2 + (size_t)l*NG*NB, be2 + l*NB, agg, (int)VmaxS);
      gemm128_k<1,0><<<gblocks, 128, 0, stream>>>(agg,   Wu1 + (size_t)l*NB*NB, bu1 + l*NB, nodef, N);
      gemm128_k<0,1><<<gblocks, 128, 0, stream>>>(nodef, Wu2 + (size_t)l*NB*NB, bu2 + l*NB, h, N);
    }
  } else if (ws_size >= need2){
    int*   rowptr = (int*)(agg + NSZ);
    int*   cnt    = rowptr + RPAD;
    int*   cur    = cnt + NPAD;
    int*   bsum   = cur + NPAD;
    int*   boff   = bsum + 256;
    int*   asrc   = boff + 256;
    int*   tgtv   = asrc + V;
    float* dvis   = (float*)(tgtv + V);

    (void)hipMemsetAsync(cnt, 0, (size_t)N*sizeof(int), stream);
    hist_k  <<<(E + 255)/256, 256, 0, stream>>>(a, cnt, E);
    reduce_k<<<nb, 256, 0, stream>>>(cnt, bsum, N);
    scanb_k <<<1, 64, 0, stream>>>(bsum, boff, nb);
    scan2_k <<<nb, 256, 0, stream>>>(cnt, boff, rowptr, N, V);
    copy_k  <<<(N + 255)/256, 256, 0, stream>>>(rowptr, cur, N);
    fill_k  <<<(E + 255)/256, 256, 0, stream>>>(a, dbuf, cur, asrc, dvis, tgtv, E);

    int vblocks = (V + 127)/128;
    for (int l = 0; l < 3; l++){
      gemm128_k<0,0><<<gblocks, 128, 0, stream>>>(h, Wn + (size_t)l*NB*NB, bn + l*NB, nodef, N);
      (void)hipMemsetAsync(agg, 0, NSZ*sizeof(float), stream);
      visit_k<<<vblocks, 256, 0, stream>>>(dvis, asrc, tgtv, nodef,
                                           We1 + (size_t)l*NG*NG, be1 + l*NG,
                                           We2 + (size_t)l*NG*NB, be2 + l*NB, agg, V);
      gemm128_k<1,0><<<gblocks, 128, 0, stream>>>(agg,   Wu1 + (size_t)l*NB*NB, bu1 + l*NB, nodef, N);
      gemm128_k<0,1><<<gblocks, 128, 0, stream>>>(nodef, Wu2 + (size_t)l*NB*NB, bu2 + l*NB, h, N);
    }
  } else {
    for (int l = 0; l < 3; l++){
      gemm128_k<0,0><<<gblocks, 128, 0, stream>>>(h, Wn + (size_t)l*NB*NB, bn + l*NB, nodef, N);
      (void)hipMemsetAsync(agg, 0, NSZ*sizeof(float), stream);
      edge_k<<<eblocks, 256, 0, stream>>>(dbuf, a, nodef,
                                          We1 + (size_t)l*NG*NG, be1 + l*NG,
                                          We2 + (size_t)l*NG*NB, be2 + l*NB, agg, E);
      gemm128_k<1,0><<<gblocks, 128, 0, stream>>>(agg,   Wu1 + (size_t)l*NB*NB, bu1 + l*NB, nodef, N);
      gemm128_k<0,1><<<gblocks, 128, 0, stream>>>(nodef, Wu2 + (size_t)l*NB*NB, bu2 + l*NB, h, N);
    }
  }

  (void)hipMemsetAsync(d_out, 0, (size_t)out_size*sizeof(float), stream);
  readout_k<<<gblocks, 128, 0, stream>>>(h, W1, b1, W2, b2, molp, (float*)d_out, N);
}

// Round 11
// 1499.671 us; speedup vs baseline: 7.1895x; 1.0343x over previous
//
#include <hip/hip_runtime.h>
#include <hip/hip_bf16.h>

#define NG 50
#define NB 128

__device__ __forceinline__ float sspf(float x){
  float t = __expf(-fabsf(x));
  return fmaxf(x, 0.f) + __logf(1.f + t) - 0.6931471805599453094f;
}

constexpr float RBF_STEP  = 5.0f / 49.0f;
constexpr float RBF_COEFF = -0.5f / (RBF_STEP * RBF_STEP);

// ---------------- h = embed[r] ----------------
__global__ void embed_k(const int* __restrict__ r, const float* __restrict__ embed,
                        float* __restrict__ h, int N){
  int idx = blockIdx.x * blockDim.x + threadIdx.x;
  if (idx < N * 32){
    int n = idx >> 5, c = (idx & 31) * 4;
    *(float4*)&h[(size_t)n * NB + c] = *(const float4*)&embed[(size_t)r[n] * NB + c];
  }
}

// ---------------- per-edge distance ----------------
__global__ void dist_k(const int* __restrict__ a, const float* __restrict__ xyz,
                       float* __restrict__ d, int E){
  int e = blockIdx.x * blockDim.x + threadIdx.x;
  if (e < E){
    int i = a[2*e], j = a[2*e+1];
    float dx = xyz[3*i+0] - xyz[3*j+0];
    float dy = xyz[3*i+1] - xyz[3*j+1];
    float dz = xyz[3*i+2] - xyz[3*j+2];
    d[e] = sqrtf(dx*dx + dy*dy + dz*dz);
  }
}

// ---------------- pad We1/be1 into [50][64] / [64] per layer ----------------
__global__ void padw_k(const float* __restrict__ We1, const float* __restrict__ be1,
                       float* __restrict__ We1p, float* __restrict__ be1p){
  int idx = blockIdx.x*blockDim.x + threadIdx.x;
  if (idx < 3*NG*64){
    int l = idx/(NG*64), rem = idx%(NG*64), m = rem>>6, k = rem&63;
    We1p[idx] = (k < NG) ? We1[((size_t)l*NG + m)*NG + k] : 0.f;
  }
  if (idx < 3*64){
    int l = idx>>6, k = idx&63;
    be1p[idx] = (k < NG) ? be1[l*NG + k] : 0.f;
  }
}

// ================= CSR build =================
__global__ void hist_k(const int* __restrict__ a, int* __restrict__ cnt, int E){
  int e = blockIdx.x * blockDim.x + threadIdx.x;
  if (e < E){
    atomicAdd(&cnt[a[2*e]],   1);
    atomicAdd(&cnt[a[2*e+1]], 1);
  }
}

__global__ void pad_k(const int* __restrict__ cnt, int* __restrict__ pcnt, int N){
  int i = blockIdx.x*blockDim.x + threadIdx.x;
  if (i < N) pcnt[i] = (cnt[i] + 7) & ~7;
}

#define SCAN_TILE 512
__global__ void reduce_k(const int* __restrict__ cnt, int* __restrict__ bsum, int N){
  __shared__ int s[256];
  int b = blockIdx.x, t = threadIdx.x;
  int i0 = b*SCAN_TILE + t;
  int v = 0;
  if (i0 < N)       v += cnt[i0];
  if (i0+256 < N)   v += cnt[i0+256];
  s[t] = v; __syncthreads();
  for (int o=128;o>0;o>>=1){ if (t<o) s[t]+=s[t+o]; __syncthreads(); }
  if (t==0) bsum[b] = s[0];
}

__global__ void scanb_k(const int* __restrict__ bsum, int* __restrict__ boff, int nb){
  if (threadIdx.x==0 && blockIdx.x==0){
    int acc = 0;
    for (int i=0;i<nb;i++){ boff[i]=acc; acc+=bsum[i]; }
  }
}

__global__ void scan2_k(const int* __restrict__ cnt, const int* __restrict__ boff,
                        int* __restrict__ rowptr, int N, int total){
  __shared__ int s[256];
  int b = blockIdx.x, t = threadIdx.x;
  int i0 = b*SCAN_TILE;
  int a0 = (i0+2*t   < N) ? cnt[i0+2*t]   : 0;
  int a1 = (i0+2*t+1 < N) ? cnt[i0+2*t+1] : 0;
  int pair = a0 + a1;
  s[t] = pair; __syncthreads();
  for (int o=1;o<256;o<<=1){
    int v = (t>=o) ? s[t-o] : 0;
    __syncthreads();
    s[t] += v;
    __syncthreads();
  }
  int excl = s[t] - pair + boff[b];
  if (i0+2*t   < N) rowptr[i0+2*t]   = excl;
  if (i0+2*t+1 < N) rowptr[i0+2*t+1] = excl + a0;
  if (b==0 && t==0) rowptr[N] = total;
}

__global__ void copy_k(const int* __restrict__ src, int* __restrict__ dst, int n){
  int i = blockIdx.x*blockDim.x + threadIdx.x;
  if (i < n) dst[i] = src[i];
}

// visit list (SoA): asrc[p]=source node, dvis[p]=edge distance, tgtv[p]=target
__global__ void fill_k(const int* __restrict__ a, const float* __restrict__ dists,
                       int* __restrict__ cur,
                       int* __restrict__ asrc, float* __restrict__ dvis,
                       int* __restrict__ tgtv, int E){
  int e = blockIdx.x*blockDim.x + threadIdx.x;
  if (e < E){
    int i = a[2*e], j = a[2*e+1];
    float d = dists[e];
    int p = atomicAdd(&cur[i], 1);
    asrc[p] = j; dvis[p] = d; tgtv[p] = i;
    int q = atomicAdd(&cur[j], 1);
    asrc[q] = i; dvis[q] = d; tgtv[q] = j;
  }
}

// ---------------- generic (N x 128) @ (128 x 128) + b, opt ssp, opt residual ----
template<int ACT, int RESID>
__launch_bounds__(128, 3)
__global__ void gemm128_k(const float* __restrict__ in, const float* __restrict__ W,
                          const float* __restrict__ bias, float* __restrict__ out, int N){
  __shared__ float As[32][64];
  __shared__ float Ws[32][128];
  int tid = threadIdx.x;
  int tc = tid & 15, tr = tid >> 4;
  int row0 = blockIdx.x * 64;
  int c0 = tc * 8;

  float bcol[8];
  {
    float4 b0 = *(const float4*)&bias[c0];
    float4 b1 = *(const float4*)&bias[c0+4];
    bcol[0]=b0.x; bcol[1]=b0.y; bcol[2]=b0.z; bcol[3]=b0.w;
    bcol[4]=b1.x; bcol[5]=b1.y; bcol[6]=b1.z; bcol[7]=b1.w;
  }
  float acc[8][8];
  #pragma unroll
  for (int r=0;r<8;r++)
    #pragma unroll
    for (int q=0;q<8;q++) acc[r][q] = bcol[q];

  for (int kc=0; kc<4; kc++){
    #pragma unroll
    for (int p=0;p<4;p++){
      int f = tid + 128*p;
      int rr = f >> 3, kq = f & 7;
      int grow = row0 + rr;
      float4 v = (grow < N) ? *(const float4*)&in[(size_t)grow*NB + kc*32 + kq*4]
                            : make_float4(0.f,0.f,0.f,0.f);
      As[kq*4+0][rr] = v.x; As[kq*4+1][rr] = v.y;
      As[kq*4+2][rr] = v.z; As[kq*4+3][rr] = v.w;
    }
    #pragma unroll
    for (int p=0;p<8;p++){
      int f = tid + 128*p;
      int wk = f >> 5, cq = f & 31;
      *(float4*)&Ws[wk][cq*4] = *(const float4*)&W[(size_t)(kc*32+wk)*NB + cq*4];
    }
    __syncthreads();
    #pragma unroll 4
    for (int k=0;k<32;k++){
      float4 a0 = *(const float4*)&As[k][tr*8];
      float4 a1 = *(const float4*)&As[k][tr*8+4];
      float4 w0 = *(const float4*)&Ws[k][c0];
      float4 w1 = *(const float4*)&Ws[k][c0+4];
      float av[8] = {a0.x,a0.y,a0.z,a0.w,a1.x,a1.y,a1.z,a1.w};
      float wv[8] = {w0.x,w0.y,w0.z,w0.w,w1.x,w1.y,w1.z,w1.w};
      #pragma unroll
      for (int r=0;r<8;r++)
        #pragma unroll
        for (int q=0;q<8;q++) acc[r][q] += av[r]*wv[q];
    }
    __syncthreads();
  }
  #pragma unroll
  for (int r=0;r<8;r++){
    int row = row0 + tr*8 + r;
    if (row < N){
      float v[8];
      #pragma unroll
      for (int q=0;q<8;q++) v[q] = (ACT==1) ? sspf(acc[r][q]) : acc[r][q];
      if (RESID){
        float4 o0 = *(const float4*)&out[(size_t)row*NB + c0];
        float4 o1 = *(const float4*)&out[(size_t)row*NB + c0+4];
        v[0]+=o0.x; v[1]+=o0.y; v[2]+=o0.z; v[3]+=o0.w;
        v[4]+=o1.x; v[5]+=o1.y; v[6]+=o1.z; v[7]+=o1.w;
      }
      *(float4*)&out[(size_t)row*NB + c0]   = make_float4(v[0],v[1],v[2],v[3]);
      *(float4*)&out[(size_t)row*NB + c0+4] = make_float4(v[4],v[5],v[6],v[7]);
    }
  }
}

// ---------------- visit2_k: 8-aligned runs, minimal LDS (5 blocks/CU) --------
// We1p/be1p AND We2/be2 read from global (L1/L2-resident broadcast rows).
__launch_bounds__(256, 5)
__global__ void visit2_k(const float* __restrict__ dvis,
                         const int* __restrict__ asrc,
                         const int* __restrict__ tgtv,
                         const float* __restrict__ nodef,
                         const float* __restrict__ We1p, const float* __restrict__ be1p,
                         const float* __restrict__ We2, const float* __restrict__ be2,
                         float* __restrict__ agg, int Vmax){
  __shared__ float buf[NG][NB];     // 25.6 KB : g -> T -> part[16][NB]
  __shared__ float ds_[NB];
  __shared__ int   srcs[NB], tgts[NB];
  __shared__ int   tgt8[16];
  int tid = threadIdx.x;

  int vbase = blockIdx.x * NB;
  if (tid < NB){
    int p = vbase + tid;
    if (p < Vmax){
      srcs[tid] = asrc[p]; tgts[tid] = tgtv[p]; ds_[tid] = dvis[p];
    } else {
      srcs[tid] = 0; tgts[tid] = -1; ds_[tid] = 0.f;
    }
  }
  __syncthreads();
  if (tgts[0] < 0) return;          // fully-padded trailing block (uniform)

  if (tid < 16)  tgt8[tid] = tgts[tid*8];

  // g phase
  for (int idx = tid; idx < NG*NB; idx += 256){
    int m = idx >> 7, e = idx & 127;
    float t = ds_[e] - RBF_STEP * (float)m;
    buf[m][e] = __expf(RBF_COEFF * t * t);
  }
  __syncthreads();

  int te = tid >> 4, tk = tid & 15;
  int e0 = te * 8, k0 = tk * 4;

  // T phase (We1p from global, padded stride 64)
  float tacc[8][4];
  {
    float4 bv = *(const float4*)&be1p[k0];
    float bq[4] = {bv.x,bv.y,bv.z,bv.w};
    #pragma unroll
    for (int r=0;r<8;r++)
      #pragma unroll
      for (int q=0;q<4;q++) tacc[r][q] = bq[q];
  }
  #pragma unroll 2
  for (int m=0;m<NG;m++){
    float4 w  = *(const float4*)&We1p[m*64 + k0];
    float4 g0 = *(const float4*)&buf[m][e0];
    float4 g1 = *(const float4*)&buf[m][e0+4];
    float ge[8] = {g0.x,g0.y,g0.z,g0.w,g1.x,g1.y,g1.z,g1.w};
    float wv[4] = {w.x,w.y,w.z,w.w};
    #pragma unroll
    for (int r=0;r<8;r++)
      #pragma unroll
      for (int q=0;q<4;q++) tacc[r][q] += ge[r]*wv[q];
  }
  __syncthreads();
  #pragma unroll
  for (int q=0;q<4;q++){
    int k = k0 + q;
    if (k < NG){
      float v[8];
      #pragma unroll
      for (int r=0;r<8;r++) v[r] = sspf(tacc[r][q]);
      *(float4*)&buf[k][e0]   = make_float4(v[0],v[1],v[2],v[3]);
      *(float4*)&buf[k][e0+4] = make_float4(v[4],v[5],v[6],v[7]);
    }
  }
  __syncthreads();

  // EF phase (We2 rows from global — broadcast-friendly, L1/L2-resident)
  int c0 = tk * 8;
  float acc[8][8];
  {
    float4 b0 = *(const float4*)&be2[c0];
    float4 b1 = *(const float4*)&be2[c0+4];
    float bq[8] = {b0.x,b0.y,b0.z,b0.w,b1.x,b1.y,b1.z,b1.w};
    #pragma unroll
    for (int r=0;r<8;r++)
      #pragma unroll
      for (int q=0;q<8;q++) acc[r][q] = bq[q];
  }
  #pragma unroll 2
  for (int k=0;k<NG;k++){
    float4 w0 = *(const float4*)&We2[k*NB + c0];
    float4 w1 = *(const float4*)&We2[k*NB + c0+4];
    float4 t0 = *(const float4*)&buf[k][e0];
    float4 t1 = *(const float4*)&buf[k][e0+4];
    float tv[8] = {t0.x,t0.y,t0.z,t0.w,t1.x,t1.y,t1.z,t1.w};
    float wv[8] = {w0.x,w0.y,w0.z,w0.w,w1.x,w1.y,w1.z,w1.w};
    #pragma unroll
    for (int r=0;r<8;r++)
      #pragma unroll
      for (int q=0;q<8;q++) acc[r][q] += tv[r]*wv[q];
  }
  __syncthreads();   // buf reads done; reuse as part[16][NB]

  // group accumulate: all 8 visits in this group share one target (8-aligned)
  float run[8];
  #pragma unroll
  for (int q=0;q<8;q++) run[q] = 0.f;
  #pragma unroll
  for (int r=0;r<8;r++){
    int t = tgts[e0+r];
    int s = srcs[e0+r];
    float4 n0 = *(const float4*)&nodef[(size_t)s*NB + c0];
    float4 n1 = *(const float4*)&nodef[(size_t)s*NB + c0+4];
    float nv[8] = {n0.x,n0.y,n0.z,n0.w,n1.x,n1.y,n1.z,n1.w};
    if (t >= 0){
      #pragma unroll
      for (int q=0;q<8;q++) run[q] += acc[r][q] * nv[q];
    }
  }
  float* part = &buf[0][0];         // part[g][ch] = buf row g
  #pragma unroll
  for (int q=0;q<8;q++) part[te*NB + c0 + q] = run[q];
  __syncthreads();

  // leaders: sum consecutive groups with same target; store/atomic
  int g = te;
  int t = tgt8[g];
  if (t >= 0 && (g == 0 || tgt8[g-1] != t)){
    int gend = g;
    while (gend+1 < 16 && tgt8[gend+1] == t) gend++;
    float s[8];
    #pragma unroll
    for (int q=0;q<8;q++) s[q] = 0.f;
    for (int g2=g; g2<=gend; ++g2)
      #pragma unroll
      for (int q=0;q<8;q++) s[q] += part[g2*NB + c0 + q];
    float* ap = &agg[(size_t)t*NB + c0];
    bool border = (g == 0) || (gend == 15);
    if (border){
      #pragma unroll
      for (int q=0;q<8;q++) atomicAdd(ap+q, s[q]);
    } else {
      *(float4*)ap     = make_float4(s[0],s[1],s[2],s[3]);
      *(float4*)(ap+4) = make_float4(s[4],s[5],s[6],s[7]);
    }
  }
}

// ---------------- visit_k (tier-2 fallback): fragment atomics ----------------
__launch_bounds__(256, 2)
__global__ void visit_k(const float* __restrict__ dvis,
                        const int* __restrict__ asrc,
                        const int* __restrict__ tgtv,
                        const float* __restrict__ nodef,
                        const float* __restrict__ We1, const float* __restrict__ be1,
                        const float* __restrict__ We2, const float* __restrict__ be2,
                        float* __restrict__ agg, int V){
  __shared__ float We1s[NG][64];
  __shared__ float We2s[NG][NB];
  __shared__ float buf[NG][NB];
  __shared__ float be1s[64], be2s[NB];
  __shared__ float ds_[NB];
  __shared__ int   srcs[NB], tgts[NB];
  int tid = threadIdx.x;

  for (int idx = tid; idx < NG*64; idx += 256){
    int m = idx >> 6, k = idx & 63;
    We1s[m][k] = (k < NG) ? We1[m*NG + k] : 0.f;
  }
  for (int idx = tid; idx < NG*NB; idx += 256)
    We2s[0][idx] = We2[idx];
  if (tid < 64)  be1s[tid] = (tid < NG) ? be1[tid] : 0.f;
  if (tid < NB)  be2s[tid] = be2[tid];

  int vbase = blockIdx.x * NB;
  if (tid < NB){
    int p = vbase + tid;
    if (p < V){
      srcs[tid] = asrc[p]; tgts[tid] = tgtv[p]; ds_[tid] = dvis[p];
    } else {
      srcs[tid] = 0; tgts[tid] = -1; ds_[tid] = 0.f;
    }
  }
  __syncthreads();
  for (int idx = tid; idx < NG*NB; idx += 256){
    int m = idx >> 7, e = idx & 127;
    float t = ds_[e] - RBF_STEP * (float)m;
    buf[m][e] = __expf(RBF_COEFF * t * t);
  }
  __syncthreads();
  int te = tid >> 4, tk = tid & 15;
  int e0 = te * 8, k0 = tk * 4;
  float tacc[8][4];
  {
    float4 bv = *(const float4*)&be1s[k0];
    float bq[4] = {bv.x,bv.y,bv.z,bv.w};
    #pragma unroll
    for (int r=0;r<8;r++)
      #pragma unroll
      for (int q=0;q<4;q++) tacc[r][q] = bq[q];
  }
  #pragma unroll 2
  for (int m=0;m<NG;m++){
    float4 w  = *(const float4*)&We1s[m][k0];
    float4 g0 = *(const float4*)&buf[m][e0];
    float4 g1 = *(const float4*)&buf[m][e0+4];
    float ge[8] = {g0.x,g0.y,g0.z,g0.w,g1.x,g1.y,g1.z,g1.w};
    float wv[4] = {w.x,w.y,w.z,w.w};
    #pragma unroll
    for (int r=0;r<8;r++)
      #pragma unroll
      for (int q=0;q<4;q++) tacc[r][q] += ge[r]*wv[q];
  }
  __syncthreads();
  #pragma unroll
  for (int q=0;q<4;q++){
    int k = k0 + q;
    if (k < NG){
      float v[8];
      #pragma unroll
      for (int r=0;r<8;r++) v[r] = sspf(tacc[r][q]);
      *(float4*)&buf[k][e0]   = make_float4(v[0],v[1],v[2],v[3]);
      *(float4*)&buf[k][e0+4] = make_float4(v[4],v[5],v[6],v[7]);
    }
  }
  __syncthreads();
  int c0 = tk * 8;
  float acc[8][8];
  {
    float4 b0 = *(const float4*)&be2s[c0];
    float4 b1 = *(const float4*)&be2s[c0+4];
    float bq[8] = {b0.x,b0.y,b0.z,b0.w,b1.x,b1.y,b1.z,b1.w};
    #pragma unroll
    for (int r=0;r<8;r++)
      #pragma unroll
      for (int q=0;q<8;q++) acc[r][q] = bq[q];
  }
  #pragma unroll 2
  for (int k=0;k<NG;k++){
    float4 w0 = *(const float4*)&We2s[k][c0];
    float4 w1 = *(const float4*)&We2s[k][c0+4];
    float4 t0 = *(const float4*)&buf[k][e0];
    float4 t1 = *(const float4*)&buf[k][e0+4];
    float tv[8] = {t0.x,t0.y,t0.z,t0.w,t1.x,t1.y,t1.z,t1.w};
    float wv[8] = {w0.x,w0.y,w0.z,w0.w,w1.x,w1.y,w1.z,w1.w};
    #pragma unroll
    for (int r=0;r<8;r++)
      #pragma unroll
      for (int q=0;q<8;q++) acc[r][q] += tv[r]*wv[q];
  }
  int   curtgt = tgts[e0];
  float run[8];
  #pragma unroll
  for (int q=0;q<8;q++) run[q] = 0.f;
  #pragma unroll
  for (int r=0;r<8;r++){
    int t = tgts[e0+r];
    int s = srcs[e0+r];
    float4 n0 = *(const float4*)&nodef[(size_t)s*NB + c0];
    float4 n1 = *(const float4*)&nodef[(size_t)s*NB + c0+4];
    float nv[8] = {n0.x,n0.y,n0.z,n0.w,n1.x,n1.y,n1.z,n1.w};
    if (t != curtgt){
      if (curtgt >= 0){
        float* ap = &agg[(size_t)curtgt*NB + c0];
        #pragma unroll
        for (int q=0;q<8;q++) atomicAdd(ap+q, run[q]);
      }
      curtgt = t;
      #pragma unroll
      for (int q=0;q<8;q++) run[q] = 0.f;
    }
    if (t >= 0){
      #pragma unroll
      for (int q=0;q<8;q++) run[q] += acc[r][q] * nv[q];
    }
  }
  if (curtgt >= 0){
    float* ap = &agg[(size_t)curtgt*NB + c0];
    #pragma unroll
    for (int q=0;q<8;q++) atomicAdd(ap+q, run[q]);
  }
}

// ---------------- legacy atomic edge kernel (last-resort fallback) -----------
__launch_bounds__(256, 2)
__global__ void edge_k(const float* __restrict__ dists, const int* __restrict__ a,
                       const float* __restrict__ nodef,
                       const float* __restrict__ We1, const float* __restrict__ be1,
                       const float* __restrict__ We2, const float* __restrict__ be2,
                       float* __restrict__ agg, int E){
  __shared__ float We1s[NG][64];
  __shared__ float We2s[NG][NB];
  __shared__ float buf[NG][NB];
  __shared__ float be1s[64], be2s[NB];
  __shared__ float ds_[NB];
  __shared__ int   ijs[2*NB];
  int tid = threadIdx.x;

  for (int idx = tid; idx < NG*64; idx += 256){
    int m = idx >> 6, k = idx & 63;
    We1s[m][k] = (k < NG) ? We1[m*NG + k] : 0.f;
  }
  for (int idx = tid; idx < NG*NB; idx += 256)
    We2s[0][idx] = We2[idx];
  if (tid < 64)  be1s[tid] = (tid < NG) ? be1[tid] : 0.f;
  if (tid < NB)  be2s[tid] = be2[tid];

  int ebase = blockIdx.x * NB;
  if (tid < NB){
    int e = ebase + tid;
    if (e < E){ ds_[tid] = dists[e]; ijs[2*tid] = a[2*e]; ijs[2*tid+1] = a[2*e+1]; }
    else      { ds_[tid] = 0.f;      ijs[2*tid] = -1;     ijs[2*tid+1] = -1; }
  }
  __syncthreads();
  for (int idx = tid; idx < NG*NB; idx += 256){
    int m = idx >> 7, e = idx & 127;
    float t = ds_[e] - RBF_STEP * (float)m;
    buf[m][e] = __expf(RBF_COEFF * t * t);
  }
  __syncthreads();
  int te = tid >> 4, tk = tid & 15;
  int e0 = te * 8, k0 = tk * 4;
  float tacc[8][4];
  {
    float4 bv = *(const float4*)&be1s[k0];
    float bq[4] = {bv.x,bv.y,bv.z,bv.w};
    #pragma unroll
    for (int r=0;r<8;r++)
      #pragma unroll
      for (int q=0;q<4;q++) tacc[r][q] = bq[q];
  }
  #pragma unroll 2
  for (int m=0;m<NG;m++){
    float4 w  = *(const float4*)&We1s[m][k0];
    float4 g0 = *(const float4*)&buf[m][e0];
    float4 g1 = *(const float4*)&buf[m][e0+4];
    float ge[8] = {g0.x,g0.y,g0.z,g0.w,g1.x,g1.y,g1.z,g1.w};
    float wv[4] = {w.x,w.y,w.z,w.w};
    #pragma unroll
    for (int r=0;r<8;r++)
      #pragma unroll
      for (int q=0;q<4;q++) tacc[r][q] += ge[r]*wv[q];
  }
  __syncthreads();
  #pragma unroll
  for (int q=0;q<4;q++){
    int k = k0 + q;
    if (k < NG){
      float v[8];
      #pragma unroll
      for (int r=0;r<8;r++) v[r] = sspf(tacc[r][q]);
      *(float4*)&buf[k][e0]   = make_float4(v[0],v[1],v[2],v[3]);
      *(float4*)&buf[k][e0+4] = make_float4(v[4],v[5],v[6],v[7]);
    }
  }
  __syncthreads();
  int c0 = tk * 8;
  float acc[8][8];
  {
    float4 b0 = *(const float4*)&be2s[c0];
    float4 b1 = *(const float4*)&be2s[c0+4];
    float bq[8] = {b0.x,b0.y,b0.z,b0.w,b1.x,b1.y,b1.z,b1.w};
    #pragma unroll
    for (int r=0;r<8;r++)
      #pragma unroll
      for (int q=0;q<8;q++) acc[r][q] = bq[q];
  }
  #pragma unroll 2
  for (int k=0;k<NG;k++){
    float4 w0 = *(const float4*)&We2s[k][c0];
    float4 w1 = *(const float4*)&We2s[k][c0+4];
    float4 t0 = *(const float4*)&buf[k][e0];
    float4 t1 = *(const float4*)&buf[k][e0+4];
    float tv[8] = {t0.x,t0.y,t0.z,t0.w,t1.x,t1.y,t1.z,t1.w};
    float wv[8] = {w0.x,w0.y,w0.z,w0.w,w1.x,w1.y,w1.z,w1.w};
    #pragma unroll
    for (int r=0;r<8;r++)
      #pragma unroll
      for (int q=0;q<8;q++) acc[r][q] += tv[r]*wv[q];
  }
  #pragma unroll
  for (int r=0;r<8;r++){
    int el = e0 + r;
    int i = ijs[2*el], j = ijs[2*el+1];
    if (i < 0) continue;
    float4 nj0 = *(const float4*)&nodef[(size_t)j*NB + c0];
    float4 nj1 = *(const float4*)&nodef[(size_t)j*NB + c0+4];
    float4 ni0 = *(const float4*)&nodef[(size_t)i*NB + c0];
    float4 ni1 = *(const float4*)&nodef[(size_t)i*NB + c0+4];
    float* ai = &agg[(size_t)i*NB + c0];
    float* aj = &agg[(size_t)j*NB + c0];
    float njv[8] = {nj0.x,nj0.y,nj0.z,nj0.w,nj1.x,nj1.y,nj1.z,nj1.w};
    float niv[8] = {ni0.x,ni0.y,ni0.z,ni0.w,ni1.x,ni1.y,ni1.z,ni1.w};
    #pragma unroll
    for (int q=0;q<8;q++){
      atomicAdd(ai+q, njv[q]*acc[r][q]);
      atomicAdd(aj+q, niv[q]*acc[r][q]);
    }
  }
}

// ---------------- readout: e = ssp(h@W1+b1)@W2+b2, molecule segment sum ------
__launch_bounds__(128, 3)
__global__ void readout_k(const float* __restrict__ h, const float* __restrict__ W1,
                          const float* __restrict__ b1, const float* __restrict__ W2,
                          const float* __restrict__ b2, const int* __restrict__ molp,
                          float* __restrict__ out, int N){
  __shared__ float As[32][64];
  __shared__ float W1s[32][64];
  __shared__ float segsum[2];
  int tid = threadIdx.x;
  int tc = tid & 15, tr = tid >> 4;
  int row0 = blockIdx.x * 64;
  int c0 = tc * 4;

  float acc[8][4];
  {
    float4 bv = *(const float4*)&b1[c0];
    float bq[4] = {bv.x,bv.y,bv.z,bv.w};
    #pragma unroll
    for (int r=0;r<8;r++)
      #pragma unroll
      for (int q=0;q<4;q++) acc[r][q] = bq[q];
  }
  for (int kc=0;kc<4;kc++){
    #pragma unroll
    for (int p=0;p<4;p++){
      int f = tid + 128*p; int rr = f >> 3; int kq = f & 7;
      int grow = row0 + rr;
      float4 v = (grow < N) ? *(const float4*)&h[(size_t)grow*NB + kc*32 + kq*4]
                            : make_float4(0.f,0.f,0.f,0.f);
      As[kq*4+0][rr] = v.x; As[kq*4+1][rr] = v.y;
      As[kq*4+2][rr] = v.z; As[kq*4+3][rr] = v.w;
    }
    #pragma unroll
    for (int p=0;p<4;p++){
      int f = tid + 128*p; int wk = f >> 4; int cq = f & 15;
      *(float4*)&W1s[wk][cq*4] = *(const float4*)&W1[(size_t)(kc*32+wk)*64 + cq*4];
    }
    __syncthreads();
    #pragma unroll 4
    for (int k=0;k<32;k++){
      float4 a0 = *(const float4*)&As[k][tr*8];
      float4 a1 = *(const float4*)&As[k][tr*8+4];
      float4 w  = *(const float4*)&W1s[k][c0];
      float av[8] = {a0.x,a0.y,a0.z,a0.w,a1.x,a1.y,a1.z,a1.w};
      float wv[4] = {w.x,w.y,w.z,w.w};
      #pragma unroll
      for (int r=0;r<8;r++)
        #pragma unroll
        for (int q=0;q<4;q++) acc[r][q] += av[r]*wv[q];
    }
    __syncthreads();
  }
  float4 w2f = *(const float4*)&W2[c0];
  float part[8];
  #pragma unroll
  for (int r=0;r<8;r++)
    part[r] = sspf(acc[r][0])*w2f.x + sspf(acc[r][1])*w2f.y +
              sspf(acc[r][2])*w2f.z + sspf(acc[r][3])*w2f.w;
  #pragma unroll
  for (int off=1; off<16; off<<=1)
    #pragma unroll
    for (int r=0;r<8;r++) part[r] += __shfl_xor(part[r], off);

  if (tid < 2) segsum[tid] = 0.f;
  __syncthreads();
  int ms = molp[0];
  float b2v = b2[0];
  int seg0 = row0 / ms;
  if (tc == 0){
    #pragma unroll
    for (int r=0;r<8;r++){
      int row = row0 + tr*8 + r;
      if (row < N){
        int s = row/ms - seg0;
        if (s < 2) atomicAdd(&segsum[s], part[r] + b2v);
        else       atomicAdd(&out[row/ms], part[r] + b2v);
      }
    }
  }
  __syncthreads();
  if (tid == 0 && segsum[0] != 0.f) atomicAdd(&out[seg0], segsum[0]);
  if (tid == 1){
    int lastrow = row0 + 63; if (lastrow > N-1) lastrow = N-1;
    if (lastrow/ms > seg0 && segsum[1] != 0.f) atomicAdd(&out[seg0+1], segsum[1]);
  }
}

extern "C" void kernel_launch(void* const* d_in, const int* in_sizes, int n_in,
                              void* d_out, int out_size, void* d_ws, size_t ws_size,
                              hipStream_t stream){
  const int*   r     = (const int*)  d_in[0];
  const float* xyz   = (const float*)d_in[1];
  const int*   a     = (const int*)  d_in[2];
  const int*   molp  = (const int*)  d_in[3];
  const float* embed = (const float*)d_in[4];
  const float* Wn    = (const float*)d_in[5];
  const float* bn    = (const float*)d_in[6];
  const float* We1   = (const float*)d_in[7];
  const float* be1   = (const float*)d_in[8];
  const float* We2   = (const float*)d_in[9];
  const float* be2   = (const float*)d_in[10];
  const float* Wu1   = (const float*)d_in[11];
  const float* bu1   = (const float*)d_in[12];
  const float* Wu2   = (const float*)d_in[13];
  const float* bu2   = (const float*)d_in[14];
  const float* W1    = (const float*)d_in[15];
  const float* b1    = (const float*)d_in[16];
  const float* W2    = (const float*)d_in[17];
  const float* b2    = (const float*)d_in[18];

  int N = in_sizes[0];          // 50000
  int E = in_sizes[2] / 2;      // 500000
  int V = 2*E;                  // directed visits
  size_t VmaxS = (size_t)V + 8*(size_t)N;   // 8-pad worst case

  float* ws   = (float*)d_ws;
  size_t E4   = ((size_t)E + 3) & ~(size_t)3;
  size_t NSZ  = (size_t)N * NB;
  size_t RPAD = ((size_t)N + 1 + 3) & ~(size_t)3;
  size_t NPAD = ((size_t)N + 3) & ~(size_t)3;
  size_t base = E4 + 3*NSZ;
  size_t WPAD = 3*NG*64 + 3*64;   // We1p + be1p

  // tier1: rowptr|cnt|pcnt|cur|bsum|boff | asrc,tgtv (int, VmaxS each) | dvis (float) | We1p,be1p
  size_t need1 = (base + RPAD + 3*NPAD + 512 + 3*VmaxS + WPAD) * sizeof(float);
  // tier2: rowptr|cnt|cur|bsum|boff | asrc,tgtv,dvis (V each)
  size_t need2 = (base + RPAD + 2*NPAD + 512 + 3*(size_t)V) * sizeof(float);

  float* dbuf  = ws;
  float* h     = dbuf + E4;
  float* nodef = h + NSZ;
  float* agg   = nodef + NSZ;

  int gblocks = (N + 63)/64;
  int eblocks = (E + 127)/128;
  int nb = (N + SCAN_TILE - 1) / SCAN_TILE;

  embed_k<<<(N*32 + 255)/256, 256, 0, stream>>>(r, embed, h, N);
  dist_k <<<(E + 255)/256,    256, 0, stream>>>(a, xyz, dbuf, E);

  if (ws_size >= need1){
    int*   rowptr = (int*)(agg + NSZ);
    int*   cnt    = rowptr + RPAD;
    int*   pcnt   = cnt + NPAD;
    int*   cur    = pcnt + NPAD;
    int*   bsum   = cur + NPAD;
    int*   boff   = bsum + 256;
    int*   asrc   = boff + 256;
    int*   tgtv   = asrc + VmaxS;
    float* dvis   = (float*)(tgtv + VmaxS);
    float* We1p   = dvis + VmaxS;
    float* be1p   = We1p + 3*NG*64;

    (void)hipMemsetAsync(cnt, 0, (size_t)N*sizeof(int), stream);
    (void)hipMemsetAsync(asrc, 0, VmaxS*sizeof(int), stream);
    (void)hipMemsetAsync(tgtv, 0xFF, VmaxS*sizeof(int), stream);
    (void)hipMemsetAsync(dvis, 0, VmaxS*sizeof(float), stream);
    padw_k  <<<(3*NG*64 + 255)/256, 256, 0, stream>>>(We1, be1, We1p, be1p);
    hist_k  <<<(E + 255)/256, 256, 0, stream>>>(a, cnt, E);
    pad_k   <<<(N + 255)/256, 256, 0, stream>>>(cnt, pcnt, N);
    reduce_k<<<nb, 256, 0, stream>>>(pcnt, bsum, N);
    scanb_k <<<1, 64, 0, stream>>>(bsum, boff, nb);
    scan2_k <<<nb, 256, 0, stream>>>(pcnt, boff, rowptr, N, 0);
    copy_k  <<<(N + 255)/256, 256, 0, stream>>>(rowptr, cur, N);
    fill_k  <<<(E + 255)/256, 256, 0, stream>>>(a, dbuf, cur, asrc, dvis, tgtv, E);

    int vblocks = (int)((VmaxS + 127)/128);
    for (int l = 0; l < 3; l++){
      gemm128_k<0,0><<<gblocks, 128, 0, stream>>>(h, Wn + (size_t)l*NB*NB, bn + l*NB, nodef, N);
      (void)hipMemsetAsync(agg, 0, NSZ*sizeof(float), stream);
      visit2_k<<<vblocks, 256, 0, stream>>>(dvis, asrc, tgtv, nodef,
                                            We1p + (size_t)l*NG*64, be1p + (size_t)l*64,
                                            We2 + (size_t)l*NG*NB, be2 + l*NB, agg, (int)VmaxS);
      gemm128_k<1,0><<<gblocks, 128, 0, stream>>>(agg,   Wu1 + (size_t)l*NB*NB, bu1 + l*NB, nodef, N);
      gemm128_k<0,1><<<gblocks, 128, 0, stream>>>(nodef, Wu2 + (size_t)l*NB*NB, bu2 + l*NB, h, N);
    }
  } else if (ws_size >= need2){
    int*   rowptr = (int*)(agg + NSZ);
    int*   cnt    = rowptr + RPAD;
    int*   cur    = cnt + NPAD;
    int*   bsum   = cur + NPAD;
    int*   boff   = bsum + 256;
    int*   asrc   = boff + 256;
    int*   tgtv   = asrc + V;
    float* dvis   = (float*)(tgtv + V);

    (void)hipMemsetAsync(cnt, 0, (size_t)N*sizeof(int), stream);
    hist_k  <<<(E + 255)/256, 256, 0, stream>>>(a, cnt, E);
    reduce_k<<<nb, 256, 0, stream>>>(cnt, bsum, N);
    scanb_k <<<1, 64, 0, stream>>>(bsum, boff, nb);
    scan2_k <<<nb, 256, 0, stream>>>(cnt, boff, rowptr, N, V);
    copy_k  <<<(N + 255)/256, 256, 0, stream>>>(rowptr, cur, N);
    fill_k  <<<(E + 255)/256, 256, 0, stream>>>(a, dbuf, cur, asrc, dvis, tgtv, E);

    int vblocks = (V + 127)/128;
    for (int l = 0; l < 3; l++){
      gemm128_k<0,0><<<gblocks, 128, 0, stream>>>(h, Wn + (size_t)l*NB*NB, bn + l*NB, nodef, N);
      (void)hipMemsetAsync(agg, 0, NSZ*sizeof(float), stream);
      visit_k<<<vblocks, 256, 0, stream>>>(dvis, asrc, tgtv, nodef,
                                           We1 + (size_t)l*NG*NG, be1 + l*NG,
                                           We2 + (size_t)l*NG*NB, be2 + l*NB, agg, V);
      gemm128_k<1,0><<<gblocks, 128, 0, stream>>>(agg,   Wu1 + (size_t)l*NB*NB, bu1 + l*NB, nodef, N);
      gemm128_k<0,1><<<gblocks, 128, 0, stream>>>(nodef, Wu2 + (size_t)l*NB*NB, bu2 + l*NB, h, N);
    }
  } else {
    for (int l = 0; l < 3; l++){
      gemm128_k<0,0><<<gblocks, 128, 0, stream>>>(h, Wn + (size_t)l*NB*NB, bn + l*NB, nodef, N);
      (void)hipMemsetAsync(agg, 0, NSZ*sizeof(float), stream);
      edge_k<<<eblocks, 256, 0, stream>>>(dbuf, a, nodef,
                                          We1 + (size_t)l*NG*NG, be1 + l*NG,
                                          We2 + (size_t)l*NG*NB, be2 + l*NB, agg, E);
      gemm128_k<1,0><<<gblocks, 128, 0, stream>>>(agg,   Wu1 + (size_t)l*NB*NB, bu1 + l*NB, nodef, N);
      gemm128_k<0,1><<<gblocks, 128, 0, stream>>>(nodef, Wu2 + (size_t)l*NB*NB, bu2 + l*NB, h, N);
    }
  }

  (void)hipMemsetAsync(d_out, 0, (size_t)out_size*sizeof(float), stream);
  readout_k<<<gblocks, 128, 0, stream>>>(h, W1, b1, W2, b2, molp, (float*)d_out, N);
}

// Round 12
// 1473.110 us; speedup vs baseline: 7.3191x; 1.0180x over previous
//
#include <hip/hip_runtime.h>
#include <hip/hip_bf16.h>

#define NG 50
#define NB 128

__device__ __forceinline__ float sspf(float x){
  float t = __expf(-fabsf(x));
  return fmaxf(x, 0.f) + __logf(1.f + t) - 0.6931471805599453094f;
}

constexpr float RBF_STEP  = 5.0f / 49.0f;
constexpr float RBF_COEFF = -0.5f / (RBF_STEP * RBF_STEP);

// ---------------- h = embed[r] ----------------
__global__ void embed_k(const int* __restrict__ r, const float* __restrict__ embed,
                        float* __restrict__ h, int N){
  int idx = blockIdx.x * blockDim.x + threadIdx.x;
  if (idx < N * 32){
    int n = idx >> 5, c = (idx & 31) * 4;
    *(float4*)&h[(size_t)n * NB + c] = *(const float4*)&embed[(size_t)r[n] * NB + c];
  }
}

// ---------------- per-edge distance ----------------
__global__ void dist_k(const int* __restrict__ a, const float* __restrict__ xyz,
                       float* __restrict__ d, int E){
  int e = blockIdx.x * blockDim.x + threadIdx.x;
  if (e < E){
    int i = a[2*e], j = a[2*e+1];
    float dx = xyz[3*i+0] - xyz[3*j+0];
    float dy = xyz[3*i+1] - xyz[3*j+1];
    float dz = xyz[3*i+2] - xyz[3*j+2];
    d[e] = sqrtf(dx*dx + dy*dy + dz*dz);
  }
}

// ---------------- pad We1/be1 into [50][64] / [64] per layer ----------------
__global__ void padw_k(const float* __restrict__ We1, const float* __restrict__ be1,
                       float* __restrict__ We1p, float* __restrict__ be1p){
  int idx = blockIdx.x*blockDim.x + threadIdx.x;
  if (idx < 3*NG*64){
    int l = idx/(NG*64), rem = idx%(NG*64), m = rem>>6, k = rem&63;
    We1p[idx] = (k < NG) ? We1[((size_t)l*NG + m)*NG + k] : 0.f;
  }
  if (idx < 3*64){
    int l = idx>>6, k = idx&63;
    be1p[idx] = (k < NG) ? be1[l*NG + k] : 0.f;
  }
}

// ================= CSR build =================
__global__ void hist_k(const int* __restrict__ a, int* __restrict__ cnt, int E){
  int e = blockIdx.x * blockDim.x + threadIdx.x;
  if (e < E){
    atomicAdd(&cnt[a[2*e]],   1);
    atomicAdd(&cnt[a[2*e+1]], 1);
  }
}

__global__ void pad_k(const int* __restrict__ cnt, int* __restrict__ pcnt, int N){
  int i = blockIdx.x*blockDim.x + threadIdx.x;
  if (i < N) pcnt[i] = (cnt[i] + 7) & ~7;
}

#define SCAN_TILE 512
__global__ void reduce_k(const int* __restrict__ cnt, int* __restrict__ bsum, int N){
  __shared__ int s[256];
  int b = blockIdx.x, t = threadIdx.x;
  int i0 = b*SCAN_TILE + t;
  int v = 0;
  if (i0 < N)       v += cnt[i0];
  if (i0+256 < N)   v += cnt[i0+256];
  s[t] = v; __syncthreads();
  for (int o=128;o>0;o>>=1){ if (t<o) s[t]+=s[t+o]; __syncthreads(); }
  if (t==0) bsum[b] = s[0];
}

__global__ void scanb_k(const int* __restrict__ bsum, int* __restrict__ boff, int nb){
  if (threadIdx.x==0 && blockIdx.x==0){
    int acc = 0;
    for (int i=0;i<nb;i++){ boff[i]=acc; acc+=bsum[i]; }
  }
}

__global__ void scan2_k(const int* __restrict__ cnt, const int* __restrict__ boff,
                        int* __restrict__ rowptr, int N, int total){
  __shared__ int s[256];
  int b = blockIdx.x, t = threadIdx.x;
  int i0 = b*SCAN_TILE;
  int a0 = (i0+2*t   < N) ? cnt[i0+2*t]   : 0;
  int a1 = (i0+2*t+1 < N) ? cnt[i0+2*t+1] : 0;
  int pair = a0 + a1;
  s[t] = pair; __syncthreads();
  for (int o=1;o<256;o<<=1){
    int v = (t>=o) ? s[t-o] : 0;
    __syncthreads();
    s[t] += v;
    __syncthreads();
  }
  int excl = s[t] - pair + boff[b];
  if (i0+2*t   < N) rowptr[i0+2*t]   = excl;
  if (i0+2*t+1 < N) rowptr[i0+2*t+1] = excl + a0;
  if (b==0 && t==0) rowptr[N] = total;
}

__global__ void copy_k(const int* __restrict__ src, int* __restrict__ dst, int n){
  int i = blockIdx.x*blockDim.x + threadIdx.x;
  if (i < n) dst[i] = src[i];
}

// visit list (SoA): asrc[p]=source node, dvis[p]=edge distance, tgtv[p]=target
__global__ void fill_k(const int* __restrict__ a, const float* __restrict__ dists,
                       int* __restrict__ cur,
                       int* __restrict__ asrc, float* __restrict__ dvis,
                       int* __restrict__ tgtv, int E){
  int e = blockIdx.x*blockDim.x + threadIdx.x;
  if (e < E){
    int i = a[2*e], j = a[2*e+1];
    float d = dists[e];
    int p = atomicAdd(&cur[i], 1);
    asrc[p] = j; dvis[p] = d; tgtv[p] = i;
    int q = atomicAdd(&cur[j], 1);
    asrc[q] = i; dvis[q] = d; tgtv[q] = j;
  }
}

// ------- gemm256_k: (N x 128) @ (128 x 128) + b, opt ssp, opt residual -------
// 256 threads, 128x128 tile, 16x16 thread grid, 8x8 acc per thread.
// As padded [32][132] (conflict-reduced transposed stores). 4 blocks/CU.
template<int ACT, int RESID>
__launch_bounds__(256, 4)
__global__ void gemm256_k(const float* __restrict__ in, const float* __restrict__ W,
                          const float* __restrict__ bias, float* __restrict__ out, int N){
  __shared__ float As[32][132];   // 16.9 KB, transposed: As[k][row]
  __shared__ float Ws[32][128];   // 16 KB
  int tid = threadIdx.x;
  int tc = tid & 15, tr = tid >> 4;     // 16x16; each thread 8 rows x 8 cols
  int row0 = blockIdx.x * 128;
  int c0 = tc * 8;

  float bcol[8];
  {
    float4 b0 = *(const float4*)&bias[c0];
    float4 b1 = *(const float4*)&bias[c0+4];
    bcol[0]=b0.x; bcol[1]=b0.y; bcol[2]=b0.z; bcol[3]=b0.w;
    bcol[4]=b1.x; bcol[5]=b1.y; bcol[6]=b1.z; bcol[7]=b1.w;
  }
  float acc[8][8];
  #pragma unroll
  for (int r=0;r<8;r++)
    #pragma unroll
    for (int q=0;q<8;q++) acc[r][q] = bcol[q];

  for (int kc=0; kc<4; kc++){
    // stage A chunk (128 rows x 32 k), transposed into LDS
    #pragma unroll
    for (int p=0;p<4;p++){
      int f = tid + 256*p;            // 0..1023
      int rr = f >> 3, kq = f & 7;
      int grow = row0 + rr;
      float4 v = (grow < N) ? *(const float4*)&in[(size_t)grow*NB + kc*32 + kq*4]
                            : make_float4(0.f,0.f,0.f,0.f);
      As[kq*4+0][rr] = v.x; As[kq*4+1][rr] = v.y;
      As[kq*4+2][rr] = v.z; As[kq*4+3][rr] = v.w;
    }
    // stage W chunk (32 k x 128 cols)
    #pragma unroll
    for (int p=0;p<4;p++){
      int f = tid + 256*p;            // 0..1023
      int wk = f >> 5, cq = f & 31;
      *(float4*)&Ws[wk][cq*4] = *(const float4*)&W[(size_t)(kc*32+wk)*NB + cq*4];
    }
    __syncthreads();
    #pragma unroll 4
    for (int k=0;k<32;k++){
      float4 a0 = *(const float4*)&As[k][tr*8];
      float4 a1 = *(const float4*)&As[k][tr*8+4];
      float4 w0 = *(const float4*)&Ws[k][c0];
      float4 w1 = *(const float4*)&Ws[k][c0+4];
      float av[8] = {a0.x,a0.y,a0.z,a0.w,a1.x,a1.y,a1.z,a1.w};
      float wv[8] = {w0.x,w0.y,w0.z,w0.w,w1.x,w1.y,w1.z,w1.w};
      #pragma unroll
      for (int r=0;r<8;r++)
        #pragma unroll
        for (int q=0;q<8;q++) acc[r][q] += av[r]*wv[q];
    }
    __syncthreads();
  }
  #pragma unroll
  for (int r=0;r<8;r++){
    int row = row0 + tr*8 + r;
    if (row < N){
      float v[8];
      #pragma unroll
      for (int q=0;q<8;q++) v[q] = (ACT==1) ? sspf(acc[r][q]) : acc[r][q];
      if (RESID){
        float4 o0 = *(const float4*)&out[(size_t)row*NB + c0];
        float4 o1 = *(const float4*)&out[(size_t)row*NB + c0+4];
        v[0]+=o0.x; v[1]+=o0.y; v[2]+=o0.z; v[3]+=o0.w;
        v[4]+=o1.x; v[5]+=o1.y; v[6]+=o1.z; v[7]+=o1.w;
      }
      *(float4*)&out[(size_t)row*NB + c0]   = make_float4(v[0],v[1],v[2],v[3]);
      *(float4*)&out[(size_t)row*NB + c0+4] = make_float4(v[4],v[5],v[6],v[7]);
    }
  }
}

// ---------------- visit2_k: 8-aligned runs, minimal LDS (5 blocks/CU) --------
__launch_bounds__(256, 5)
__global__ void visit2_k(const float* __restrict__ dvis,
                         const int* __restrict__ asrc,
                         const int* __restrict__ tgtv,
                         const float* __restrict__ nodef,
                         const float* __restrict__ We1p, const float* __restrict__ be1p,
                         const float* __restrict__ We2, const float* __restrict__ be2,
                         float* __restrict__ agg, int Vmax){
  __shared__ float buf[NG][NB];     // 25.6 KB : g -> T -> part[16][NB]
  __shared__ float ds_[NB];
  __shared__ int   srcs[NB], tgts[NB];
  __shared__ int   tgt8[16];
  int tid = threadIdx.x;

  int vbase = blockIdx.x * NB;
  if (tid < NB){
    int p = vbase + tid;
    if (p < Vmax){
      srcs[tid] = asrc[p]; tgts[tid] = tgtv[p]; ds_[tid] = dvis[p];
    } else {
      srcs[tid] = 0; tgts[tid] = -1; ds_[tid] = 0.f;
    }
  }
  __syncthreads();
  if (tgts[0] < 0) return;          // fully-padded trailing block (uniform)

  if (tid < 16)  tgt8[tid] = tgts[tid*8];

  for (int idx = tid; idx < NG*NB; idx += 256){
    int m = idx >> 7, e = idx & 127;
    float t = ds_[e] - RBF_STEP * (float)m;
    buf[m][e] = __expf(RBF_COEFF * t * t);
  }
  __syncthreads();

  int te = tid >> 4, tk = tid & 15;
  int e0 = te * 8, k0 = tk * 4;

  float tacc[8][4];
  {
    float4 bv = *(const float4*)&be1p[k0];
    float bq[4] = {bv.x,bv.y,bv.z,bv.w};
    #pragma unroll
    for (int r=0;r<8;r++)
      #pragma unroll
      for (int q=0;q<4;q++) tacc[r][q] = bq[q];
  }
  #pragma unroll 2
  for (int m=0;m<NG;m++){
    float4 w  = *(const float4*)&We1p[m*64 + k0];
    float4 g0 = *(const float4*)&buf[m][e0];
    float4 g1 = *(const float4*)&buf[m][e0+4];
    float ge[8] = {g0.x,g0.y,g0.z,g0.w,g1.x,g1.y,g1.z,g1.w};
    float wv[4] = {w.x,w.y,w.z,w.w};
    #pragma unroll
    for (int r=0;r<8;r++)
      #pragma unroll
      for (int q=0;q<4;q++) tacc[r][q] += ge[r]*wv[q];
  }
  __syncthreads();
  #pragma unroll
  for (int q=0;q<4;q++){
    int k = k0 + q;
    if (k < NG){
      float v[8];
      #pragma unroll
      for (int r=0;r<8;r++) v[r] = sspf(tacc[r][q]);
      *(float4*)&buf[k][e0]   = make_float4(v[0],v[1],v[2],v[3]);
      *(float4*)&buf[k][e0+4] = make_float4(v[4],v[5],v[6],v[7]);
    }
  }
  __syncthreads();

  int c0 = tk * 8;
  float acc[8][8];
  {
    float4 b0 = *(const float4*)&be2[c0];
    float4 b1 = *(const float4*)&be2[c0+4];
    float bq[8] = {b0.x,b0.y,b0.z,b0.w,b1.x,b1.y,b1.z,b1.w};
    #pragma unroll
    for (int r=0;r<8;r++)
      #pragma unroll
      for (int q=0;q<8;q++) acc[r][q] = bq[q];
  }
  #pragma unroll 2
  for (int k=0;k<NG;k++){
    float4 w0 = *(const float4*)&We2[k*NB + c0];
    float4 w1 = *(const float4*)&We2[k*NB + c0+4];
    float4 t0 = *(const float4*)&buf[k][e0];
    float4 t1 = *(const float4*)&buf[k][e0+4];
    float tv[8] = {t0.x,t0.y,t0.z,t0.w,t1.x,t1.y,t1.z,t1.w};
    float wv[8] = {w0.x,w0.y,w0.z,w0.w,w1.x,w1.y,w1.z,w1.w};
    #pragma unroll
    for (int r=0;r<8;r++)
      #pragma unroll
      for (int q=0;q<8;q++) acc[r][q] += tv[r]*wv[q];
  }
  __syncthreads();   // buf reads done; reuse as part[16][NB]

  float run[8];
  #pragma unroll
  for (int q=0;q<8;q++) run[q] = 0.f;
  #pragma unroll
  for (int r=0;r<8;r++){
    int t = tgts[e0+r];
    int s = srcs[e0+r];
    float4 n0 = *(const float4*)&nodef[(size_t)s*NB + c0];
    float4 n1 = *(const float4*)&nodef[(size_t)s*NB + c0+4];
    float nv[8] = {n0.x,n0.y,n0.z,n0.w,n1.x,n1.y,n1.z,n1.w};
    if (t >= 0){
      #pragma unroll
      for (int q=0;q<8;q++) run[q] += acc[r][q] * nv[q];
    }
  }
  float* part = &buf[0][0];
  #pragma unroll
  for (int q=0;q<8;q++) part[te*NB + c0 + q] = run[q];
  __syncthreads();

  int g = te;
  int t = tgt8[g];
  if (t >= 0 && (g == 0 || tgt8[g-1] != t)){
    int gend = g;
    while (gend+1 < 16 && tgt8[gend+1] == t) gend++;
    float s[8];
    #pragma unroll
    for (int q=0;q<8;q++) s[q] = 0.f;
    for (int g2=g; g2<=gend; ++g2)
      #pragma unroll
      for (int q=0;q<8;q++) s[q] += part[g2*NB + c0 + q];
    float* ap = &agg[(size_t)t*NB + c0];
    bool border = (g == 0) || (gend == 15);
    if (border){
      #pragma unroll
      for (int q=0;q<8;q++) atomicAdd(ap+q, s[q]);
    } else {
      *(float4*)ap     = make_float4(s[0],s[1],s[2],s[3]);
      *(float4*)(ap+4) = make_float4(s[4],s[5],s[6],s[7]);
    }
  }
}

// ---------------- visit_k (tier-2 fallback): fragment atomics ----------------
__launch_bounds__(256, 2)
__global__ void visit_k(const float* __restrict__ dvis,
                        const int* __restrict__ asrc,
                        const int* __restrict__ tgtv,
                        const float* __restrict__ nodef,
                        const float* __restrict__ We1, const float* __restrict__ be1,
                        const float* __restrict__ We2, const float* __restrict__ be2,
                        float* __restrict__ agg, int V){
  __shared__ float We1s[NG][64];
  __shared__ float We2s[NG][NB];
  __shared__ float buf[NG][NB];
  __shared__ float be1s[64], be2s[NB];
  __shared__ float ds_[NB];
  __shared__ int   srcs[NB], tgts[NB];
  int tid = threadIdx.x;

  for (int idx = tid; idx < NG*64; idx += 256){
    int m = idx >> 6, k = idx & 63;
    We1s[m][k] = (k < NG) ? We1[m*NG + k] : 0.f;
  }
  for (int idx = tid; idx < NG*NB; idx += 256)
    We2s[0][idx] = We2[idx];
  if (tid < 64)  be1s[tid] = (tid < NG) ? be1[tid] : 0.f;
  if (tid < NB)  be2s[tid] = be2[tid];

  int vbase = blockIdx.x * NB;
  if (tid < NB){
    int p = vbase + tid;
    if (p < V){
      srcs[tid] = asrc[p]; tgts[tid] = tgtv[p]; ds_[tid] = dvis[p];
    } else {
      srcs[tid] = 0; tgts[tid] = -1; ds_[tid] = 0.f;
    }
  }
  __syncthreads();
  for (int idx = tid; idx < NG*NB; idx += 256){
    int m = idx >> 7, e = idx & 127;
    float t = ds_[e] - RBF_STEP * (float)m;
    buf[m][e] = __expf(RBF_COEFF * t * t);
  }
  __syncthreads();
  int te = tid >> 4, tk = tid & 15;
  int e0 = te * 8, k0 = tk * 4;
  float tacc[8][4];
  {
    float4 bv = *(const float4*)&be1s[k0];
    float bq[4] = {bv.x,bv.y,bv.z,bv.w};
    #pragma unroll
    for (int r=0;r<8;r++)
      #pragma unroll
      for (int q=0;q<4;q++) tacc[r][q] = bq[q];
  }
  #pragma unroll 2
  for (int m=0;m<NG;m++){
    float4 w  = *(const float4*)&We1s[m][k0];
    float4 g0 = *(const float4*)&buf[m][e0];
    float4 g1 = *(const float4*)&buf[m][e0+4];
    float ge[8] = {g0.x,g0.y,g0.z,g0.w,g1.x,g1.y,g1.z,g1.w};
    float wv[4] = {w.x,w.y,w.z,w.w};
    #pragma unroll
    for (int r=0;r<8;r++)
      #pragma unroll
      for (int q=0;q<4;q++) tacc[r][q] += ge[r]*wv[q];
  }
  __syncthreads();
  #pragma unroll
  for (int q=0;q<4;q++){
    int k = k0 + q;
    if (k < NG){
      float v[8];
      #pragma unroll
      for (int r=0;r<8;r++) v[r] = sspf(tacc[r][q]);
      *(float4*)&buf[k][e0]   = make_float4(v[0],v[1],v[2],v[3]);
      *(float4*)&buf[k][e0+4] = make_float4(v[4],v[5],v[6],v[7]);
    }
  }
  __syncthreads();
  int c0 = tk * 8;
  float acc[8][8];
  {
    float4 b0 = *(const float4*)&be2s[c0];
    float4 b1 = *(const float4*)&be2s[c0+4];
    float bq[8] = {b0.x,b0.y,b0.z,b0.w,b1.x,b1.y,b1.z,b1.w};
    #pragma unroll
    for (int r=0;r<8;r++)
      #pragma unroll
      for (int q=0;q<8;q++) acc[r][q] = bq[q];
  }
  #pragma unroll 2
  for (int k=0;k<NG;k++){
    float4 w0 = *(const float4*)&We2s[k][c0];
    float4 w1 = *(const float4*)&We2s[k][c0+4];
    float4 t0 = *(const float4*)&buf[k][e0];
    float4 t1 = *(const float4*)&buf[k][e0+4];
    float tv[8] = {t0.x,t0.y,t0.z,t0.w,t1.x,t1.y,t1.z,t1.w};
    float wv[8] = {w0.x,w0.y,w0.z,w0.w,w1.x,w1.y,w1.z,w1.w};
    #pragma unroll
    for (int r=0;r<8;r++)
      #pragma unroll
      for (int q=0;q<8;q++) acc[r][q] += tv[r]*wv[q];
  }
  int   curtgt = tgts[e0];
  float run[8];
  #pragma unroll
  for (int q=0;q<8;q++) run[q] = 0.f;
  #pragma unroll
  for (int r=0;r<8;r++){
    int t = tgts[e0+r];
    int s = srcs[e0+r];
    float4 n0 = *(const float4*)&nodef[(size_t)s*NB + c0];
    float4 n1 = *(const float4*)&nodef[(size_t)s*NB + c0+4];
    float nv[8] = {n0.x,n0.y,n0.z,n0.w,n1.x,n1.y,n1.z,n1.w};
    if (t != curtgt){
      if (curtgt >= 0){
        float* ap = &agg[(size_t)curtgt*NB + c0];
        #pragma unroll
        for (int q=0;q<8;q++) atomicAdd(ap+q, run[q]);
      }
      curtgt = t;
      #pragma unroll
      for (int q=0;q<8;q++) run[q] = 0.f;
    }
    if (t >= 0){
      #pragma unroll
      for (int q=0;q<8;q++) run[q] += acc[r][q] * nv[q];
    }
  }
  if (curtgt >= 0){
    float* ap = &agg[(size_t)curtgt*NB + c0];
    #pragma unroll
    for (int q=0;q<8;q++) atomicAdd(ap+q, run[q]);
  }
}

// ---------------- legacy atomic edge kernel (last-resort fallback) -----------
__launch_bounds__(256, 2)
__global__ void edge_k(const float* __restrict__ dists, const int* __restrict__ a,
                       const float* __restrict__ nodef,
                       const float* __restrict__ We1, const float* __restrict__ be1,
                       const float* __restrict__ We2, const float* __restrict__ be2,
                       float* __restrict__ agg, int E){
  __shared__ float We1s[NG][64];
  __shared__ float We2s[NG][NB];
  __shared__ float buf[NG][NB];
  __shared__ float be1s[64], be2s[NB];
  __shared__ float ds_[NB];
  __shared__ int   ijs[2*NB];
  int tid = threadIdx.x;

  for (int idx = tid; idx < NG*64; idx += 256){
    int m = idx >> 6, k = idx & 63;
    We1s[m][k] = (k < NG) ? We1[m*NG + k] : 0.f;
  }
  for (int idx = tid; idx < NG*NB; idx += 256)
    We2s[0][idx] = We2[idx];
  if (tid < 64)  be1s[tid] = (tid < NG) ? be1[tid] : 0.f;
  if (tid < NB)  be2s[tid] = be2[tid];

  int ebase = blockIdx.x * NB;
  if (tid < NB){
    int e = ebase + tid;
    if (e < E){ ds_[tid] = dists[e]; ijs[2*tid] = a[2*e]; ijs[2*tid+1] = a[2*e+1]; }
    else      { ds_[tid] = 0.f;      ijs[2*tid] = -1;     ijs[2*tid+1] = -1; }
  }
  __syncthreads();
  for (int idx = tid; idx < NG*NB; idx += 256){
    int m = idx >> 7, e = idx & 127;
    float t = ds_[e] - RBF_STEP * (float)m;
    buf[m][e] = __expf(RBF_COEFF * t * t);
  }
  __syncthreads();
  int te = tid >> 4, tk = tid & 15;
  int e0 = te * 8, k0 = tk * 4;
  float tacc[8][4];
  {
    float4 bv = *(const float4*)&be1s[k0];
    float bq[4] = {bv.x,bv.y,bv.z,bv.w};
    #pragma unroll
    for (int r=0;r<8;r++)
      #pragma unroll
      for (int q=0;q<4;q++) tacc[r][q] = bq[q];
  }
  #pragma unroll 2
  for (int m=0;m<NG;m++){
    float4 w  = *(const float4*)&We1s[m][k0];
    float4 g0 = *(const float4*)&buf[m][e0];
    float4 g1 = *(const float4*)&buf[m][e0+4];
    float ge[8] = {g0.x,g0.y,g0.z,g0.w,g1.x,g1.y,g1.z,g1.w};
    float wv[4] = {w.x,w.y,w.z,w.w};
    #pragma unroll
    for (int r=0;r<8;r++)
      #pragma unroll
      for (int q=0;q<4;q++) tacc[r][q] += ge[r]*wv[q];
  }
  __syncthreads();
  #pragma unroll
  for (int q=0;q<4;q++){
    int k = k0 + q;
    if (k < NG){
      float v[8];
      #pragma unroll
      for (int r=0;r<8;r++) v[r] = sspf(tacc[r][q]);
      *(float4*)&buf[k][e0]   = make_float4(v[0],v[1],v[2],v[3]);
      *(float4*)&buf[k][e0+4] = make_float4(v[4],v[5],v[6],v[7]);
    }
  }
  __syncthreads();
  int c0 = tk * 8;
  float acc[8][8];
  {
    float4 b0 = *(const float4*)&be2s[c0];
    float4 b1 = *(const float4*)&be2s[c0+4];
    float bq[8] = {b0.x,b0.y,b0.z,b0.w,b1.x,b1.y,b1.z,b1.w};
    #pragma unroll
    for (int r=0;r<8;r++)
      #pragma unroll
      for (int q=0;q<8;q++) acc[r][q] = bq[q];
  }
  #pragma unroll 2
  for (int k=0;k<NG;k++){
    float4 w0 = *(const float4*)&We2s[k][c0];
    float4 w1 = *(const float4*)&We2s[k][c0+4];
    float4 t0 = *(const float4*)&buf[k][e0];
    float4 t1 = *(const float4*)&buf[k][e0+4];
    float tv[8] = {t0.x,t0.y,t0.z,t0.w,t1.x,t1.y,t1.z,t1.w};
    float wv[8] = {w0.x,w0.y,w0.z,w0.w,w1.x,w1.y,w1.z,w1.w};
    #pragma unroll
    for (int r=0;r<8;r++)
      #pragma unroll
      for (int q=0;q<8;q++) acc[r][q] += tv[r]*wv[q];
  }
  #pragma unroll
  for (int r=0;r<8;r++){
    int el = e0 + r;
    int i = ijs[2*el], j = ijs[2*el+1];
    if (i < 0) continue;
    float4 nj0 = *(const float4*)&nodef[(size_t)j*NB + c0];
    float4 nj1 = *(const float4*)&nodef[(size_t)j*NB + c0+4];
    float4 ni0 = *(const float4*)&nodef[(size_t)i*NB + c0];
    float4 ni1 = *(const float4*)&nodef[(size_t)i*NB + c0+4];
    float* ai = &agg[(size_t)i*NB + c0];
    float* aj = &agg[(size_t)j*NB + c0];
    float njv[8] = {nj0.x,nj0.y,nj0.z,nj0.w,nj1.x,nj1.y,nj1.z,nj1.w};
    float niv[8] = {ni0.x,ni0.y,ni0.z,ni0.w,ni1.x,ni1.y,ni1.z,ni1.w};
    #pragma unroll
    for (int q=0;q<8;q++){
      atomicAdd(ai+q, njv[q]*acc[r][q]);
      atomicAdd(aj+q, niv[q]*acc[r][q]);
    }
  }
}

// ---------------- readout: e = ssp(h@W1+b1)@W2+b2, molecule segment sum ------
__launch_bounds__(128, 3)
__global__ void readout_k(const float* __restrict__ h, const float* __restrict__ W1,
                          const float* __restrict__ b1, const float* __restrict__ W2,
                          const float* __restrict__ b2, const int* __restrict__ molp,
                          float* __restrict__ out, int N){
  __shared__ float As[32][64];
  __shared__ float W1s[32][64];
  __shared__ float segsum[2];
  int tid = threadIdx.x;
  int tc = tid & 15, tr = tid >> 4;
  int row0 = blockIdx.x * 64;
  int c0 = tc * 4;

  float acc[8][4];
  {
    float4 bv = *(const float4*)&b1[c0];
    float bq[4] = {bv.x,bv.y,bv.z,bv.w};
    #pragma unroll
    for (int r=0;r<8;r++)
      #pragma unroll
      for (int q=0;q<4;q++) acc[r][q] = bq[q];
  }
  for (int kc=0;kc<4;kc++){
    #pragma unroll
    for (int p=0;p<4;p++){
      int f = tid + 128*p; int rr = f >> 3; int kq = f & 7;
      int grow = row0 + rr;
      float4 v = (grow < N) ? *(const float4*)&h[(size_t)grow*NB + kc*32 + kq*4]
                            : make_float4(0.f,0.f,0.f,0.f);
      As[kq*4+0][rr] = v.x; As[kq*4+1][rr] = v.y;
      As[kq*4+2][rr] = v.z; As[kq*4+3][rr] = v.w;
    }
    #pragma unroll
    for (int p=0;p<4;p++){
      int f = tid + 128*p; int wk = f >> 4; int cq = f & 15;
      *(float4*)&W1s[wk][cq*4] = *(const float4*)&W1[(size_t)(kc*32+wk)*64 + cq*4];
    }
    __syncthreads();
    #pragma unroll 4
    for (int k=0;k<32;k++){
      float4 a0 = *(const float4*)&As[k][tr*8];
      float4 a1 = *(const float4*)&As[k][tr*8+4];
      float4 w  = *(const float4*)&W1s[k][c0];
      float av[8] = {a0.x,a0.y,a0.z,a0.w,a1.x,a1.y,a1.z,a1.w};
      float wv[4] = {w.x,w.y,w.z,w.w};
      #pragma unroll
      for (int r=0;r<8;r++)
        #pragma unroll
        for (int q=0;q<4;q++) acc[r][q] += av[r]*wv[q];
    }
    __syncthreads();
  }
  float4 w2f = *(const float4*)&W2[c0];
  float part[8];
  #pragma unroll
  for (int r=0;r<8;r++)
    part[r] = sspf(acc[r][0])*w2f.x + sspf(acc[r][1])*w2f.y +
              sspf(acc[r][2])*w2f.z + sspf(acc[r][3])*w2f.w;
  #pragma unroll
  for (int off=1; off<16; off<<=1)
    #pragma unroll
    for (int r=0;r<8;r++) part[r] += __shfl_xor(part[r], off);

  if (tid < 2) segsum[tid] = 0.f;
  __syncthreads();
  int ms = molp[0];
  float b2v = b2[0];
  int seg0 = row0 / ms;
  if (tc == 0){
    #pragma unroll
    for (int r=0;r<8;r++){
      int row = row0 + tr*8 + r;
      if (row < N){
        int s = row/ms - seg0;
        if (s < 2) atomicAdd(&segsum[s], part[r] + b2v);
        else       atomicAdd(&out[row/ms], part[r] + b2v);
      }
    }
  }
  __syncthreads();
  if (tid == 0 && segsum[0] != 0.f) atomicAdd(&out[seg0], segsum[0]);
  if (tid == 1){
    int lastrow = row0 + 63; if (lastrow > N-1) lastrow = N-1;
    if (lastrow/ms > seg0 && segsum[1] != 0.f) atomicAdd(&out[seg0+1], segsum[1]);
  }
}

extern "C" void kernel_launch(void* const* d_in, const int* in_sizes, int n_in,
                              void* d_out, int out_size, void* d_ws, size_t ws_size,
                              hipStream_t stream){
  const int*   r     = (const int*)  d_in[0];
  const float* xyz   = (const float*)d_in[1];
  const int*   a     = (const int*)  d_in[2];
  const int*   molp  = (const int*)  d_in[3];
  const float* embed = (const float*)d_in[4];
  const float* Wn    = (const float*)d_in[5];
  const float* bn    = (const float*)d_in[6];
  const float* We1   = (const float*)d_in[7];
  const float* be1   = (const float*)d_in[8];
  const float* We2   = (const float*)d_in[9];
  const float* be2   = (const float*)d_in[10];
  const float* Wu1   = (const float*)d_in[11];
  const float* bu1   = (const float*)d_in[12];
  const float* Wu2   = (const float*)d_in[13];
  const float* bu2   = (const float*)d_in[14];
  const float* W1    = (const float*)d_in[15];
  const float* b1    = (const float*)d_in[16];
  const float* W2    = (const float*)d_in[17];
  const float* b2    = (const float*)d_in[18];

  int N = in_sizes[0];          // 50000
  int E = in_sizes[2] / 2;      // 500000
  int V = 2*E;                  // directed visits
  size_t VmaxS = (size_t)V + 8*(size_t)N;   // 8-pad worst case

  float* ws   = (float*)d_ws;
  size_t E4   = ((size_t)E + 3) & ~(size_t)3;
  size_t NSZ  = (size_t)N * NB;
  size_t RPAD = ((size_t)N + 1 + 3) & ~(size_t)3;
  size_t NPAD = ((size_t)N + 3) & ~(size_t)3;
  size_t base = E4 + 3*NSZ;
  size_t WPAD = 3*NG*64 + 3*64;   // We1p + be1p

  size_t need1 = (base + RPAD + 3*NPAD + 512 + 3*VmaxS + WPAD) * sizeof(float);
  size_t need2 = (base + RPAD + 2*NPAD + 512 + 3*(size_t)V) * sizeof(float);

  float* dbuf  = ws;
  float* h     = dbuf + E4;
  float* nodef = h + NSZ;
  float* agg   = nodef + NSZ;

  int g2blocks = (N + 127)/128;
  int gblocks  = (N + 63)/64;
  int eblocks  = (E + 127)/128;
  int nb = (N + SCAN_TILE - 1) / SCAN_TILE;

  embed_k<<<(N*32 + 255)/256, 256, 0, stream>>>(r, embed, h, N);
  dist_k <<<(E + 255)/256,    256, 0, stream>>>(a, xyz, dbuf, E);

  if (ws_size >= need1){
    int*   rowptr = (int*)(agg + NSZ);
    int*   cnt    = rowptr + RPAD;
    int*   pcnt   = cnt + NPAD;
    int*   cur    = pcnt + NPAD;
    int*   bsum   = cur + NPAD;
    int*   boff   = bsum + 256;
    int*   asrc   = boff + 256;
    int*   tgtv   = asrc + VmaxS;
    float* dvis   = (float*)(tgtv + VmaxS);
    float* We1p   = dvis + VmaxS;
    float* be1p   = We1p + 3*NG*64;

    (void)hipMemsetAsync(cnt, 0, (size_t)N*sizeof(int), stream);
    (void)hipMemsetAsync(asrc, 0, VmaxS*sizeof(int), stream);
    (void)hipMemsetAsync(tgtv, 0xFF, VmaxS*sizeof(int), stream);
    (void)hipMemsetAsync(dvis, 0, VmaxS*sizeof(float), stream);
    padw_k  <<<(3*NG*64 + 255)/256, 256, 0, stream>>>(We1, be1, We1p, be1p);
    hist_k  <<<(E + 255)/256, 256, 0, stream>>>(a, cnt, E);
    pad_k   <<<(N + 255)/256, 256, 0, stream>>>(cnt, pcnt, N);
    reduce_k<<<nb, 256, 0, stream>>>(pcnt, bsum, N);
    scanb_k <<<1, 64, 0, stream>>>(bsum, boff, nb);
    scan2_k <<<nb, 256, 0, stream>>>(pcnt, boff, rowptr, N, 0);
    copy_k  <<<(N + 255)/256, 256, 0, stream>>>(rowptr, cur, N);
    fill_k  <<<(E + 255)/256, 256, 0, stream>>>(a, dbuf, cur, asrc, dvis, tgtv, E);

    int vblocks = (int)((VmaxS + 127)/128);
    for (int l = 0; l < 3; l++){
      gemm256_k<0,0><<<g2blocks, 256, 0, stream>>>(h, Wn + (size_t)l*NB*NB, bn + l*NB, nodef, N);
      (void)hipMemsetAsync(agg, 0, NSZ*sizeof(float), stream);
      visit2_k<<<vblocks, 256, 0, stream>>>(dvis, asrc, tgtv, nodef,
                                            We1p + (size_t)l*NG*64, be1p + (size_t)l*64,
                                            We2 + (size_t)l*NG*NB, be2 + l*NB, agg, (int)VmaxS);
      gemm256_k<1,0><<<g2blocks, 256, 0, stream>>>(agg,   Wu1 + (size_t)l*NB*NB, bu1 + l*NB, nodef, N);
      gemm256_k<0,1><<<g2blocks, 256, 0, stream>>>(nodef, Wu2 + (size_t)l*NB*NB, bu2 + l*NB, h, N);
    }
  } else if (ws_size >= need2){
    int*   rowptr = (int*)(agg + NSZ);
    int*   cnt    = rowptr + RPAD;
    int*   cur    = cnt + NPAD;
    int*   bsum   = cur + NPAD;
    int*   boff   = bsum + 256;
    int*   asrc   = boff + 256;
    int*   tgtv   = asrc + V;
    float* dvis   = (float*)(tgtv + V);

    (void)hipMemsetAsync(cnt, 0, (size_t)N*sizeof(int), stream);
    hist_k  <<<(E + 255)/256, 256, 0, stream>>>(a, cnt, E);
    reduce_k<<<nb, 256, 0, stream>>>(cnt, bsum, N);
    scanb_k <<<1, 64, 0, stream>>>(bsum, boff, nb);
    scan2_k <<<nb, 256, 0, stream>>>(cnt, boff, rowptr, N, V);
    copy_k  <<<(N + 255)/256, 256, 0, stream>>>(rowptr, cur, N);
    fill_k  <<<(E + 255)/256, 256, 0, stream>>>(a, dbuf, cur, asrc, dvis, tgtv, E);

    int vblocks = (V + 127)/128;
    for (int l = 0; l < 3; l++){
      gemm256_k<0,0><<<g2blocks, 256, 0, stream>>>(h, Wn + (size_t)l*NB*NB, bn + l*NB, nodef, N);
      (void)hipMemsetAsync(agg, 0, NSZ*sizeof(float), stream);
      visit_k<<<vblocks, 256, 0, stream>>>(dvis, asrc, tgtv, nodef,
                                           We1 + (size_t)l*NG*NG, be1 + l*NG,
                                           We2 + (size_t)l*NG*NB, be2 + l*NB, agg, V);
      gemm256_k<1,0><<<g2blocks, 256, 0, stream>>>(agg,   Wu1 + (size_t)l*NB*NB, bu1 + l*NB, nodef, N);
      gemm256_k<0,1><<<g2blocks, 256, 0, stream>>>(nodef, Wu2 + (size_t)l*NB*NB, bu2 + l*NB, h, N);
    }
  } else {
    for (int l = 0; l < 3; l++){
      gemm256_k<0,0><<<g2blocks, 256, 0, stream>>>(h, Wn + (size_t)l*NB*NB, bn + l*NB, nodef, N);
      (void)hipMemsetAsync(agg, 0, NSZ*sizeof(float), stream);
      edge_k<<<eblocks, 256, 0, stream>>>(dbuf, a, nodef,
                                          We1 + (size_t)l*NG*NG, be1 + l*NG,
                                          We2 + (size_t)l*NG*NB, be2 + l*NB, agg, E);
      gemm256_k<1,0><<<g2blocks, 256, 0, stream>>>(agg,   Wu1 + (size_t)l*NB*NB, bu1 + l*NB, nodef, N);
      gemm256_k<0,1><<<g2blocks, 256, 0, stream>>>(nodef, Wu2 + (size_t)l*NB*NB, bu2 + l*NB, h, N);
    }
  }

  (void)hipMemsetAsync(d_out, 0, (size_t)out_size*sizeof(float), stream);
  readout_k<<<gblocks, 128, 0, stream>>>(h, W1, b1, W2, b2, molp, (float*)d_out, N);
}

// Round 13
// 1403.952 us; speedup vs baseline: 7.6797x; 1.0493x over previous
//
#include <hip/hip_runtime.h>
#include <hip/hip_bf16.h>

#define NG 50
#define NB 128

__device__ __forceinline__ float sspf(float x){
  float t = __expf(-fabsf(x));
  return fmaxf(x, 0.f) + __logf(1.f + t) - 0.6931471805599453094f;
}

constexpr float RBF_STEP  = 5.0f / 49.0f;
constexpr float RBF_COEFF = -0.5f / (RBF_STEP * RBF_STEP);

// ---------------- h = embed[r] ----------------
__global__ void embed_k(const int* __restrict__ r, const float* __restrict__ embed,
                        float* __restrict__ h, int N){
  int idx = blockIdx.x * blockDim.x + threadIdx.x;
  if (idx < N * 32){
    int n = idx >> 5, c = (idx & 31) * 4;
    *(float4*)&h[(size_t)n * NB + c] = *(const float4*)&embed[(size_t)r[n] * NB + c];
  }
}

// ---------------- per-edge distance ----------------
__global__ void dist_k(const int* __restrict__ a, const float* __restrict__ xyz,
                       float* __restrict__ d, int E){
  int e = blockIdx.x * blockDim.x + threadIdx.x;
  if (e < E){
    int i = a[2*e], j = a[2*e+1];
    float dx = xyz[3*i+0] - xyz[3*j+0];
    float dy = xyz[3*i+1] - xyz[3*j+1];
    float dz = xyz[3*i+2] - xyz[3*j+2];
    d[e] = sqrtf(dx*dx + dy*dy + dz*dz);
  }
}

// ---------------- pad We1/be1 into [50][64] / [64] per layer ----------------
__global__ void padw_k(const float* __restrict__ We1, const float* __restrict__ be1,
                       float* __restrict__ We1p, float* __restrict__ be1p){
  int idx = blockIdx.x*blockDim.x + threadIdx.x;
  if (idx < 3*NG*64){
    int l = idx/(NG*64), rem = idx%(NG*64), m = rem>>6, k = rem&63;
    We1p[idx] = (k < NG) ? We1[((size_t)l*NG + m)*NG + k] : 0.f;
  }
  if (idx < 3*64){
    int l = idx>>6, k = idx&63;
    be1p[idx] = (k < NG) ? be1[l*NG + k] : 0.f;
  }
}

// ================= CSR build =================
__global__ void hist_k(const int* __restrict__ a, int* __restrict__ cnt, int E){
  int e = blockIdx.x * blockDim.x + threadIdx.x;
  if (e < E){
    atomicAdd(&cnt[a[2*e]],   1);
    atomicAdd(&cnt[a[2*e+1]], 1);
  }
}

// pad each node's run to a multiple of 4 (4-aligned runs; see visit2_k proof)
__global__ void pad_k(const int* __restrict__ cnt, int* __restrict__ pcnt, int N){
  int i = blockIdx.x*blockDim.x + threadIdx.x;
  if (i < N) pcnt[i] = (cnt[i] + 3) & ~3;
}

#define SCAN_TILE 512
__global__ void reduce_k(const int* __restrict__ cnt, int* __restrict__ bsum, int N){
  __shared__ int s[256];
  int b = blockIdx.x, t = threadIdx.x;
  int i0 = b*SCAN_TILE + t;
  int v = 0;
  if (i0 < N)       v += cnt[i0];
  if (i0+256 < N)   v += cnt[i0+256];
  s[t] = v; __syncthreads();
  for (int o=128;o>0;o>>=1){ if (t<o) s[t]+=s[t+o]; __syncthreads(); }
  if (t==0) bsum[b] = s[0];
}

__global__ void scanb_k(const int* __restrict__ bsum, int* __restrict__ boff, int nb){
  if (threadIdx.x==0 && blockIdx.x==0){
    int acc = 0;
    for (int i=0;i<nb;i++){ boff[i]=acc; acc+=bsum[i]; }
  }
}

__global__ void scan2_k(const int* __restrict__ cnt, const int* __restrict__ boff,
                        int* __restrict__ rowptr, int N, int total){
  __shared__ int s[256];
  int b = blockIdx.x, t = threadIdx.x;
  int i0 = b*SCAN_TILE;
  int a0 = (i0+2*t   < N) ? cnt[i0+2*t]   : 0;
  int a1 = (i0+2*t+1 < N) ? cnt[i0+2*t+1] : 0;
  int pair = a0 + a1;
  s[t] = pair; __syncthreads();
  for (int o=1;o<256;o<<=1){
    int v = (t>=o) ? s[t-o] : 0;
    __syncthreads();
    s[t] += v;
    __syncthreads();
  }
  int excl = s[t] - pair + boff[b];
  if (i0+2*t   < N) rowptr[i0+2*t]   = excl;
  if (i0+2*t+1 < N) rowptr[i0+2*t+1] = excl + a0;
  if (b==0 && t==0) rowptr[N] = total;
}

__global__ void copy_k(const int* __restrict__ src, int* __restrict__ dst, int n){
  int i = blockIdx.x*blockDim.x + threadIdx.x;
  if (i < n) dst[i] = src[i];
}

// visit list (SoA): asrc[p]=source node, dvis[p]=edge distance, tgtv[p]=target
__global__ void fill_k(const int* __restrict__ a, const float* __restrict__ dists,
                       int* __restrict__ cur,
                       int* __restrict__ asrc, float* __restrict__ dvis,
                       int* __restrict__ tgtv, int E){
  int e = blockIdx.x*blockDim.x + threadIdx.x;
  if (e < E){
    int i = a[2*e], j = a[2*e+1];
    float d = dists[e];
    int p = atomicAdd(&cur[i], 1);
    asrc[p] = j; dvis[p] = d; tgtv[p] = i;
    int q = atomicAdd(&cur[j], 1);
    asrc[q] = i; dvis[q] = d; tgtv[q] = j;
  }
}

// ------- gemm256_k: (N x 128) @ (128 x 128) + b, opt ssp, opt residual -------
template<int ACT, int RESID>
__launch_bounds__(256, 4)
__global__ void gemm256_k(const float* __restrict__ in, const float* __restrict__ W,
                          const float* __restrict__ bias, float* __restrict__ out, int N){
  __shared__ float As[32][132];   // transposed: As[k][row]
  __shared__ float Ws[32][128];
  int tid = threadIdx.x;
  int tc = tid & 15, tr = tid >> 4;
  int row0 = blockIdx.x * 128;
  int c0 = tc * 8;

  float bcol[8];
  {
    float4 b0 = *(const float4*)&bias[c0];
    float4 b1 = *(const float4*)&bias[c0+4];
    bcol[0]=b0.x; bcol[1]=b0.y; bcol[2]=b0.z; bcol[3]=b0.w;
    bcol[4]=b1.x; bcol[5]=b1.y; bcol[6]=b1.z; bcol[7]=b1.w;
  }
  float acc[8][8];
  #pragma unroll
  for (int r=0;r<8;r++)
    #pragma unroll
    for (int q=0;q<8;q++) acc[r][q] = bcol[q];

  for (int kc=0; kc<4; kc++){
    #pragma unroll
    for (int p=0;p<4;p++){
      int f = tid + 256*p;
      int rr = f >> 3, kq = f & 7;
      int grow = row0 + rr;
      float4 v = (grow < N) ? *(const float4*)&in[(size_t)grow*NB + kc*32 + kq*4]
                            : make_float4(0.f,0.f,0.f,0.f);
      As[kq*4+0][rr] = v.x; As[kq*4+1][rr] = v.y;
      As[kq*4+2][rr] = v.z; As[kq*4+3][rr] = v.w;
    }
    #pragma unroll
    for (int p=0;p<4;p++){
      int f = tid + 256*p;
      int wk = f >> 5, cq = f & 31;
      *(float4*)&Ws[wk][cq*4] = *(const float4*)&W[(size_t)(kc*32+wk)*NB + cq*4];
    }
    __syncthreads();
    #pragma unroll 4
    for (int k=0;k<32;k++){
      float4 a0 = *(const float4*)&As[k][tr*8];
      float4 a1 = *(const float4*)&As[k][tr*8+4];
      float4 w0 = *(const float4*)&Ws[k][c0];
      float4 w1 = *(const float4*)&Ws[k][c0+4];
      float av[8] = {a0.x,a0.y,a0.z,a0.w,a1.x,a1.y,a1.z,a1.w};
      float wv[8] = {w0.x,w0.y,w0.z,w0.w,w1.x,w1.y,w1.z,w1.w};
      #pragma unroll
      for (int r=0;r<8;r++)
        #pragma unroll
        for (int q=0;q<8;q++) acc[r][q] += av[r]*wv[q];
    }
    __syncthreads();
  }
  #pragma unroll
  for (int r=0;r<8;r++){
    int row = row0 + tr*8 + r;
    if (row < N){
      float v[8];
      #pragma unroll
      for (int q=0;q<8;q++) v[q] = (ACT==1) ? sspf(acc[r][q]) : acc[r][q];
      if (RESID){
        float4 o0 = *(const float4*)&out[(size_t)row*NB + c0];
        float4 o1 = *(const float4*)&out[(size_t)row*NB + c0+4];
        v[0]+=o0.x; v[1]+=o0.y; v[2]+=o0.z; v[3]+=o0.w;
        v[4]+=o1.x; v[5]+=o1.y; v[6]+=o1.z; v[7]+=o1.w;
      }
      *(float4*)&out[(size_t)row*NB + c0]   = make_float4(v[0],v[1],v[2],v[3]);
      *(float4*)&out[(size_t)row*NB + c0+4] = make_float4(v[4],v[5],v[6],v[7]);
    }
  }
}

// ---------------- visit2_k: 4-aligned runs, minimal LDS (5 blocks/CU) --------
// Runs padded to multiples of 4; each thread's 8 visits = two 4-groups.
// Proof pad slots never start a group/block: runs 4-aligned, pad interval
// [cnt,pcnt) contains no multiple of 4; group starts (mult 4) & block starts
// (mult 128) are multiples of 4 relative to run start.
__launch_bounds__(256, 5)
__global__ void visit2_k(const float* __restrict__ dvis,
                         const int* __restrict__ asrc,
                         const int* __restrict__ tgtv,
                         const float* __restrict__ nodef,
                         const float* __restrict__ We1p, const float* __restrict__ be1p,
                         const float* __restrict__ We2, const float* __restrict__ be2,
                         float* __restrict__ agg, int Vmax){
  __shared__ float buf[NG][NB];     // 25.6 KB : g -> T -> part[32][NB]
  __shared__ float ds_[NB];
  __shared__ int   srcs[NB], tgts[NB];
  __shared__ int   tgt4[32];
  int tid = threadIdx.x;

  int vbase = blockIdx.x * NB;
  if (tid < NB){
    int p = vbase + tid;
    if (p < Vmax){
      srcs[tid] = asrc[p]; tgts[tid] = tgtv[p]; ds_[tid] = dvis[p];
    } else {
      srcs[tid] = 0; tgts[tid] = -1; ds_[tid] = 0.f;
    }
  }
  __syncthreads();
  if (tgts[0] < 0) return;          // fully-padded trailing block (uniform)

  if (tid < 32)  tgt4[tid] = tgts[tid*4];

  // g phase
  for (int idx = tid; idx < NG*NB; idx += 256){
    int m = idx >> 7, e = idx & 127;
    float t = ds_[e] - RBF_STEP * (float)m;
    buf[m][e] = __expf(RBF_COEFF * t * t);
  }
  __syncthreads();

  int te = tid >> 4, tk = tid & 15;
  int e0 = te * 8, k0 = tk * 4;

  // T phase (We1p from global, padded stride 64)
  float tacc[8][4];
  {
    float4 bv = *(const float4*)&be1p[k0];
    float bq[4] = {bv.x,bv.y,bv.z,bv.w};
    #pragma unroll
    for (int r=0;r<8;r++)
      #pragma unroll
      for (int q=0;q<4;q++) tacc[r][q] = bq[q];
  }
  #pragma unroll 2
  for (int m=0;m<NG;m++){
    float4 w  = *(const float4*)&We1p[m*64 + k0];
    float4 g0 = *(const float4*)&buf[m][e0];
    float4 g1 = *(const float4*)&buf[m][e0+4];
    float ge[8] = {g0.x,g0.y,g0.z,g0.w,g1.x,g1.y,g1.z,g1.w};
    float wv[4] = {w.x,w.y,w.z,w.w};
    #pragma unroll
    for (int r=0;r<8;r++)
      #pragma unroll
      for (int q=0;q<4;q++) tacc[r][q] += ge[r]*wv[q];
  }
  __syncthreads();
  #pragma unroll
  for (int q=0;q<4;q++){
    int k = k0 + q;
    if (k < NG){
      float v[8];
      #pragma unroll
      for (int r=0;r<8;r++) v[r] = sspf(tacc[r][q]);
      *(float4*)&buf[k][e0]   = make_float4(v[0],v[1],v[2],v[3]);
      *(float4*)&buf[k][e0+4] = make_float4(v[4],v[5],v[6],v[7]);
    }
  }
  __syncthreads();

  // EF phase (We2 rows from global — broadcast-friendly, L1/L2-resident)
  int c0 = tk * 8;
  float acc[8][8];
  {
    float4 b0 = *(const float4*)&be2[c0];
    float4 b1 = *(const float4*)&be2[c0+4];
    float bq[8] = {b0.x,b0.y,b0.z,b0.w,b1.x,b1.y,b1.z,b1.w};
    #pragma unroll
    for (int r=0;r<8;r++)
      #pragma unroll
      for (int q=0;q<8;q++) acc[r][q] = bq[q];
  }
  #pragma unroll 2
  for (int k=0;k<NG;k++){
    float4 w0 = *(const float4*)&We2[k*NB + c0];
    float4 w1 = *(const float4*)&We2[k*NB + c0+4];
    float4 t0 = *(const float4*)&buf[k][e0];
    float4 t1 = *(const float4*)&buf[k][e0+4];
    float tv[8] = {t0.x,t0.y,t0.z,t0.w,t1.x,t1.y,t1.z,t1.w};
    float wv[8] = {w0.x,w0.y,w0.z,w0.w,w1.x,w1.y,w1.z,w1.w};
    #pragma unroll
    for (int r=0;r<8;r++)
      #pragma unroll
      for (int q=0;q<8;q++) acc[r][q] += tv[r]*wv[q];
  }
  __syncthreads();   // buf reads done; reuse as part[32][NB]

  // group accumulate: this thread's 8 visits are groups 2te (r=0..3) and
  // 2te+1 (r=4..7); each 4-group has a single target (4-aligned runs).
  float runA[8], runB[8];
  #pragma unroll
  for (int q=0;q<8;q++){ runA[q] = 0.f; runB[q] = 0.f; }
  #pragma unroll
  for (int r=0;r<8;r++){
    int t = tgts[e0+r];
    int s = srcs[e0+r];
    float4 n0 = *(const float4*)&nodef[(size_t)s*NB + c0];
    float4 n1 = *(const float4*)&nodef[(size_t)s*NB + c0+4];
    float nv[8] = {n0.x,n0.y,n0.z,n0.w,n1.x,n1.y,n1.z,n1.w};
    if (t >= 0){
      if (r < 4){
        #pragma unroll
        for (int q=0;q<8;q++) runA[q] += acc[r][q] * nv[q];
      } else {
        #pragma unroll
        for (int q=0;q<8;q++) runB[q] += acc[r][q] * nv[q];
      }
    }
  }
  float* part = &buf[0][0];         // part[g][ch] = buf row g (32 rows used)
  #pragma unroll
  for (int q=0;q<8;q++){
    part[(2*te  )*NB + c0 + q] = runA[q];
    part[(2*te+1)*NB + c0 + q] = runB[q];
  }
  __syncthreads();

  // leaders: each thread handles its two groups; sum consecutive same-target
  // groups; interior runs -> plain store, border runs -> atomic.
  #pragma unroll
  for (int gi=0; gi<2; gi++){
    int g = 2*te + gi;
    int t = tgt4[g];
    if (t >= 0 && (g == 0 || tgt4[g-1] != t)){
      int gend = g;
      while (gend+1 < 32 && tgt4[gend+1] == t) gend++;
      float s[8];
      #pragma unroll
      for (int q=0;q<8;q++) s[q] = 0.f;
      for (int g2=g; g2<=gend; ++g2)
        #pragma unroll
        for (int q=0;q<8;q++) s[q] += part[g2*NB + c0 + q];
      float* ap = &agg[(size_t)t*NB + c0];
      bool border = (g == 0) || (gend == 31);
      if (border){
        #pragma unroll
        for (int q=0;q<8;q++) atomicAdd(ap+q, s[q]);
      } else {
        *(float4*)ap     = make_float4(s[0],s[1],s[2],s[3]);
        *(float4*)(ap+4) = make_float4(s[4],s[5],s[6],s[7]);
      }
    }
  }
}

// ---------------- visit_k (tier-2 fallback): fragment atomics ----------------
__launch_bounds__(256, 2)
__global__ void visit_k(const float* __restrict__ dvis,
                        const int* __restrict__ asrc,
                        const int* __restrict__ tgtv,
                        const float* __restrict__ nodef,
                        const float* __restrict__ We1, const float* __restrict__ be1,
                        const float* __restrict__ We2, const float* __restrict__ be2,
                        float* __restrict__ agg, int V){
  __shared__ float We1s[NG][64];
  __shared__ float We2s[NG][NB];
  __shared__ float buf[NG][NB];
  __shared__ float be1s[64], be2s[NB];
  __shared__ float ds_[NB];
  __shared__ int   srcs[NB], tgts[NB];
  int tid = threadIdx.x;

  for (int idx = tid; idx < NG*64; idx += 256){
    int m = idx >> 6, k = idx & 63;
    We1s[m][k] = (k < NG) ? We1[m*NG + k] : 0.f;
  }
  for (int idx = tid; idx < NG*NB; idx += 256)
    We2s[0][idx] = We2[idx];
  if (tid < 64)  be1s[tid] = (tid < NG) ? be1[tid] : 0.f;
  if (tid < NB)  be2s[tid] = be2[tid];

  int vbase = blockIdx.x * NB;
  if (tid < NB){
    int p = vbase + tid;
    if (p < V){
      srcs[tid] = asrc[p]; tgts[tid] = tgtv[p]; ds_[tid] = dvis[p];
    } else {
      srcs[tid] = 0; tgts[tid] = -1; ds_[tid] = 0.f;
    }
  }
  __syncthreads();
  for (int idx = tid; idx < NG*NB; idx += 256){
    int m = idx >> 7, e = idx & 127;
    float t = ds_[e] - RBF_STEP * (float)m;
    buf[m][e] = __expf(RBF_COEFF * t * t);
  }
  __syncthreads();
  int te = tid >> 4, tk = tid & 15;
  int e0 = te * 8, k0 = tk * 4;
  float tacc[8][4];
  {
    float4 bv = *(const float4*)&be1s[k0];
    float bq[4] = {bv.x,bv.y,bv.z,bv.w};
    #pragma unroll
    for (int r=0;r<8;r++)
      #pragma unroll
      for (int q=0;q<4;q++) tacc[r][q] = bq[q];
  }
  #pragma unroll 2
  for (int m=0;m<NG;m++){
    float4 w  = *(const float4*)&We1s[m][k0];
    float4 g0 = *(const float4*)&buf[m][e0];
    float4 g1 = *(const float4*)&buf[m][e0+4];
    float ge[8] = {g0.x,g0.y,g0.z,g0.w,g1.x,g1.y,g1.z,g1.w};
    float wv[4] = {w.x,w.y,w.z,w.w};
    #pragma unroll
    for (int r=0;r<8;r++)
      #pragma unroll
      for (int q=0;q<4;q++) tacc[r][q] += ge[r]*wv[q];
  }
  __syncthreads();
  #pragma unroll
  for (int q=0;q<4;q++){
    int k = k0 + q;
    if (k < NG){
      float v[8];
      #pragma unroll
      for (int r=0;r<8;r++) v[r] = sspf(tacc[r][q]);
      *(float4*)&buf[k][e0]   = make_float4(v[0],v[1],v[2],v[3]);
      *(float4*)&buf[k][e0+4] = make_float4(v[4],v[5],v[6],v[7]);
    }
  }
  __syncthreads();
  int c0 = tk * 8;
  float acc[8][8];
  {
    float4 b0 = *(const float4*)&be2s[c0];
    float4 b1 = *(const float4*)&be2s[c0+4];
    float bq[8] = {b0.x,b0.y,b0.z,b0.w,b1.x,b1.y,b1.z,b1.w};
    #pragma unroll
    for (int r=0;r<8;r++)
      #pragma unroll
      for (int q=0;q<8;q++) acc[r][q] = bq[q];
  }
  #pragma unroll 2
  for (int k=0;k<NG;k++){
    float4 w0 = *(const float4*)&We2s[k][c0];
    float4 w1 = *(const float4*)&We2s[k][c0+4];
    float4 t0 = *(const float4*)&buf[k][e0];
    float4 t1 = *(const float4*)&buf[k][e0+4];
    float tv[8] = {t0.x,t0.y,t0.z,t0.w,t1.x,t1.y,t1.z,t1.w};
    float wv[8] = {w0.x,w0.y,w0.z,w0.w,w1.x,w1.y,w1.z,w1.w};
    #pragma unroll
    for (int r=0;r<8;r++)
      #pragma unroll
      for (int q=0;q<8;q++) acc[r][q] += tv[r]*wv[q];
  }
  int   curtgt = tgts[e0];
  float run[8];
  #pragma unroll
  for (int q=0;q<8;q++) run[q] = 0.f;
  #pragma unroll
  for (int r=0;r<8;r++){
    int t = tgts[e0+r];
    int s = srcs[e0+r];
    float4 n0 = *(const float4*)&nodef[(size_t)s*NB + c0];
    float4 n1 = *(const float4*)&nodef[(size_t)s*NB + c0+4];
    float nv[8] = {n0.x,n0.y,n0.z,n0.w,n1.x,n1.y,n1.z,n1.w};
    if (t != curtgt){
      if (curtgt >= 0){
        float* ap = &agg[(size_t)curtgt*NB + c0];
        #pragma unroll
        for (int q=0;q<8;q++) atomicAdd(ap+q, run[q]);
      }
      curtgt = t;
      #pragma unroll
      for (int q=0;q<8;q++) run[q] = 0.f;
    }
    if (t >= 0){
      #pragma unroll
      for (int q=0;q<8;q++) run[q] += acc[r][q] * nv[q];
    }
  }
  if (curtgt >= 0){
    float* ap = &agg[(size_t)curtgt*NB + c0];
    #pragma unroll
    for (int q=0;q<8;q++) atomicAdd(ap+q, run[q]);
  }
}

// ---------------- legacy atomic edge kernel (last-resort fallback) -----------
__launch_bounds__(256, 2)
__global__ void edge_k(const float* __restrict__ dists, const int* __restrict__ a,
                       const float* __restrict__ nodef,
                       const float* __restrict__ We1, const float* __restrict__ be1,
                       const float* __restrict__ We2, const float* __restrict__ be2,
                       float* __restrict__ agg, int E){
  __shared__ float We1s[NG][64];
  __shared__ float We2s[NG][NB];
  __shared__ float buf[NG][NB];
  __shared__ float be1s[64], be2s[NB];
  __shared__ float ds_[NB];
  __shared__ int   ijs[2*NB];
  int tid = threadIdx.x;

  for (int idx = tid; idx < NG*64; idx += 256){
    int m = idx >> 6, k = idx & 63;
    We1s[m][k] = (k < NG) ? We1[m*NG + k] : 0.f;
  }
  for (int idx = tid; idx < NG*NB; idx += 256)
    We2s[0][idx] = We2[idx];
  if (tid < 64)  be1s[tid] = (tid < NG) ? be1[tid] : 0.f;
  if (tid < NB)  be2s[tid] = be2[tid];

  int ebase = blockIdx.x * NB;
  if (tid < NB){
    int e = ebase + tid;
    if (e < E){ ds_[tid] = dists[e]; ijs[2*tid] = a[2*e]; ijs[2*tid+1] = a[2*e+1]; }
    else      { ds_[tid] = 0.f;      ijs[2*tid] = -1;     ijs[2*tid+1] = -1; }
  }
  __syncthreads();
  for (int idx = tid; idx < NG*NB; idx += 256){
    int m = idx >> 7, e = idx & 127;
    float t = ds_[e] - RBF_STEP * (float)m;
    buf[m][e] = __expf(RBF_COEFF * t * t);
  }
  __syncthreads();
  int te = tid >> 4, tk = tid & 15;
  int e0 = te * 8, k0 = tk * 4;
  float tacc[8][4];
  {
    float4 bv = *(const float4*)&be1s[k0];
    float bq[4] = {bv.x,bv.y,bv.z,bv.w};
    #pragma unroll
    for (int r=0;r<8;r++)
      #pragma unroll
      for (int q=0;q<4;q++) tacc[r][q] = bq[q];
  }
  #pragma unroll 2
  for (int m=0;m<NG;m++){
    float4 w  = *(const float4*)&We1s[m][k0];
    float4 g0 = *(const float4*)&buf[m][e0];
    float4 g1 = *(const float4*)&buf[m][e0+4];
    float ge[8] = {g0.x,g0.y,g0.z,g0.w,g1.x,g1.y,g1.z,g1.w};
    float wv[4] = {w.x,w.y,w.z,w.w};
    #pragma unroll
    for (int r=0;r<8;r++)
      #pragma unroll
      for (int q=0;q<4;q++) tacc[r][q] += ge[r]*wv[q];
  }
  __syncthreads();
  #pragma unroll
  for (int q=0;q<4;q++){
    int k = k0 + q;
    if (k < NG){
      float v[8];
      #pragma unroll
      for (int r=0;r<8;r++) v[r] = sspf(tacc[r][q]);
      *(float4*)&buf[k][e0]   = make_float4(v[0],v[1],v[2],v[3]);
      *(float4*)&buf[k][e0+4] = make_float4(v[4],v[5],v[6],v[7]);
    }
  }
  __syncthreads();
  int c0 = tk * 8;
  float acc[8][8];
  {
    float4 b0 = *(const float4*)&be2s[c0];
    float4 b1 = *(const float4*)&be2s[c0+4];
    float bq[8] = {b0.x,b0.y,b0.z,b0.w,b1.x,b1.y,b1.z,b1.w};
    #pragma unroll
    for (int r=0;r<8;r++)
      #pragma unroll
      for (int q=0;q<8;q++) acc[r][q] = bq[q];
  }
  #pragma unroll 2
  for (int k=0;k<NG;k++){
    float4 w0 = *(const float4*)&We2s[k][c0];
    float4 w1 = *(const float4*)&We2s[k][c0+4];
    float4 t0 = *(const float4*)&buf[k][e0];
    float4 t1 = *(const float4*)&buf[k][e0+4];
    float tv[8] = {t0.x,t0.y,t0.z,t0.w,t1.x,t1.y,t1.z,t1.w};
    float wv[8] = {w0.x,w0.y,w0.z,w0.w,w1.x,w1.y,w1.z,w1.w};
    #pragma unroll
    for (int r=0;r<8;r++)
      #pragma unroll
      for (int q=0;q<8;q++) acc[r][q] += tv[r]*wv[q];
  }
  #pragma unroll
  for (int r=0;r<8;r++){
    int el = e0 + r;
    int i = ijs[2*el], j = ijs[2*el+1];
    if (i < 0) continue;
    float4 nj0 = *(const float4*)&nodef[(size_t)j*NB + c0];
    float4 nj1 = *(const float4*)&nodef[(size_t)j*NB + c0+4];
    float4 ni0 = *(const float4*)&nodef[(size_t)i*NB + c0];
    float4 ni1 = *(const float4*)&nodef[(size_t)i*NB + c0+4];
    float* ai = &agg[(size_t)i*NB + c0];
    float* aj = &agg[(size_t)j*NB + c0];
    float njv[8] = {nj0.x,nj0.y,nj0.z,nj0.w,nj1.x,nj1.y,nj1.z,nj1.w};
    float niv[8] = {ni0.x,ni0.y,ni0.z,ni0.w,ni1.x,ni1.y,ni1.z,ni1.w};
    #pragma unroll
    for (int q=0;q<8;q++){
      atomicAdd(ai+q, njv[q]*acc[r][q]);
      atomicAdd(aj+q, niv[q]*acc[r][q]);
    }
  }
}

// ---------------- readout: e = ssp(h@W1+b1)@W2+b2, molecule segment sum ------
__launch_bounds__(128, 4)
__global__ void readout_k(const float* __restrict__ h, const float* __restrict__ W1,
                          const float* __restrict__ b1, const float* __restrict__ W2,
                          const float* __restrict__ b2, const int* __restrict__ molp,
                          float* __restrict__ out, int N){
  __shared__ float As[32][64];
  __shared__ float W1s[32][64];
  __shared__ float segsum[2];
  int tid = threadIdx.x;
  int tc = tid & 15, tr = tid >> 4;
  int row0 = blockIdx.x * 64;
  int c0 = tc * 4;

  float acc[8][4];
  {
    float4 bv = *(const float4*)&b1[c0];
    float bq[4] = {bv.x,bv.y,bv.z,bv.w};
    #pragma unroll
    for (int r=0;r<8;r++)
      #pragma unroll
      for (int q=0;q<4;q++) acc[r][q] = bq[q];
  }
  for (int kc=0;kc<4;kc++){
    #pragma unroll
    for (int p=0;p<4;p++){
      int f = tid + 128*p; int rr = f >> 3; int kq = f & 7;
      int grow = row0 + rr;
      float4 v = (grow < N) ? *(const float4*)&h[(size_t)grow*NB + kc*32 + kq*4]
                            : make_float4(0.f,0.f,0.f,0.f);
      As[kq*4+0][rr] = v.x; As[kq*4+1][rr] = v.y;
      As[kq*4+2][rr] = v.z; As[kq*4+3][rr] = v.w;
    }
    #pragma unroll
    for (int p=0;p<4;p++){
      int f = tid + 128*p; int wk = f >> 4; int cq = f & 15;
      *(float4*)&W1s[wk][cq*4] = *(const float4*)&W1[(size_t)(kc*32+wk)*64 + cq*4];
    }
    __syncthreads();
    #pragma unroll 4
    for (int k=0;k<32;k++){
      float4 a0 = *(const float4*)&As[k][tr*8];
      float4 a1 = *(const float4*)&As[k][tr*8+4];
      float4 w  = *(const float4*)&W1s[k][c0];
      float av[8] = {a0.x,a0.y,a0.z,a0.w,a1.x,a1.y,a1.z,a1.w};
      float wv[4] = {w.x,w.y,w.z,w.w};
      #pragma unroll
      for (int r=0;r<8;r++)
        #pragma unroll
        for (int q=0;q<4;q++) acc[r][q] += av[r]*wv[q];
    }
    __syncthreads();
  }
  float4 w2f = *(const float4*)&W2[c0];
  float part[8];
  #pragma unroll
  for (int r=0;r<8;r++)
    part[r] = sspf(acc[r][0])*w2f.x + sspf(acc[r][1])*w2f.y +
              sspf(acc[r][2])*w2f.z + sspf(acc[r][3])*w2f.w;
  #pragma unroll
  for (int off=1; off<16; off<<=1)
    #pragma unroll
    for (int r=0;r<8;r++) part[r] += __shfl_xor(part[r], off);

  if (tid < 2) segsum[tid] = 0.f;
  __syncthreads();
  int ms = molp[0];
  float b2v = b2[0];
  int seg0 = row0 / ms;
  if (tc == 0){
    #pragma unroll
    for (int r=0;r<8;r++){
      int row = row0 + tr*8 + r;
      if (row < N){
        int s = row/ms - seg0;
        if (s < 2) atomicAdd(&segsum[s], part[r] + b2v);
        else       atomicAdd(&out[row/ms], part[r] + b2v);
      }
    }
  }
  __syncthreads();
  if (tid == 0 && segsum[0] != 0.f) atomicAdd(&out[seg0], segsum[0]);
  if (tid == 1){
    int lastrow = row0 + 63; if (lastrow > N-1) lastrow = N-1;
    if (lastrow/ms > seg0 && segsum[1] != 0.f) atomicAdd(&out[seg0+1], segsum[1]);
  }
}

extern "C" void kernel_launch(void* const* d_in, const int* in_sizes, int n_in,
                              void* d_out, int out_size, void* d_ws, size_t ws_size,
                              hipStream_t stream){
  const int*   r     = (const int*)  d_in[0];
  const float* xyz   = (const float*)d_in[1];
  const int*   a     = (const int*)  d_in[2];
  const int*   molp  = (const int*)  d_in[3];
  const float* embed = (const float*)d_in[4];
  const float* Wn    = (const float*)d_in[5];
  const float* bn    = (const float*)d_in[6];
  const float* We1   = (const float*)d_in[7];
  const float* be1   = (const float*)d_in[8];
  const float* We2   = (const float*)d_in[9];
  const float* be2   = (const float*)d_in[10];
  const float* Wu1   = (const float*)d_in[11];
  const float* bu1   = (const float*)d_in[12];
  const float* Wu2   = (const float*)d_in[13];
  const float* bu2   = (const float*)d_in[14];
  const float* W1    = (const float*)d_in[15];
  const float* b1    = (const float*)d_in[16];
  const float* W2    = (const float*)d_in[17];
  const float* b2    = (const float*)d_in[18];

  int N = in_sizes[0];          // 50000
  int E = in_sizes[2] / 2;      // 500000
  int V = 2*E;                  // directed visits
  size_t VmaxS = (size_t)V + 4*(size_t)N;   // 4-pad worst case

  float* ws   = (float*)d_ws;
  size_t E4   = ((size_t)E + 3) & ~(size_t)3;
  size_t NSZ  = (size_t)N * NB;
  size_t RPAD = ((size_t)N + 1 + 3) & ~(size_t)3;
  size_t NPAD = ((size_t)N + 3) & ~(size_t)3;
  size_t base = E4 + 3*NSZ;
  size_t WPAD = 3*NG*64 + 3*64;   // We1p + be1p

  size_t need1 = (base + RPAD + 3*NPAD + 512 + 3*VmaxS + WPAD) * sizeof(float);
  size_t need2 = (base + RPAD + 2*NPAD + 512 + 3*(size_t)V) * sizeof(float);

  float* dbuf  = ws;
  float* h     = dbuf + E4;
  float* nodef = h + NSZ;
  float* agg   = nodef + NSZ;

  int g2blocks = (N + 127)/128;
  int gblocks  = (N + 63)/64;
  int eblocks  = (E + 127)/128;
  int nb = (N + SCAN_TILE - 1) / SCAN_TILE;

  embed_k<<<(N*32 + 255)/256, 256, 0, stream>>>(r, embed, h, N);
  dist_k <<<(E + 255)/256,    256, 0, stream>>>(a, xyz, dbuf, E);

  if (ws_size >= need1){
    int*   rowptr = (int*)(agg + NSZ);
    int*   cnt    = rowptr + RPAD;
    int*   pcnt   = cnt + NPAD;
    int*   cur    = pcnt + NPAD;
    int*   bsum   = cur + NPAD;
    int*   boff   = bsum + 256;
    int*   asrc   = boff + 256;
    int*   tgtv   = asrc + VmaxS;
    float* dvis   = (float*)(tgtv + VmaxS);
    float* We1p   = dvis + VmaxS;
    float* be1p   = We1p + 3*NG*64;

    (void)hipMemsetAsync(cnt, 0, (size_t)N*sizeof(int), stream);
    (void)hipMemsetAsync(asrc, 0, VmaxS*sizeof(int), stream);
    (void)hipMemsetAsync(tgtv, 0xFF, VmaxS*sizeof(int), stream);
    (void)hipMemsetAsync(dvis, 0, VmaxS*sizeof(float), stream);
    padw_k  <<<(3*NG*64 + 255)/256, 256, 0, stream>>>(We1, be1, We1p, be1p);
    hist_k  <<<(E + 255)/256, 256, 0, stream>>>(a, cnt, E);
    pad_k   <<<(N + 255)/256, 256, 0, stream>>>(cnt, pcnt, N);
    reduce_k<<<nb, 256, 0, stream>>>(pcnt, bsum, N);
    scanb_k <<<1, 64, 0, stream>>>(bsum, boff, nb);
    scan2_k <<<nb, 256, 0, stream>>>(pcnt, boff, rowptr, N, 0);
    copy_k  <<<(N + 255)/256, 256, 0, stream>>>(rowptr, cur, N);
    fill_k  <<<(E + 255)/256, 256, 0, stream>>>(a, dbuf, cur, asrc, dvis, tgtv, E);

    int vblocks = (int)((VmaxS + 127)/128);
    for (int l = 0; l < 3; l++){
      gemm256_k<0,0><<<g2blocks, 256, 0, stream>>>(h, Wn + (size_t)l*NB*NB, bn + l*NB, nodef, N);
      (void)hipMemsetAsync(agg, 0, NSZ*sizeof(float), stream);
      visit2_k<<<vblocks, 256, 0, stream>>>(dvis, asrc, tgtv, nodef,
                                            We1p + (size_t)l*NG*64, be1p + (size_t)l*64,
                                            We2 + (size_t)l*NG*NB, be2 + l*NB, agg, (int)VmaxS);
      gemm256_k<1,0><<<g2blocks, 256, 0, stream>>>(agg,   Wu1 + (size_t)l*NB*NB, bu1 + l*NB, nodef, N);
      gemm256_k<0,1><<<g2blocks, 256, 0, stream>>>(nodef, Wu2 + (size_t)l*NB*NB, bu2 + l*NB, h, N);
    }
  } else if (ws_size >= need2){
    int*   rowptr = (int*)(agg + NSZ);
    int*   cnt    = rowptr + RPAD;
    int*   cur    = cnt + NPAD;
    int*   bsum   = cur + NPAD;
    int*   boff   = bsum + 256;
    int*   asrc   = boff + 256;
    int*   tgtv   = asrc + V;
    float* dvis   = (float*)(tgtv + V);

    (void)hipMemsetAsync(cnt, 0, (size_t)N*sizeof(int), stream);
    hist_k  <<<(E + 255)/256, 256, 0, stream>>>(a, cnt, E);
    reduce_k<<<nb, 256, 0, stream>>>(cnt, bsum, N);
    scanb_k <<<1, 64, 0, stream>>>(bsum, boff, nb);
    scan2_k <<<nb, 256, 0, stream>>>(cnt, boff, rowptr, N, V);
    copy_k  <<<(N + 255)/256, 256, 0, stream>>>(rowptr, cur, N);
    fill_k  <<<(E + 255)/256, 256, 0, stream>>>(a, dbuf, cur, asrc, dvis, tgtv, E);

    int vblocks = (V + 127)/128;
    for (int l = 0; l < 3; l++){
      gemm256_k<0,0><<<g2blocks, 256, 0, stream>>>(h, Wn + (size_t)l*NB*NB, bn + l*NB, nodef, N);
      (void)hipMemsetAsync(agg, 0, NSZ*sizeof(float), stream);
      visit_k<<<vblocks, 256, 0, stream>>>(dvis, asrc, tgtv, nodef,
                                           We1 + (size_t)l*NG*NG, be1 + l*NG,
                                           We2 + (size_t)l*NG*NB, be2 + l*NB, agg, V);
      gemm256_k<1,0><<<g2blocks, 256, 0, stream>>>(agg,   Wu1 + (size_t)l*NB*NB, bu1 + l*NB, nodef, N);
      gemm256_k<0,1><<<g2blocks, 256, 0, stream>>>(nodef, Wu2 + (size_t)l*NB*NB, bu2 + l*NB, h, N);
    }
  } else {
    for (int l = 0; l < 3; l++){
      gemm256_k<0,0><<<g2blocks, 256, 0, stream>>>(h, Wn + (size_t)l*NB*NB, bn + l*NB, nodef, N);
      (void)hipMemsetAsync(agg, 0, NSZ*sizeof(float), stream);
      edge_k<<<eblocks, 256, 0, stream>>>(dbuf, a, nodef,
                                          We1 + (size_t)l*NG*NG, be1 + l*NG,
                                          We2 + (size_t)l*NG*NB, be2 + l*NB, agg, E);
      gemm256_k<1,0><<<g2blocks, 256, 0, stream>>>(agg,   Wu1 + (size_t)l*NB*NB, bu1 + l*NB, nodef, N);
      gemm256_k<0,1><<<g2blocks, 256, 0, stream>>>(nodef, Wu2 + (size_t)l*NB*NB, bu2 + l*NB, h, N);
    }
  }

  (void)hipMemsetAsync(d_out, 0, (size_t)out_size*sizeof(float), stream);
  readout_k<<<gblocks, 128, 0, stream>>>(h, W1, b1, W2, b2, molp, (float*)d_out, N);
}